// Round 4
// baseline (3198.316 us; speedup 1.0000x reference)
//
#include <hip/hip_runtime.h>

// ---------------------------------------------------------------- constants
#define EPSV 1e-5f
constexpr int Bsz = 4, T0 = 512, Dm = 512, TT = 513, NHh = 8, KK = 4;
constexpr int IN = 1024, DHd = 128, NCc = 1000;
constexpr int ROWS = Bsz * TT; // 2052
constexpr int NCH = 9;         // chunks of 64: 8*64 + 1 = 513

__device__ __forceinline__ float siluf(float x) { return x / (1.f + __expf(-x)); }

// ---------------------------------------------------------------- concat x + cls
__global__ __launch_bounds__(256) void concat_kernel(const float* __restrict__ x,
                                                     const float* __restrict__ cls,
                                                     float* __restrict__ h) {
    int idx = blockIdx.x * 256 + threadIdx.x;
    if (idx >= Bsz * TT * Dm) return;
    int d = idx & (Dm - 1);
    int bt = idx >> 9;
    int t = bt % TT, b = bt / TT;
    h[idx] = (t < T0) ? x[((size_t)(b * T0 + t)) * Dm + d] : cls[d];
}

// ---------------------------------------------------------------- LayerNorm rows of D=512
__global__ __launch_bounds__(256) void ln_kernel(const float* __restrict__ in,
                                                 const float* __restrict__ s,
                                                 const float* __restrict__ bb,
                                                 float* __restrict__ out) {
    int row = blockIdx.x, tid = threadIdx.x;
    const float* r = in + (size_t)row * Dm;
    __shared__ float s1[4], s2[4];
    float x0 = r[tid], x1 = r[tid + 256];
    float sum = x0 + x1, sq = x0 * x0 + x1 * x1;
#pragma unroll
    for (int o = 32; o > 0; o >>= 1) { sum += __shfl_xor(sum, o); sq += __shfl_xor(sq, o); }
    if ((tid & 63) == 0) { s1[tid >> 6] = sum; s2[tid >> 6] = sq; }
    __syncthreads();
    sum = s1[0] + s1[1] + s1[2] + s1[3];
    sq  = s2[0] + s2[1] + s2[2] + s2[3];
    float mu = sum / Dm, var = sq / Dm - mu * mu, inv = rsqrtf(var + EPSV);
    out[(size_t)row * Dm + tid]       = (x0 - mu) * inv * s[tid] + bb[tid];
    out[(size_t)row * Dm + tid + 256] = (x1 - mu) * inv * s[tid + 256] + bb[tid + 256];
}

// ---------------------------------------------------------------- generic f32 GEMM
__global__ __launch_bounds__(256) void gemm_kernel(const float* __restrict__ A, int lda,
                                                   const float* __restrict__ W, int ldw,
                                                   const float* __restrict__ bias,
                                                   const float* __restrict__ resid, int ldr,
                                                   float* __restrict__ Cout, int ldc,
                                                   int M, int Kd, float scale) {
    __shared__ __align__(16) float As[16][68];
    __shared__ __align__(16) float Bs[16][64];
    int tid = threadIdx.x;
    int tx = tid & 15, ty = tid >> 4;
    int m0 = blockIdx.y * 64, n0 = blockIdx.x * 64;
    int arow = tid >> 2, akp = (tid & 3) * 4;
    int brow = tid >> 4, bnp = (tid & 15) * 4;
    float acc[4][4] = {};
    for (int k0 = 0; k0 < Kd; k0 += 16) {
        float4 av = make_float4(0.f, 0.f, 0.f, 0.f);
        int gm = m0 + arow;
        if (gm < M) av = *(const float4*)(A + (size_t)gm * lda + k0 + akp);
        As[akp + 0][arow] = av.x; As[akp + 1][arow] = av.y;
        As[akp + 2][arow] = av.z; As[akp + 3][arow] = av.w;
        float4 wv = *(const float4*)(W + (size_t)(k0 + brow) * ldw + n0 + bnp);
        Bs[brow][bnp + 0] = wv.x; Bs[brow][bnp + 1] = wv.y;
        Bs[brow][bnp + 2] = wv.z; Bs[brow][bnp + 3] = wv.w;
        __syncthreads();
#pragma unroll
        for (int k = 0; k < 16; k++) {
            float4 a  = *(const float4*)&As[k][ty * 4];
            float4 bv = *(const float4*)&Bs[k][tx * 4];
            float aa[4] = {a.x, a.y, a.z, a.w};
            float bb2[4] = {bv.x, bv.y, bv.z, bv.w};
#pragma unroll
            for (int i = 0; i < 4; i++)
#pragma unroll
                for (int j = 0; j < 4; j++) acc[i][j] += aa[i] * bb2[j];
        }
        __syncthreads();
    }
#pragma unroll
    for (int i = 0; i < 4; i++) {
        int gm = m0 + ty * 4 + i;
        if (gm >= M) continue;
        float* crow = Cout + (size_t)gm * ldc + n0 + tx * 4;
        const float* rrow = resid ? (resid + (size_t)gm * ldr + n0 + tx * 4) : nullptr;
#pragma unroll
        for (int j = 0; j < 4; j++) {
            float vsum = acc[i][j] * scale;
            if (bias) vsum += bias[n0 + tx * 4 + j];
            if (rrow) vsum += rrow[j];
            crow[j] = vsum;
        }
    }
}

// ---------------------------------------------------------------- causal depthwise conv (K=4) + SiLU
__global__ __launch_bounds__(256) void conv_silu_kernel(const float* __restrict__ up,
                                                        const float* __restrict__ ck,
                                                        const float* __restrict__ cb,
                                                        float* __restrict__ xc) {
    int idx = blockIdx.x * 256 + threadIdx.x;
    if (idx >= ROWS * IN) return;
    int c = idx & (IN - 1);
    int bt = idx >> 10;
    int t = bt % TT, b = bt / TT;
    float acc = cb[c];
#pragma unroll
    for (int j = 0; j < KK; j++) {
        int tt = t - (KK - 1) + j;
        if (tt >= 0) acc += up[((size_t)(b * TT + tt)) * (2 * IN) + c] * ck[c * KK + j];
    }
    xc[idx] = siluf(acc);
}

// ---------------------------------------------------------------- input/forget gate projections
__global__ __launch_bounds__(256) void gates_kernel(const float* __restrict__ xc,
                                                    const float* __restrict__ wig, const float* __restrict__ big,
                                                    const float* __restrict__ wfg, const float* __restrict__ bfg,
                                                    float* __restrict__ ip, float* __restrict__ fp) {
    int row = blockIdx.x, tid = threadIdx.x;
    __shared__ float sx[IN];
    for (int i = tid; i < IN; i += 256) sx[i] = xc[(size_t)row * IN + i];
    __syncthreads();
    int g = tid >> 4, l = tid & 15;
    const float* w = (g < 8) ? wig : wfg;
    int h = g & 7;
    float acc = 0.f;
    for (int kk = l; kk < IN; kk += 16) acc += sx[kk] * w[kk * NHh + h];
#pragma unroll
    for (int o = 8; o > 0; o >>= 1) acc += __shfl_down(acc, o, 16);
    if (l == 0) {
        if (g < 8) ip[(size_t)row * NHh + h] = acc + big[h];
        else       fp[(size_t)row * NHh + h] = acc + bfg[h];
    }
}

// ---------------------------------------------------------------- chunkwise mLSTM
// Kernel A: sequential scalar gate scan per chain (32 chains).
__global__ __launch_bounds__(64) void gate_scan_kernel(const float* __restrict__ ip,
        const float* __restrict__ fp, float* __restrict__ gG, float* __restrict__ gM,
        float* __restrict__ gMb, float* __restrict__ gDec) {
    int chain = threadIdx.x;
    if (chain >= Bsz * NHh) return;
    int b = chain >> 3, h = chain & 7;
    float F = 0.f, M = 0.f, Mbprev = 0.f;
    for (int t = 0; t < TT; t++) {
        size_t gi = (size_t)(b * TT + t) * NHh + h;
        float fpv = fp[gi], ipv = ip[gi];
        float fl = (fpv >= 0.f) ? -log1pf(__expf(-fpv)) : (fpv - log1pf(__expf(fpv)));
        F += fl;
        float G = ipv - F;
        M = fmaxf(M, G);
        gG[chain * TT + t] = G;
        gM[chain * TT + t] = M;
        if (((t & 63) == 63) || t == TT - 1) {
            int c = t >> 6;
            gMb[chain * NCH + c] = M;
            gDec[chain * NCH + c] = __expf(Mbprev - M);
            Mbprev = M;
        }
    }
}

// Kernel B1: per-chunk local state P[d][e] = sum_j exp(G_j - Mb_c) k_j[d] v_j[e]
__global__ __launch_bounds__(256) void chunk_state_kernel(const float* __restrict__ kk,
        const float* __restrict__ vv, const float* __restrict__ gG,
        const float* __restrict__ gMb, float* __restrict__ P, float* __restrict__ nP) {
    int c = blockIdx.x, chain = blockIdx.y;
    int b = chain >> 3, h = chain & 7;
    int t0 = c * 64;
    int nvalid = min(64, TT - t0);
    __shared__ float sK[32][128], sV[32][128], sw[64];
    int tid = threadIdx.x;
    if (tid < 64) {
        float Mb = gMb[chain * NCH + c];
        sw[tid] = (tid < nvalid) ? __expf(gG[chain * TT + t0 + tid] - Mb) : 0.f;
    }
    int e = tid & 127, dg = (tid >> 7) * 64;
    float4 acc[16];
#pragma unroll
    for (int i = 0; i < 16; i++) acc[i] = make_float4(0.f, 0.f, 0.f, 0.f);
    float na = 0.f;
    for (int jh = 0; jh < 2; jh++) {
        int lrow = tid >> 5, lcol = (tid & 31) * 4;
        for (int rr = 0; rr < 4; rr++) {
            int r = lrow + rr * 8;
            int gr = jh * 32 + r;
            float4 kv = make_float4(0.f,0.f,0.f,0.f), vvv = kv;
            if (gr < nvalid) {
                size_t gb = ((size_t)(b * TT + t0 + gr)) * IN + h * DHd + lcol;
                kv = *(const float4*)(kk + gb);
                vvv = *(const float4*)(vv + gb);
            }
            *(float4*)&sK[r][lcol] = kv;
            *(float4*)&sV[r][lcol] = vvv;
        }
        __syncthreads();
        int jmax = min(32, nvalid - jh * 32);
        for (int j = 0; j < jmax; j++) {
            float wvj = sw[jh * 32 + j] * sV[j][e];
            const float4* kr = (const float4*)&sK[j][dg];
#pragma unroll
            for (int d4 = 0; d4 < 16; d4++) {
                float4 kq = kr[d4];
                acc[d4].x += kq.x * wvj; acc[d4].y += kq.y * wvj;
                acc[d4].z += kq.z * wvj; acc[d4].w += kq.w * wvj;
            }
        }
        if (tid < 128) {
            for (int j = 0; j < jmax; j++) na += sw[jh * 32 + j] * sK[j][tid];
        }
        __syncthreads();
    }
    float* Pbase = P + (((size_t)(c * 32 + chain)) << 14);
#pragma unroll
    for (int d4 = 0; d4 < 16; d4++) {
        Pbase[(size_t)(dg + d4 * 4 + 0) * 128 + e] = acc[d4].x;
        Pbase[(size_t)(dg + d4 * 4 + 1) * 128 + e] = acc[d4].y;
        Pbase[(size_t)(dg + d4 * 4 + 2) * 128 + e] = acc[d4].z;
        Pbase[(size_t)(dg + d4 * 4 + 3) * 128 + e] = acc[d4].w;
    }
    if (tid < 128) nP[(size_t)(c * 32 + chain) * 128 + tid] = na;
}

// Kernel B2: in-place exclusive combine over chunks.
__global__ __launch_bounds__(256) void chunk_combine_kernel(float* __restrict__ P,
        const float* __restrict__ gDec) {
    int chain = blockIdx.x >> 6;
    int idx = (blockIdx.x & 63) * 256 + threadIdx.x;
    float run = 0.f;
    for (int c = 0; c < NCH; c++) {
        size_t a = (((size_t)(c * 32 + chain)) << 14) + idx;
        float tmp = P[a];
        P[a] = run;
        run = run * gDec[chain * NCH + c] + tmp;
    }
}

__global__ __launch_bounds__(256) void n_combine_kernel(float* __restrict__ nP,
        const float* __restrict__ gDec) {
    int gidx = blockIdx.x * 256 + threadIdx.x;
    int chain = gidx >> 7, d = gidx & 127;
    float run = 0.f;
    for (int c = 0; c < NCH; c++) {
        size_t a = (size_t)(c * 32 + chain) * 128 + d;
        float tmp = nP[a];
        nP[a] = run;
        run = run * gDec[chain * NCH + c] + tmp;
    }
}

// Kernel C: per-chunk outputs, single 32-register accumulator (no spills).
// Order: inter (Q@CB) -> scale by sWr -> S=QK^T -> denom -> intra (D@V) -> store.
__global__ __launch_bounds__(256) void chunk_out_kernel(const float* __restrict__ qq,
        const float* __restrict__ kk, const float* __restrict__ vv,
        const float* __restrict__ gG, const float* __restrict__ gM,
        const float* __restrict__ gMb, const float* __restrict__ P,
        const float* __restrict__ nP, float* __restrict__ hs) {
    int c = blockIdx.x, chain = blockIdx.y;
    int b = chain >> 3, h = chain & 7;
    int t0 = c * 64;
    int nvalid = min(64, TT - t0);
    __shared__ float smem[13248];
    float* sG  = smem;          // 64
    float* sM  = smem + 64;     // 64
    float* sWr = smem + 128;    // 64
    float* sInv= smem + 192;    // 64
    float* sNb = smem + 256;    // 128
    float (*sD)[65] = (float(*)[65])(smem + 384);          // 64x65
    float* scr = smem + 384 + 64 * 65;                     // 8704 floats scratch
    int tid = threadIdx.x;

    float Mbprev = (c > 0) ? gMb[chain * NCH + c - 1] : 0.f;
    if (tid < 64) {
        bool val = tid < nvalid;
        sG[tid] = val ? gG[chain * TT + t0 + tid] : -1e30f;
        float Mv = val ? gM[chain * TT + t0 + tid] : 1e30f;
        sM[tid] = Mv;
        sWr[tid] = val ? __expf(Mbprev - Mv) : 0.f;
    }
    if (tid >= 128 && tid < 256) sNb[tid - 128] = nP[(size_t)(c * 32 + chain) * 128 + (tid - 128)];
    __syncthreads();

    int e = tid & 127, rg = (tid >> 7) * 32;
    float acc[32];
#pragma unroll
    for (int r = 0; r < 32; r++) acc[r] = 0.f;

    // ---- Phase 0: inter H = Q @ CB   (sD region still free -> overlap it)
    {
        float (*sCB)[128] = (float(*)[128])(smem + 384);          // 64x128
        float (*Qh2)[68]  = (float(*)[68])(smem + 384 + 64*128);  // 64x68
        const float* CBbase = P + (((size_t)(c * 32 + chain)) << 14);
        for (int dh = 0; dh < 2; dh++) {
            {
                int dr = tid >> 5, dc = (tid & 31) * 4;
                for (int rr = 0; rr < 8; rr++) {
                    int d = dr + rr * 8;
                    *(float4*)&sCB[d][dc] = *(const float4*)(CBbase + (size_t)(dh * 64 + d) * 128 + dc);
                }
                int lr = tid >> 2, c0 = (tid & 3) * 16;
                bool val = lr < nvalid;
                size_t gb = ((size_t)(b * TT + t0 + lr)) * IN + h * DHd + dh * 64 + c0;
#pragma unroll
                for (int i = 0; i < 4; i++) {
                    float4 qv = val ? *(const float4*)(qq + gb + i * 4) : make_float4(0.f,0.f,0.f,0.f);
                    *(float4*)&Qh2[lr][c0 + i * 4] = qv;
                }
            }
            __syncthreads();
            for (int dd = 0; dd < 64; dd++) {
                float cbv = sCB[dd][e];
#pragma unroll 8
                for (int r = 0; r < 32; r++) acc[r] += Qh2[rg + r][dd] * cbv;
            }
            __syncthreads();
        }
        // scale by per-row inter weight
#pragma unroll
        for (int r = 0; r < 32; r++) acc[r] *= sWr[rg + r];
    }

    // ---- Phase 1: S = Q K^T; weights -> sD; qnb
    float qnb = 0.f;
    {
        float (*Qh)[68] = (float(*)[68])scr;
        float (*Kh)[68] = (float(*)[68])(scr + 64 * 68);
        int j = tid & 63, ig = (tid >> 6) * 16;
        float accS[16];
#pragma unroll
        for (int i = 0; i < 16; i++) accS[i] = 0.f;
        for (int dh = 0; dh < 2; dh++) {
            int lr = tid >> 2, c0 = (tid & 3) * 16;
            bool val = lr < nvalid;
            size_t gb = ((size_t)(b * TT + t0 + lr)) * IN + h * DHd + dh * 64 + c0;
#pragma unroll
            for (int i = 0; i < 4; i++) {
                float4 qv = val ? *(const float4*)(qq + gb + i * 4) : make_float4(0.f,0.f,0.f,0.f);
                float4 kv = val ? *(const float4*)(kk + gb + i * 4) : make_float4(0.f,0.f,0.f,0.f);
                *(float4*)&Qh[lr][c0 + i * 4] = qv;
                *(float4*)&Kh[lr][c0 + i * 4] = kv;
            }
            __syncthreads();
#pragma unroll
            for (int d4 = 0; d4 < 16; d4++) {
                float4 kf = *(const float4*)&Kh[j][d4 * 4];
#pragma unroll
                for (int i = 0; i < 16; i++) {
                    float4 qf = *(const float4*)&Qh[ig + i][d4 * 4];
                    accS[i] += qf.x * kf.x + qf.y * kf.y + qf.z * kf.z + qf.w * kf.w;
                }
            }
            if (tid < 64) {
                for (int d = 0; d < 64; d++) qnb += Qh[tid][d] * sNb[dh * 64 + d];
            }
            __syncthreads();
        }
        float Gj = sG[j];
#pragma unroll
        for (int i = 0; i < 16; i++) {
            int irow = ig + i;
            float w = (j <= irow) ? __expf(Gj - sM[irow]) : 0.f;
            sD[irow][j] = accS[i] * w;
        }
    }
    __syncthreads();

    // ---- Phase 2: denominators
    if (tid < 64) {
        float s = 0.f;
        for (int jj = 0; jj < 64; jj++) s += sD[tid][jj];
        float den = s + sWr[tid] * qnb;
        sInv[tid] = 1.f / fmaxf(fabsf(den), 1.f);
    }
    __syncthreads();

    // ---- Phase 3: intra H += D @ V
    {
        float (*sV)[128] = (float(*)[128])scr;
        int lrow = tid >> 5, lcol = (tid & 31) * 4;
        for (int rr = 0; rr < 8; rr++) {
            int r = lrow + rr * 8;
            float4 vvv = make_float4(0.f,0.f,0.f,0.f);
            if (r < nvalid) {
                size_t gb = ((size_t)(b * TT + t0 + r)) * IN + h * DHd + lcol;
                vvv = *(const float4*)(vv + gb);
            }
            *(float4*)&sV[r][lcol] = vvv;
        }
        __syncthreads();
        for (int jj = 0; jj < nvalid; jj++) {
            float vvv = sV[jj][e];
#pragma unroll 8
            for (int r = 0; r < 32; r++) acc[r] += sD[rg + r][jj] * vvv;
        }
    }

    // ---- store
    for (int r = 0; r < 32; r++) {
        int irow = rg + r;
        if (irow < nvalid)
            hs[((size_t)(b * TT + t0 + irow)) * IN + h * DHd + e] = acc[r] * sInv[irow];
    }
}

// ---------------------------------------------------------------- per-head norm * hn_s * silu(z)
__global__ __launch_bounds__(64) void headnorm_kernel(const float* __restrict__ hs,
                                                      const float* __restrict__ hn,
                                                      const float* __restrict__ up,
                                                      float* __restrict__ out) {
    int idx = blockIdx.x;
    int h = idx & 7, bt = idx >> 3;
    int tid = threadIdx.x;
    size_t base = (size_t)bt * IN + h * DHd;
    float x0 = hs[base + tid], x1 = hs[base + 64 + tid];
    float sum = x0 + x1, sq = x0 * x0 + x1 * x1;
#pragma unroll
    for (int o = 32; o > 0; o >>= 1) { sum += __shfl_xor(sum, o); sq += __shfl_xor(sq, o); }
    float mu = sum / DHd, var = sq / DHd - mu * mu, inv = rsqrtf(var + EPSV);
    size_t zb = (size_t)bt * (2 * IN) + IN + h * DHd;
    out[base + tid]      = (x0 - mu) * inv * hn[h * DHd + tid]      * siluf(up[zb + tid]);
    out[base + 64 + tid] = (x1 - mu) * inv * hn[h * DHd + 64 + tid] * siluf(up[zb + 64 + tid]);
}

// ---------------------------------------------------------------- final classifier head
__global__ __launch_bounds__(256) void classifier_kernel(const float* __restrict__ hbuf,
                                                         const float* __restrict__ s, const float* __restrict__ bb,
                                                         const float* __restrict__ fw, const float* __restrict__ fb,
                                                         float* __restrict__ out) {
    int b = blockIdx.x, tid = threadIdx.x;
    const float* r = hbuf + ((size_t)b * TT + TT - 1) * Dm;
    __shared__ float vbuf[Dm];
    __shared__ float s1[4], s2[4];
    float x0 = r[tid], x1 = r[tid + 256];
    float sum = x0 + x1, sq = x0 * x0 + x1 * x1;
#pragma unroll
    for (int o = 32; o > 0; o >>= 1) { sum += __shfl_xor(sum, o); sq += __shfl_xor(sq, o); }
    if ((tid & 63) == 0) { s1[tid >> 6] = sum; s2[tid >> 6] = sq; }
    __syncthreads();
    sum = s1[0] + s1[1] + s1[2] + s1[3];
    sq  = s2[0] + s2[1] + s2[2] + s2[3];
    float mu = sum / Dm, var = sq / Dm - mu * mu, inv = rsqrtf(var + EPSV);
    float n0 = (x0 - mu) * inv * s[tid] + bb[tid];
    float n1 = (x1 - mu) * inv * s[tid + 256] + bb[tid + 256];
    vbuf[tid] = fmaxf(n0, 0.f);
    vbuf[tid + 256] = fmaxf(n1, 0.f);
    __syncthreads();
    for (int j = tid; j < NCc; j += 256) {
        float acc = fb[j];
        for (int kk = 0; kk < Dm; kk++) acc += vbuf[kk] * fw[kk * NCc + j];
        out[b * NCc + j] = acc;
    }
}

// ---------------------------------------------------------------- launch
extern "C" void kernel_launch(void* const* d_in, const int* in_sizes, int n_in,
                              void* d_out, int out_size, void* d_ws, size_t ws_size,
                              hipStream_t stream) {
    const float* x      = (const float*)d_in[0];
    const float* cls    = (const float*)d_in[1];
    const float* ln_s   = (const float*)d_in[2];
    const float* ln_b   = (const float*)d_in[3];
    const float* w_up   = (const float*)d_in[4];
    const float* b_up   = (const float*)d_in[5];
    const float* conv_k = (const float*)d_in[6];
    const float* conv_b = (const float*)d_in[7];
    const float* w_q    = (const float*)d_in[8];
    const float* w_k    = (const float*)d_in[9];
    const float* w_v    = (const float*)d_in[10];
    const float* w_ig   = (const float*)d_in[11];
    const float* b_ig   = (const float*)d_in[12];
    const float* w_fg   = (const float*)d_in[13];
    const float* b_fg   = (const float*)d_in[14];
    const float* hn_s   = (const float*)d_in[15];
    const float* w_down = (const float*)d_in[16];
    const float* b_down = (const float*)d_in[17];
    const float* fcls   = (const float*)d_in[18];
    const float* fclb   = (const float*)d_in[19];
    const float* fc_w   = (const float*)d_in[20];
    const float* fc_b   = (const float*)d_in[21];
    float* out = (float*)d_out;

    float* ws = (float*)d_ws;
    size_t off = 0;
    float* f_h  = ws + off; off += (size_t)ROWS * Dm;
    float* f_xn = ws + off; off += (size_t)ROWS * Dm;
    float* f_up = ws + off; off += (size_t)ROWS * 2 * IN;
    float* f_xc = ws + off; off += (size_t)ROWS * IN;
    float* f_q  = ws + off; off += (size_t)ROWS * IN;
    float* f_k  = ws + off; off += (size_t)ROWS * IN;
    float* f_v  = ws + off; off += (size_t)ROWS * IN;
    float* f_hs = ws + off; off += (size_t)ROWS * IN;
    float* f_ip = ws + off; off += (size_t)ROWS * NHh;
    float* f_fp = ws + off; off += (size_t)ROWS * NHh;
    float* g_G  = ws + off; off += 32 * TT;
    float* g_M  = ws + off; off += 32 * TT;
    float* g_Mb = ws + off; off += 32 * NCH;
    float* g_De = ws + off; off += 32 * NCH;
    float* g_P  = ws + off; off += (size_t)NCH * 32 * DHd * DHd;
    float* g_nP = ws + off; off += (size_t)NCH * 32 * DHd;

    const float kscale = 0.08838834764831845f; // DH^-0.5

    concat_kernel<<<(ROWS * Dm + 255) / 256, 256, 0, stream>>>(x, cls, f_h);

    for (int blk = 0; blk < 2; blk++) {
        const float* p_ln_s = ln_s + blk * Dm;
        const float* p_ln_b = ln_b + blk * Dm;
        const float* p_wup  = w_up + (size_t)blk * Dm * 2 * IN;
        const float* p_bup  = b_up + (size_t)blk * 2 * IN;
        const float* p_ck   = conv_k + (size_t)blk * IN * KK;
        const float* p_cb   = conv_b + (size_t)blk * IN;
        const float* p_wq   = w_q + (size_t)blk * IN * IN;
        const float* p_wk   = w_k + (size_t)blk * IN * IN;
        const float* p_wv   = w_v + (size_t)blk * IN * IN;
        const float* p_wig  = w_ig + (size_t)blk * IN * NHh;
        const float* p_big  = b_ig + (size_t)blk * NHh;
        const float* p_wfg  = w_fg + (size_t)blk * IN * NHh;
        const float* p_bfg  = b_fg + (size_t)blk * NHh;
        const float* p_hns  = hn_s + (size_t)blk * NHh * DHd;
        const float* p_wd   = w_down + (size_t)blk * IN * Dm;
        const float* p_bd   = b_down + (size_t)blk * Dm;

        ln_kernel<<<ROWS, 256, 0, stream>>>(f_h, p_ln_s, p_ln_b, f_xn);

        gemm_kernel<<<dim3(2 * IN / 64, (ROWS + 63) / 64), 256, 0, stream>>>(
            f_xn, Dm, p_wup, 2 * IN, p_bup, nullptr, 0, f_up, 2 * IN, ROWS, Dm, 1.f);

        conv_silu_kernel<<<(ROWS * IN + 255) / 256, 256, 0, stream>>>(f_up, p_ck, p_cb, f_xc);

        gemm_kernel<<<dim3(IN / 64, (ROWS + 63) / 64), 256, 0, stream>>>(
            f_xc, IN, p_wq, IN, nullptr, nullptr, 0, f_q, IN, ROWS, IN, 1.f);
        gemm_kernel<<<dim3(IN / 64, (ROWS + 63) / 64), 256, 0, stream>>>(
            f_xc, IN, p_wk, IN, nullptr, nullptr, 0, f_k, IN, ROWS, IN, kscale);
        gemm_kernel<<<dim3(IN / 64, (ROWS + 63) / 64), 256, 0, stream>>>(
            f_up, 2 * IN, p_wv, IN, nullptr, nullptr, 0, f_v, IN, ROWS, IN, 1.f);

        gates_kernel<<<ROWS, 256, 0, stream>>>(f_xc, p_wig, p_big, p_wfg, p_bfg, f_ip, f_fp);

        // chunkwise-parallel mLSTM
        gate_scan_kernel<<<1, 64, 0, stream>>>(f_ip, f_fp, g_G, g_M, g_Mb, g_De);
        chunk_state_kernel<<<dim3(NCH, 32), 256, 0, stream>>>(f_k, f_v, g_G, g_Mb, g_P, g_nP);
        chunk_combine_kernel<<<32 * 64, 256, 0, stream>>>(g_P, g_De);
        n_combine_kernel<<<16, 256, 0, stream>>>(g_nP, g_De);
        chunk_out_kernel<<<dim3(NCH, 32), 256, 0, stream>>>(f_q, f_k, f_v, g_G, g_M, g_Mb,
                                                            g_P, g_nP, f_hs);

        headnorm_kernel<<<ROWS * NHh, 64, 0, stream>>>(f_hs, p_hns, f_up, f_xc);

        gemm_kernel<<<dim3(Dm / 64, (ROWS + 63) / 64), 256, 0, stream>>>(
            f_xc, IN, p_wd, Dm, p_bd, f_h, Dm, f_h, Dm, ROWS, IN, 1.f);
    }

    classifier_kernel<<<Bsz, 256, 0, stream>>>(f_h, fcls, fclb, fc_w, fc_b, out);
}

// Round 5
// 2448.680 us; speedup vs baseline: 1.3061x; 1.3061x over previous
//
#include <hip/hip_runtime.h>

// ---------------------------------------------------------------- constants
#define EPSV 1e-5f
constexpr int Bsz = 4, T0 = 512, Dm = 512, TT = 513, NHh = 8, KK = 4;
constexpr int IN = 1024, DHd = 128, NCc = 1000;
constexpr int ROWS = Bsz * TT; // 2052
constexpr int NCH = 9;         // chunks of 64: 8*64 + 1 = 513

__device__ __forceinline__ float siluf(float x) { return x / (1.f + __expf(-x)); }

// ---------------------------------------------------------------- concat x + cls
__global__ __launch_bounds__(256) void concat_kernel(const float* __restrict__ x,
                                                     const float* __restrict__ cls,
                                                     float* __restrict__ h) {
    int idx = blockIdx.x * 256 + threadIdx.x;
    if (idx >= Bsz * TT * Dm) return;
    int d = idx & (Dm - 1);
    int bt = idx >> 9;
    int t = bt % TT, b = bt / TT;
    h[idx] = (t < T0) ? x[((size_t)(b * T0 + t)) * Dm + d] : cls[d];
}

// ---------------------------------------------------------------- LayerNorm rows of D=512
__global__ __launch_bounds__(256) void ln_kernel(const float* __restrict__ in,
                                                 const float* __restrict__ s,
                                                 const float* __restrict__ bb,
                                                 float* __restrict__ out) {
    int row = blockIdx.x, tid = threadIdx.x;
    const float* r = in + (size_t)row * Dm;
    __shared__ float s1[4], s2[4];
    float x0 = r[tid], x1 = r[tid + 256];
    float sum = x0 + x1, sq = x0 * x0 + x1 * x1;
#pragma unroll
    for (int o = 32; o > 0; o >>= 1) { sum += __shfl_xor(sum, o); sq += __shfl_xor(sq, o); }
    if ((tid & 63) == 0) { s1[tid >> 6] = sum; s2[tid >> 6] = sq; }
    __syncthreads();
    sum = s1[0] + s1[1] + s1[2] + s1[3];
    sq  = s2[0] + s2[1] + s2[2] + s2[3];
    float mu = sum / Dm, var = sq / Dm - mu * mu, inv = rsqrtf(var + EPSV);
    out[(size_t)row * Dm + tid]       = (x0 - mu) * inv * s[tid] + bb[tid];
    out[(size_t)row * Dm + tid + 256] = (x1 - mu) * inv * s[tid + 256] + bb[tid + 256];
}

// ---------------------------------------------------------------- generic f32 GEMM
__global__ __launch_bounds__(256) void gemm_kernel(const float* __restrict__ A, int lda,
                                                   const float* __restrict__ W, int ldw,
                                                   const float* __restrict__ bias,
                                                   const float* __restrict__ resid, int ldr,
                                                   float* __restrict__ Cout, int ldc,
                                                   int M, int Kd, float scale) {
    __shared__ __align__(16) float As[16][68];
    __shared__ __align__(16) float Bs[16][64];
    int tid = threadIdx.x;
    int tx = tid & 15, ty = tid >> 4;
    int m0 = blockIdx.y * 64, n0 = blockIdx.x * 64;
    int arow = tid >> 2, akp = (tid & 3) * 4;
    int brow = tid >> 4, bnp = (tid & 15) * 4;
    float acc[4][4] = {};
    for (int k0 = 0; k0 < Kd; k0 += 16) {
        float4 av = make_float4(0.f, 0.f, 0.f, 0.f);
        int gm = m0 + arow;
        if (gm < M) av = *(const float4*)(A + (size_t)gm * lda + k0 + akp);
        As[akp + 0][arow] = av.x; As[akp + 1][arow] = av.y;
        As[akp + 2][arow] = av.z; As[akp + 3][arow] = av.w;
        float4 wv = *(const float4*)(W + (size_t)(k0 + brow) * ldw + n0 + bnp);
        Bs[brow][bnp + 0] = wv.x; Bs[brow][bnp + 1] = wv.y;
        Bs[brow][bnp + 2] = wv.z; Bs[brow][bnp + 3] = wv.w;
        __syncthreads();
#pragma unroll
        for (int k = 0; k < 16; k++) {
            float4 a  = *(const float4*)&As[k][ty * 4];
            float4 bv = *(const float4*)&Bs[k][tx * 4];
            float aa[4] = {a.x, a.y, a.z, a.w};
            float bb2[4] = {bv.x, bv.y, bv.z, bv.w};
#pragma unroll
            for (int i = 0; i < 4; i++)
#pragma unroll
                for (int j = 0; j < 4; j++) acc[i][j] += aa[i] * bb2[j];
        }
        __syncthreads();
    }
#pragma unroll
    for (int i = 0; i < 4; i++) {
        int gm = m0 + ty * 4 + i;
        if (gm >= M) continue;
        float* crow = Cout + (size_t)gm * ldc + n0 + tx * 4;
        const float* rrow = resid ? (resid + (size_t)gm * ldr + n0 + tx * 4) : nullptr;
#pragma unroll
        for (int j = 0; j < 4; j++) {
            float vsum = acc[i][j] * scale;
            if (bias) vsum += bias[n0 + tx * 4 + j];
            if (rrow) vsum += rrow[j];
            crow[j] = vsum;
        }
    }
}

// ---------------------------------------------------------------- causal depthwise conv (K=4) + SiLU
__global__ __launch_bounds__(256) void conv_silu_kernel(const float* __restrict__ up,
                                                        const float* __restrict__ ck,
                                                        const float* __restrict__ cb,
                                                        float* __restrict__ xc) {
    int idx = blockIdx.x * 256 + threadIdx.x;
    if (idx >= ROWS * IN) return;
    int c = idx & (IN - 1);
    int bt = idx >> 10;
    int t = bt % TT, b = bt / TT;
    float acc = cb[c];
#pragma unroll
    for (int j = 0; j < KK; j++) {
        int tt = t - (KK - 1) + j;
        if (tt >= 0) acc += up[((size_t)(b * TT + tt)) * (2 * IN) + c] * ck[c * KK + j];
    }
    xc[idx] = siluf(acc);
}

// ---------------------------------------------------------------- input/forget gate projections
__global__ __launch_bounds__(256) void gates_kernel(const float* __restrict__ xc,
                                                    const float* __restrict__ wig, const float* __restrict__ big,
                                                    const float* __restrict__ wfg, const float* __restrict__ bfg,
                                                    float* __restrict__ ip, float* __restrict__ fp) {
    int row = blockIdx.x, tid = threadIdx.x;
    __shared__ float sx[IN];
    for (int i = tid; i < IN; i += 256) sx[i] = xc[(size_t)row * IN + i];
    __syncthreads();
    int g = tid >> 4, l = tid & 15;
    const float* w = (g < 8) ? wig : wfg;
    int h = g & 7;
    float acc = 0.f;
    for (int kk = l; kk < IN; kk += 16) acc += sx[kk] * w[kk * NHh + h];
#pragma unroll
    for (int o = 8; o > 0; o >>= 1) acc += __shfl_down(acc, o, 16);
    if (l == 0) {
        if (g < 8) ip[(size_t)row * NHh + h] = acc + big[h];
        else       fp[(size_t)row * NHh + h] = acc + bfg[h];
    }
}

// ---------------------------------------------------------------- chunkwise mLSTM
__global__ __launch_bounds__(64) void gate_scan_kernel(const float* __restrict__ ip,
        const float* __restrict__ fp, float* __restrict__ gG, float* __restrict__ gM,
        float* __restrict__ gMb, float* __restrict__ gDec) {
    int chain = threadIdx.x;
    if (chain >= Bsz * NHh) return;
    int b = chain >> 3, h = chain & 7;
    float F = 0.f, M = 0.f, Mbprev = 0.f;
    for (int t = 0; t < TT; t++) {
        size_t gi = (size_t)(b * TT + t) * NHh + h;
        float fpv = fp[gi], ipv = ip[gi];
        float fl = (fpv >= 0.f) ? -log1pf(__expf(-fpv)) : (fpv - log1pf(__expf(fpv)));
        F += fl;
        float G = ipv - F;
        M = fmaxf(M, G);
        gG[chain * TT + t] = G;
        gM[chain * TT + t] = M;
        if (((t & 63) == 63) || t == TT - 1) {
            int c = t >> 6;
            gMb[chain * NCH + c] = M;
            gDec[chain * NCH + c] = __expf(Mbprev - M);
            Mbprev = M;
        }
    }
}

// Kernel B1: per-chunk local state P[d][e] = sum_j exp(G_j - Mb_c) k_j[d] v_j[e]
__global__ __launch_bounds__(256) void chunk_state_kernel(const float* __restrict__ kk,
        const float* __restrict__ vv, const float* __restrict__ gG,
        const float* __restrict__ gMb, float* __restrict__ P, float* __restrict__ nP) {
    int c = blockIdx.x, chain = blockIdx.y;
    int b = chain >> 3, h = chain & 7;
    int t0 = c * 64;
    int nvalid = min(64, TT - t0);
    __shared__ float sK[32][128], sV[32][128], sw[64];
    int tid = threadIdx.x;
    if (tid < 64) {
        float Mb = gMb[chain * NCH + c];
        sw[tid] = (tid < nvalid) ? __expf(gG[chain * TT + t0 + tid] - Mb) : 0.f;
    }
    int e = tid & 127, dg = (tid >> 7) * 64;
    float4 acc[16];
#pragma unroll
    for (int i = 0; i < 16; i++) acc[i] = make_float4(0.f, 0.f, 0.f, 0.f);
    float na = 0.f;
    for (int jh = 0; jh < 2; jh++) {
        int lrow = tid >> 5, lcol = (tid & 31) * 4;
        for (int rr = 0; rr < 4; rr++) {
            int r = lrow + rr * 8;
            int gr = jh * 32 + r;
            float4 kv = make_float4(0.f,0.f,0.f,0.f), vvv = kv;
            if (gr < nvalid) {
                size_t gb = ((size_t)(b * TT + t0 + gr)) * IN + h * DHd + lcol;
                kv = *(const float4*)(kk + gb);
                vvv = *(const float4*)(vv + gb);
            }
            *(float4*)&sK[r][lcol] = kv;
            *(float4*)&sV[r][lcol] = vvv;
        }
        __syncthreads();
        int jmax = min(32, nvalid - jh * 32);
        for (int j = 0; j < jmax; j++) {
            float wvj = sw[jh * 32 + j] * sV[j][e];
            const float4* kr = (const float4*)&sK[j][dg];
#pragma unroll
            for (int d4 = 0; d4 < 16; d4++) {
                float4 kq = kr[d4];
                acc[d4].x += kq.x * wvj; acc[d4].y += kq.y * wvj;
                acc[d4].z += kq.z * wvj; acc[d4].w += kq.w * wvj;
            }
        }
        if (tid < 128) {
            for (int j = 0; j < jmax; j++) na += sw[jh * 32 + j] * sK[j][tid];
        }
        __syncthreads();
    }
    float* Pbase = P + (((size_t)(c * 32 + chain)) << 14);
#pragma unroll
    for (int d4 = 0; d4 < 16; d4++) {
        Pbase[(size_t)(dg + d4 * 4 + 0) * 128 + e] = acc[d4].x;
        Pbase[(size_t)(dg + d4 * 4 + 1) * 128 + e] = acc[d4].y;
        Pbase[(size_t)(dg + d4 * 4 + 2) * 128 + e] = acc[d4].z;
        Pbase[(size_t)(dg + d4 * 4 + 3) * 128 + e] = acc[d4].w;
    }
    if (tid < 128) nP[(size_t)(c * 32 + chain) * 128 + tid] = na;
}

// Kernel B2: in-place exclusive combine over chunks.
__global__ __launch_bounds__(256) void chunk_combine_kernel(float* __restrict__ P,
        const float* __restrict__ gDec) {
    int chain = blockIdx.x >> 6;
    int idx = (blockIdx.x & 63) * 256 + threadIdx.x;
    float run = 0.f;
    for (int c = 0; c < NCH; c++) {
        size_t a = (((size_t)(c * 32 + chain)) << 14) + idx;
        float tmp = P[a];
        P[a] = run;
        run = run * gDec[chain * NCH + c] + tmp;
    }
}

__global__ __launch_bounds__(256) void n_combine_kernel(float* __restrict__ nP,
        const float* __restrict__ gDec) {
    int gidx = blockIdx.x * 256 + threadIdx.x;
    int chain = gidx >> 7, d = gidx & 127;
    float run = 0.f;
    for (int c = 0; c < NCH; c++) {
        size_t a = (size_t)(c * 32 + chain) * 128 + d;
        float tmp = nP[a];
        nP[a] = run;
        run = run * gDec[chain * NCH + c] + tmp;
    }
}

// Kernel C: per-chunk outputs. ALL acc[] loops FULLY unrolled (partial unroll
// leaves a runtime index -> local array lowered to scratch -> 400MB spill traffic,
// the R3/R4 pathology).
__global__ __launch_bounds__(256) void chunk_out_kernel(const float* __restrict__ qq,
        const float* __restrict__ kk, const float* __restrict__ vv,
        const float* __restrict__ gG, const float* __restrict__ gM,
        const float* __restrict__ gMb, const float* __restrict__ P,
        const float* __restrict__ nP, float* __restrict__ hs) {
    int c = blockIdx.x, chain = blockIdx.y;
    int b = chain >> 3, h = chain & 7;
    int t0 = c * 64;
    int nvalid = min(64, TT - t0);
    __shared__ float smem[13248];
    float* sG  = smem;          // 64
    float* sM  = smem + 64;     // 64
    float* sWr = smem + 128;    // 64
    float* sInv= smem + 192;    // 64
    float* sNb = smem + 256;    // 128
    float (*sD)[65] = (float(*)[65])(smem + 384);          // 64x65
    float* scr = smem + 384 + 64 * 65;                     // 8704 floats scratch
    int tid = threadIdx.x;

    float Mbprev = (c > 0) ? gMb[chain * NCH + c - 1] : 0.f;
    if (tid < 64) {
        bool val = tid < nvalid;
        sG[tid] = val ? gG[chain * TT + t0 + tid] : -1e30f;
        float Mv = val ? gM[chain * TT + t0 + tid] : 1e30f;
        sM[tid] = Mv;
        sWr[tid] = val ? __expf(Mbprev - Mv) : 0.f;
    }
    if (tid >= 128 && tid < 256) sNb[tid - 128] = nP[(size_t)(c * 32 + chain) * 128 + (tid - 128)];
    __syncthreads();

    int e = tid & 127, rg = (tid >> 7) * 32;
    float acc[32];
#pragma unroll
    for (int r = 0; r < 32; r++) acc[r] = 0.f;

    // ---- Phase 0: inter H = Q @ CB
    {
        float (*sCB)[128] = (float(*)[128])(smem + 384);          // 64x128
        float (*Qh2)[68]  = (float(*)[68])(smem + 384 + 64*128);  // 64x68
        const float* CBbase = P + (((size_t)(c * 32 + chain)) << 14);
        for (int dh = 0; dh < 2; dh++) {
            {
                int dr = tid >> 5, dc = (tid & 31) * 4;
                for (int rr = 0; rr < 8; rr++) {
                    int d = dr + rr * 8;
                    *(float4*)&sCB[d][dc] = *(const float4*)(CBbase + (size_t)(dh * 64 + d) * 128 + dc);
                }
                int lr = tid >> 2, c0 = (tid & 3) * 16;
                bool val = lr < nvalid;
                size_t gb = ((size_t)(b * TT + t0 + lr)) * IN + h * DHd + dh * 64 + c0;
#pragma unroll
                for (int i = 0; i < 4; i++) {
                    float4 qv = val ? *(const float4*)(qq + gb + i * 4) : make_float4(0.f,0.f,0.f,0.f);
                    *(float4*)&Qh2[lr][c0 + i * 4] = qv;
                }
            }
            __syncthreads();
            for (int dd = 0; dd < 64; dd++) {
                float cbv = sCB[dd][e];
#pragma unroll
                for (int r = 0; r < 32; r++) acc[r] += Qh2[rg + r][dd] * cbv;
            }
            __syncthreads();
        }
#pragma unroll
        for (int r = 0; r < 32; r++) acc[r] *= sWr[rg + r];
    }

    // ---- Phase 1: S = Q K^T; weights -> sD; qnb
    float qnb = 0.f;
    {
        float (*Qh)[68] = (float(*)[68])scr;
        float (*Kh)[68] = (float(*)[68])(scr + 64 * 68);
        int j = tid & 63, ig = (tid >> 6) * 16;
        float accS[16];
#pragma unroll
        for (int i = 0; i < 16; i++) accS[i] = 0.f;
        for (int dh = 0; dh < 2; dh++) {
            int lr = tid >> 2, c0 = (tid & 3) * 16;
            bool val = lr < nvalid;
            size_t gb = ((size_t)(b * TT + t0 + lr)) * IN + h * DHd + dh * 64 + c0;
#pragma unroll
            for (int i = 0; i < 4; i++) {
                float4 qv = val ? *(const float4*)(qq + gb + i * 4) : make_float4(0.f,0.f,0.f,0.f);
                float4 kv = val ? *(const float4*)(kk + gb + i * 4) : make_float4(0.f,0.f,0.f,0.f);
                *(float4*)&Qh[lr][c0 + i * 4] = qv;
                *(float4*)&Kh[lr][c0 + i * 4] = kv;
            }
            __syncthreads();
#pragma unroll
            for (int d4 = 0; d4 < 16; d4++) {
                float4 kf = *(const float4*)&Kh[j][d4 * 4];
#pragma unroll
                for (int i = 0; i < 16; i++) {
                    float4 qf = *(const float4*)&Qh[ig + i][d4 * 4];
                    accS[i] += qf.x * kf.x + qf.y * kf.y + qf.z * kf.z + qf.w * kf.w;
                }
            }
            if (tid < 64) {
                for (int d = 0; d < 64; d++) qnb += Qh[tid][d] * sNb[dh * 64 + d];
            }
            __syncthreads();
        }
        float Gj = sG[j];
#pragma unroll
        for (int i = 0; i < 16; i++) {
            int irow = ig + i;
            float w = (j <= irow) ? __expf(Gj - sM[irow]) : 0.f;
            sD[irow][j] = accS[i] * w;
        }
    }
    __syncthreads();

    // ---- Phase 2: denominators
    if (tid < 64) {
        float s = 0.f;
        for (int jj = 0; jj < 64; jj++) s += sD[tid][jj];
        float den = s + sWr[tid] * qnb;
        sInv[tid] = 1.f / fmaxf(fabsf(den), 1.f);
    }
    __syncthreads();

    // ---- Phase 3: intra H += D @ V
    {
        float (*sV)[128] = (float(*)[128])scr;
        int lrow = tid >> 5, lcol = (tid & 31) * 4;
        for (int rr = 0; rr < 8; rr++) {
            int r = lrow + rr * 8;
            float4 vvv = make_float4(0.f,0.f,0.f,0.f);
            if (r < nvalid) {
                size_t gb = ((size_t)(b * TT + t0 + r)) * IN + h * DHd + lcol;
                vvv = *(const float4*)(vv + gb);
            }
            *(float4*)&sV[r][lcol] = vvv;
        }
        __syncthreads();
        for (int jj = 0; jj < nvalid; jj++) {
            float vvv = sV[jj][e];
#pragma unroll
            for (int r = 0; r < 32; r++) acc[r] += sD[rg + r][jj] * vvv;
        }
    }

    // ---- store
#pragma unroll
    for (int r = 0; r < 32; r++) {
        int irow = rg + r;
        if (irow < nvalid)
            hs[((size_t)(b * TT + t0 + irow)) * IN + h * DHd + e] = acc[r] * sInv[irow];
    }
}

// ---------------------------------------------------------------- per-head norm * hn_s * silu(z)
__global__ __launch_bounds__(64) void headnorm_kernel(const float* __restrict__ hs,
                                                      const float* __restrict__ hn,
                                                      const float* __restrict__ up,
                                                      float* __restrict__ out) {
    int idx = blockIdx.x;
    int h = idx & 7, bt = idx >> 3;
    int tid = threadIdx.x;
    size_t base = (size_t)bt * IN + h * DHd;
    float x0 = hs[base + tid], x1 = hs[base + 64 + tid];
    float sum = x0 + x1, sq = x0 * x0 + x1 * x1;
#pragma unroll
    for (int o = 32; o > 0; o >>= 1) { sum += __shfl_xor(sum, o); sq += __shfl_xor(sq, o); }
    float mu = sum / DHd, var = sq / DHd - mu * mu, inv = rsqrtf(var + EPSV);
    size_t zb = (size_t)bt * (2 * IN) + IN + h * DHd;
    out[base + tid]      = (x0 - mu) * inv * hn[h * DHd + tid]      * siluf(up[zb + tid]);
    out[base + 64 + tid] = (x1 - mu) * inv * hn[h * DHd + 64 + tid] * siluf(up[zb + 64 + tid]);
}

// ---------------------------------------------------------------- final classifier head
__global__ __launch_bounds__(256) void classifier_kernel(const float* __restrict__ hbuf,
                                                         const float* __restrict__ s, const float* __restrict__ bb,
                                                         const float* __restrict__ fw, const float* __restrict__ fb,
                                                         float* __restrict__ out) {
    int b = blockIdx.x, tid = threadIdx.x;
    const float* r = hbuf + ((size_t)b * TT + TT - 1) * Dm;
    __shared__ float vbuf[Dm];
    __shared__ float s1[4], s2[4];
    float x0 = r[tid], x1 = r[tid + 256];
    float sum = x0 + x1, sq = x0 * x0 + x1 * x1;
#pragma unroll
    for (int o = 32; o > 0; o >>= 1) { sum += __shfl_xor(sum, o); sq += __shfl_xor(sq, o); }
    if ((tid & 63) == 0) { s1[tid >> 6] = sum; s2[tid >> 6] = sq; }
    __syncthreads();
    sum = s1[0] + s1[1] + s1[2] + s1[3];
    sq  = s2[0] + s2[1] + s2[2] + s2[3];
    float mu = sum / Dm, var = sq / Dm - mu * mu, inv = rsqrtf(var + EPSV);
    float n0 = (x0 - mu) * inv * s[tid] + bb[tid];
    float n1 = (x1 - mu) * inv * s[tid + 256] + bb[tid + 256];
    vbuf[tid] = fmaxf(n0, 0.f);
    vbuf[tid + 256] = fmaxf(n1, 0.f);
    __syncthreads();
    for (int j = tid; j < NCc; j += 256) {
        float acc = fb[j];
        for (int kk = 0; kk < Dm; kk++) acc += vbuf[kk] * fw[kk * NCc + j];
        out[b * NCc + j] = acc;
    }
}

// ---------------------------------------------------------------- launch
extern "C" void kernel_launch(void* const* d_in, const int* in_sizes, int n_in,
                              void* d_out, int out_size, void* d_ws, size_t ws_size,
                              hipStream_t stream) {
    const float* x      = (const float*)d_in[0];
    const float* cls    = (const float*)d_in[1];
    const float* ln_s   = (const float*)d_in[2];
    const float* ln_b   = (const float*)d_in[3];
    const float* w_up   = (const float*)d_in[4];
    const float* b_up   = (const float*)d_in[5];
    const float* conv_k = (const float*)d_in[6];
    const float* conv_b = (const float*)d_in[7];
    const float* w_q    = (const float*)d_in[8];
    const float* w_k    = (const float*)d_in[9];
    const float* w_v    = (const float*)d_in[10];
    const float* w_ig   = (const float*)d_in[11];
    const float* b_ig   = (const float*)d_in[12];
    const float* w_fg   = (const float*)d_in[13];
    const float* b_fg   = (const float*)d_in[14];
    const float* hn_s   = (const float*)d_in[15];
    const float* w_down = (const float*)d_in[16];
    const float* b_down = (const float*)d_in[17];
    const float* fcls   = (const float*)d_in[18];
    const float* fclb   = (const float*)d_in[19];
    const float* fc_w   = (const float*)d_in[20];
    const float* fc_b   = (const float*)d_in[21];
    float* out = (float*)d_out;

    float* ws = (float*)d_ws;
    size_t off = 0;
    float* f_h  = ws + off; off += (size_t)ROWS * Dm;
    float* f_xn = ws + off; off += (size_t)ROWS * Dm;
    float* f_up = ws + off; off += (size_t)ROWS * 2 * IN;
    float* f_xc = ws + off; off += (size_t)ROWS * IN;
    float* f_q  = ws + off; off += (size_t)ROWS * IN;
    float* f_k  = ws + off; off += (size_t)ROWS * IN;
    float* f_v  = ws + off; off += (size_t)ROWS * IN;
    float* f_hs = ws + off; off += (size_t)ROWS * IN;
    float* f_ip = ws + off; off += (size_t)ROWS * NHh;
    float* f_fp = ws + off; off += (size_t)ROWS * NHh;
    float* g_G  = ws + off; off += 32 * TT;
    float* g_M  = ws + off; off += 32 * TT;
    float* g_Mb = ws + off; off += 32 * NCH;
    float* g_De = ws + off; off += 32 * NCH;
    float* g_P  = ws + off; off += (size_t)NCH * 32 * DHd * DHd;
    float* g_nP = ws + off; off += (size_t)NCH * 32 * DHd;

    const float kscale = 0.08838834764831845f; // DH^-0.5

    concat_kernel<<<(ROWS * Dm + 255) / 256, 256, 0, stream>>>(x, cls, f_h);

    for (int blk = 0; blk < 2; blk++) {
        const float* p_ln_s = ln_s + blk * Dm;
        const float* p_ln_b = ln_b + blk * Dm;
        const float* p_wup  = w_up + (size_t)blk * Dm * 2 * IN;
        const float* p_bup  = b_up + (size_t)blk * 2 * IN;
        const float* p_ck   = conv_k + (size_t)blk * IN * KK;
        const float* p_cb   = conv_b + (size_t)blk * IN;
        const float* p_wq   = w_q + (size_t)blk * IN * IN;
        const float* p_wk   = w_k + (size_t)blk * IN * IN;
        const float* p_wv   = w_v + (size_t)blk * IN * IN;
        const float* p_wig  = w_ig + (size_t)blk * IN * NHh;
        const float* p_big  = b_ig + (size_t)blk * NHh;
        const float* p_wfg  = w_fg + (size_t)blk * IN * NHh;
        const float* p_bfg  = b_fg + (size_t)blk * NHh;
        const float* p_hns  = hn_s + (size_t)blk * NHh * DHd;
        const float* p_wd   = w_down + (size_t)blk * IN * Dm;
        const float* p_bd   = b_down + (size_t)blk * Dm;

        ln_kernel<<<ROWS, 256, 0, stream>>>(f_h, p_ln_s, p_ln_b, f_xn);

        gemm_kernel<<<dim3(2 * IN / 64, (ROWS + 63) / 64), 256, 0, stream>>>(
            f_xn, Dm, p_wup, 2 * IN, p_bup, nullptr, 0, f_up, 2 * IN, ROWS, Dm, 1.f);

        conv_silu_kernel<<<(ROWS * IN + 255) / 256, 256, 0, stream>>>(f_up, p_ck, p_cb, f_xc);

        gemm_kernel<<<dim3(IN / 64, (ROWS + 63) / 64), 256, 0, stream>>>(
            f_xc, IN, p_wq, IN, nullptr, nullptr, 0, f_q, IN, ROWS, IN, 1.f);
        gemm_kernel<<<dim3(IN / 64, (ROWS + 63) / 64), 256, 0, stream>>>(
            f_xc, IN, p_wk, IN, nullptr, nullptr, 0, f_k, IN, ROWS, IN, kscale);
        gemm_kernel<<<dim3(IN / 64, (ROWS + 63) / 64), 256, 0, stream>>>(
            f_up, 2 * IN, p_wv, IN, nullptr, nullptr, 0, f_v, IN, ROWS, IN, 1.f);

        gates_kernel<<<ROWS, 256, 0, stream>>>(f_xc, p_wig, p_big, p_wfg, p_bfg, f_ip, f_fp);

        // chunkwise-parallel mLSTM
        gate_scan_kernel<<<1, 64, 0, stream>>>(f_ip, f_fp, g_G, g_M, g_Mb, g_De);
        chunk_state_kernel<<<dim3(NCH, 32), 256, 0, stream>>>(f_k, f_v, g_G, g_Mb, g_P, g_nP);
        chunk_combine_kernel<<<32 * 64, 256, 0, stream>>>(g_P, g_De);
        n_combine_kernel<<<16, 256, 0, stream>>>(g_nP, g_De);
        chunk_out_kernel<<<dim3(NCH, 32), 256, 0, stream>>>(f_q, f_k, f_v, g_G, g_M, g_Mb,
                                                            g_P, g_nP, f_hs);

        headnorm_kernel<<<ROWS * NHh, 64, 0, stream>>>(f_hs, p_hns, f_up, f_xc);

        gemm_kernel<<<dim3(Dm / 64, (ROWS + 63) / 64), 256, 0, stream>>>(
            f_xc, IN, p_wd, Dm, p_bd, f_h, Dm, f_h, Dm, ROWS, IN, 1.f);
    }

    classifier_kernel<<<Bsz, 256, 0, stream>>>(f_h, fcls, fclb, fc_w, fc_b, out);
}

// Round 6
// 1865.700 us; speedup vs baseline: 1.7143x; 1.3125x over previous
//
#include <hip/hip_runtime.h>

// ---------------------------------------------------------------- constants
#define EPSV 1e-5f
constexpr int Bsz = 4, T0 = 512, Dm = 512, TT = 513, NHh = 8, KK = 4;
constexpr int IN = 1024, DHd = 128, NCc = 1000;
constexpr int ROWS = Bsz * TT; // 2052
constexpr int NCH = 9;         // chunks of 64: 8*64 + 1 = 513

__device__ __forceinline__ float siluf(float x) { return x / (1.f + __expf(-x)); }

// ---------------------------------------------------------------- concat x + cls
__global__ __launch_bounds__(256) void concat_kernel(const float* __restrict__ x,
                                                     const float* __restrict__ cls,
                                                     float* __restrict__ h) {
    int idx = blockIdx.x * 256 + threadIdx.x;
    if (idx >= Bsz * TT * Dm) return;
    int d = idx & (Dm - 1);
    int bt = idx >> 9;
    int t = bt % TT, b = bt / TT;
    h[idx] = (t < T0) ? x[((size_t)(b * T0 + t)) * Dm + d] : cls[d];
}

// ---------------------------------------------------------------- LayerNorm rows of D=512
__global__ __launch_bounds__(256) void ln_kernel(const float* __restrict__ in,
                                                 const float* __restrict__ s,
                                                 const float* __restrict__ bb,
                                                 float* __restrict__ out) {
    int row = blockIdx.x, tid = threadIdx.x;
    const float* r = in + (size_t)row * Dm;
    __shared__ float s1[4], s2[4];
    float x0 = r[tid], x1 = r[tid + 256];
    float sum = x0 + x1, sq = x0 * x0 + x1 * x1;
#pragma unroll
    for (int o = 32; o > 0; o >>= 1) { sum += __shfl_xor(sum, o); sq += __shfl_xor(sq, o); }
    if ((tid & 63) == 0) { s1[tid >> 6] = sum; s2[tid >> 6] = sq; }
    __syncthreads();
    sum = s1[0] + s1[1] + s1[2] + s1[3];
    sq  = s2[0] + s2[1] + s2[2] + s2[3];
    float mu = sum / Dm, var = sq / Dm - mu * mu, inv = rsqrtf(var + EPSV);
    out[(size_t)row * Dm + tid]       = (x0 - mu) * inv * s[tid] + bb[tid];
    out[(size_t)row * Dm + tid + 256] = (x1 - mu) * inv * s[tid + 256] + bb[tid + 256];
}

// ---------------------------------------------------------------- generic f32 GEMM
__global__ __launch_bounds__(256) void gemm_kernel(const float* __restrict__ A, int lda,
                                                   const float* __restrict__ W, int ldw,
                                                   const float* __restrict__ bias,
                                                   const float* __restrict__ resid, int ldr,
                                                   float* __restrict__ Cout, int ldc,
                                                   int M, int Kd, float scale) {
    __shared__ __align__(16) float As[16][68];
    __shared__ __align__(16) float Bs[16][64];
    int tid = threadIdx.x;
    int tx = tid & 15, ty = tid >> 4;
    int m0 = blockIdx.y * 64, n0 = blockIdx.x * 64;
    int arow = tid >> 2, akp = (tid & 3) * 4;
    int brow = tid >> 4, bnp = (tid & 15) * 4;
    float acc[4][4] = {};
    for (int k0 = 0; k0 < Kd; k0 += 16) {
        float4 av = make_float4(0.f, 0.f, 0.f, 0.f);
        int gm = m0 + arow;
        if (gm < M) av = *(const float4*)(A + (size_t)gm * lda + k0 + akp);
        As[akp + 0][arow] = av.x; As[akp + 1][arow] = av.y;
        As[akp + 2][arow] = av.z; As[akp + 3][arow] = av.w;
        float4 wv = *(const float4*)(W + (size_t)(k0 + brow) * ldw + n0 + bnp);
        Bs[brow][bnp + 0] = wv.x; Bs[brow][bnp + 1] = wv.y;
        Bs[brow][bnp + 2] = wv.z; Bs[brow][bnp + 3] = wv.w;
        __syncthreads();
#pragma unroll
        for (int k = 0; k < 16; k++) {
            float4 a  = *(const float4*)&As[k][ty * 4];
            float4 bv = *(const float4*)&Bs[k][tx * 4];
            float aa[4] = {a.x, a.y, a.z, a.w};
            float bb2[4] = {bv.x, bv.y, bv.z, bv.w};
#pragma unroll
            for (int i = 0; i < 4; i++)
#pragma unroll
                for (int j = 0; j < 4; j++) acc[i][j] += aa[i] * bb2[j];
        }
        __syncthreads();
    }
#pragma unroll
    for (int i = 0; i < 4; i++) {
        int gm = m0 + ty * 4 + i;
        if (gm >= M) continue;
        float* crow = Cout + (size_t)gm * ldc + n0 + tx * 4;
        const float* rrow = resid ? (resid + (size_t)gm * ldr + n0 + tx * 4) : nullptr;
#pragma unroll
        for (int j = 0; j < 4; j++) {
            float vsum = acc[i][j] * scale;
            if (bias) vsum += bias[n0 + tx * 4 + j];
            if (rrow) vsum += rrow[j];
            crow[j] = vsum;
        }
    }
}

// ---------------------------------------------------------------- causal depthwise conv (K=4) + SiLU
__global__ __launch_bounds__(256) void conv_silu_kernel(const float* __restrict__ up,
                                                        const float* __restrict__ ck,
                                                        const float* __restrict__ cb,
                                                        float* __restrict__ xc) {
    int idx = blockIdx.x * 256 + threadIdx.x;
    if (idx >= ROWS * IN) return;
    int c = idx & (IN - 1);
    int bt = idx >> 10;
    int t = bt % TT, b = bt / TT;
    float acc = cb[c];
#pragma unroll
    for (int j = 0; j < KK; j++) {
        int tt = t - (KK - 1) + j;
        if (tt >= 0) acc += up[((size_t)(b * TT + tt)) * (2 * IN) + c] * ck[c * KK + j];
    }
    xc[idx] = siluf(acc);
}

// ---------------------------------------------------------------- input/forget gate projections
__global__ __launch_bounds__(256) void gates_kernel(const float* __restrict__ xc,
                                                    const float* __restrict__ wig, const float* __restrict__ big,
                                                    const float* __restrict__ wfg, const float* __restrict__ bfg,
                                                    float* __restrict__ ip, float* __restrict__ fp) {
    int row = blockIdx.x, tid = threadIdx.x;
    __shared__ float sx[IN];
    for (int i = tid; i < IN; i += 256) sx[i] = xc[(size_t)row * IN + i];
    __syncthreads();
    int g = tid >> 4, l = tid & 15;
    const float* w = (g < 8) ? wig : wfg;
    int h = g & 7;
    float acc = 0.f;
    for (int kk = l; kk < IN; kk += 16) acc += sx[kk] * w[kk * NHh + h];
#pragma unroll
    for (int o = 8; o > 0; o >>= 1) acc += __shfl_down(acc, o, 16);
    if (l == 0) {
        if (g < 8) ip[(size_t)row * NHh + h] = acc + big[h];
        else       fp[(size_t)row * NHh + h] = acc + bfg[h];
    }
}

// ---------------------------------------------------------------- chunkwise mLSTM
// Kernel A (wave-parallel): one wave per chain. Prefix-sum for F=cumsum(logsigmoid(fp)),
// prefix-max for M = max(0, cummax(G)), G = ip - F.
__global__ __launch_bounds__(64) void gate_scan_kernel(const float* __restrict__ ip,
        const float* __restrict__ fp, float* __restrict__ gG, float* __restrict__ gM,
        float* __restrict__ gMb, float* __restrict__ gDec) {
    constexpr int PER = 9; // 64*9 = 576 >= 513
    int chain = blockIdx.x;
    int b = chain >> 3, h = chain & 7;
    int lane = threadIdx.x;
    int tbase = lane * PER;
    float lcs[PER];   // local inclusive cumsum of fl, later reused as local cummax of G
    float gi[PER];
    float csum = 0.f;
#pragma unroll
    for (int i = 0; i < PER; i++) {
        int t = tbase + i;
        float fpv = 0.f, ipv = 0.f;
        if (t < TT) {
            size_t gidx = (size_t)(b * TT + t) * NHh + h;
            fpv = fp[gidx]; ipv = ip[gidx];
        }
        float flv = (fpv >= 0.f) ? -log1pf(__expf(-fpv)) : (fpv - log1pf(__expf(fpv)));
        if (t >= TT) flv = 0.f;
        csum += flv;
        lcs[i] = csum;
        gi[i] = ipv;
    }
    // wave inclusive prefix-sum of per-lane totals -> exclusive offset
    float ps = csum;
#pragma unroll
    for (int o = 1; o < 64; o <<= 1) {
        float v = __shfl_up(ps, o);
        if (lane >= o) ps += v;
    }
    float Fexcl = ps - csum;
    // G + local cummax
    float G[PER];
    float cmax = -1e30f;
#pragma unroll
    for (int i = 0; i < PER; i++) {
        int t = tbase + i;
        G[i] = (t < TT) ? (gi[i] - (Fexcl + lcs[i])) : -1e30f;
        cmax = fmaxf(cmax, G[i]);
        lcs[i] = cmax;       // local inclusive cummax
    }
    // wave inclusive prefix-max -> exclusive via shift
    float pm = cmax;
#pragma unroll
    for (int o = 1; o < 64; o <<= 1) {
        float v = __shfl_up(pm, o);
        if (lane >= o) pm = fmaxf(pm, v);
    }
    float Me = __shfl_up(pm, 1);
    if (lane == 0) Me = -1e30f;
    __shared__ float sMb[NCH];
#pragma unroll
    for (int i = 0; i < PER; i++) {
        int t = tbase + i;
        if (t < TT) {
            float Mt = fmaxf(0.f, fmaxf(Me, lcs[i]));   // includes the initial m=0
            gG[chain * TT + t] = G[i];
            gM[chain * TT + t] = Mt;
            if (((t & 63) == 63) || t == TT - 1) sMb[t >> 6] = Mt;
        }
    }
    __syncthreads();
    if (lane < NCH) {
        float Mb = sMb[lane];
        float Mbp = (lane == 0) ? 0.f : sMb[lane - 1];
        gMb[chain * NCH + lane] = Mb;
        gDec[chain * NCH + lane] = __expf(Mbp - Mb);
    }
}

// Kernel B1: per-chunk local state P[d][e] = sum_j exp(G_j - Mb_c) k_j[d] v_j[e]
__global__ __launch_bounds__(256) void chunk_state_kernel(const float* __restrict__ kk,
        const float* __restrict__ vv, const float* __restrict__ gG,
        const float* __restrict__ gMb, float* __restrict__ P, float* __restrict__ nP) {
    int c = blockIdx.x, chain = blockIdx.y;
    int b = chain >> 3, h = chain & 7;
    int t0 = c * 64;
    int nvalid = min(64, TT - t0);
    __shared__ float sK[32][128], sV[32][128], sw[64];
    int tid = threadIdx.x;
    if (tid < 64) {
        float Mb = gMb[chain * NCH + c];
        sw[tid] = (tid < nvalid) ? __expf(gG[chain * TT + t0 + tid] - Mb) : 0.f;
    }
    int e = tid & 127, dg = (tid >> 7) * 64;
    float4 acc[16];
#pragma unroll
    for (int i = 0; i < 16; i++) acc[i] = make_float4(0.f, 0.f, 0.f, 0.f);
    float na = 0.f;
    for (int jh = 0; jh < 2; jh++) {
        int lrow = tid >> 5, lcol = (tid & 31) * 4;
        for (int rr = 0; rr < 4; rr++) {
            int r = lrow + rr * 8;
            int gr = jh * 32 + r;
            float4 kv = make_float4(0.f,0.f,0.f,0.f), vvv = kv;
            if (gr < nvalid) {
                size_t gb = ((size_t)(b * TT + t0 + gr)) * IN + h * DHd + lcol;
                kv = *(const float4*)(kk + gb);
                vvv = *(const float4*)(vv + gb);
            }
            *(float4*)&sK[r][lcol] = kv;
            *(float4*)&sV[r][lcol] = vvv;
        }
        __syncthreads();
        int jmax = min(32, nvalid - jh * 32);
        for (int j = 0; j < jmax; j++) {
            float wvj = sw[jh * 32 + j] * sV[j][e];
            const float4* kr = (const float4*)&sK[j][dg];
#pragma unroll
            for (int d4 = 0; d4 < 16; d4++) {
                float4 kq = kr[d4];
                acc[d4].x += kq.x * wvj; acc[d4].y += kq.y * wvj;
                acc[d4].z += kq.z * wvj; acc[d4].w += kq.w * wvj;
            }
        }
        if (tid < 128) {
            for (int j = 0; j < jmax; j++) na += sw[jh * 32 + j] * sK[j][tid];
        }
        __syncthreads();
    }
    float* Pbase = P + (((size_t)(c * 32 + chain)) << 14);
#pragma unroll
    for (int d4 = 0; d4 < 16; d4++) {
        Pbase[(size_t)(dg + d4 * 4 + 0) * 128 + e] = acc[d4].x;
        Pbase[(size_t)(dg + d4 * 4 + 1) * 128 + e] = acc[d4].y;
        Pbase[(size_t)(dg + d4 * 4 + 2) * 128 + e] = acc[d4].z;
        Pbase[(size_t)(dg + d4 * 4 + 3) * 128 + e] = acc[d4].w;
    }
    if (tid < 128) nP[(size_t)(c * 32 + chain) * 128 + tid] = na;
}

// Kernel B2: in-place exclusive combine over chunks.
__global__ __launch_bounds__(256) void chunk_combine_kernel(float* __restrict__ P,
        const float* __restrict__ gDec) {
    int chain = blockIdx.x >> 6;
    int idx = (blockIdx.x & 63) * 256 + threadIdx.x;
    float run = 0.f;
    for (int c = 0; c < NCH; c++) {
        size_t a = (((size_t)(c * 32 + chain)) << 14) + idx;
        float tmp = P[a];
        P[a] = run;
        run = run * gDec[chain * NCH + c] + tmp;
    }
}

__global__ __launch_bounds__(256) void n_combine_kernel(float* __restrict__ nP,
        const float* __restrict__ gDec) {
    int gidx = blockIdx.x * 256 + threadIdx.x;
    int chain = gidx >> 7, d = gidx & 127;
    float run = 0.f;
    for (int c = 0; c < NCH; c++) {
        size_t a = (size_t)(c * 32 + chain) * 128 + d;
        float tmp = nP[a];
        nP[a] = run;
        run = run * gDec[chain * NCH + c] + tmp;
    }
}

// Kernel C: per-chunk outputs, 512 threads, acc[16]/accS[8] per thread to kill
// the phase-boundary register spills seen in R4/R5 (VGPR=256, 400MB scratch).
__global__ __launch_bounds__(512) void chunk_out_kernel(const float* __restrict__ qq,
        const float* __restrict__ kk, const float* __restrict__ vv,
        const float* __restrict__ gG, const float* __restrict__ gM,
        const float* __restrict__ gMb, const float* __restrict__ P,
        const float* __restrict__ nP, float* __restrict__ hs) {
    int c = blockIdx.x, chain = blockIdx.y;
    int b = chain >> 3, h = chain & 7;
    int t0 = c * 64;
    int nvalid = min(64, TT - t0);
    __shared__ float smem[13248];
    float* sG  = smem;          // 64
    float* sM  = smem + 64;     // 64
    float* sWr = smem + 128;    // 64
    float* sInv= smem + 192;    // 64
    float* sNb = smem + 256;    // 128
    float (*sD)[65] = (float(*)[65])(smem + 384);          // 64x65
    float* scr = smem + 384 + 64 * 65;                     // 8704 floats scratch
    int tid = threadIdx.x;

    float Mbprev = (c > 0) ? gMb[chain * NCH + c - 1] : 0.f;
    if (tid < 64) {
        bool val = tid < nvalid;
        sG[tid] = val ? gG[chain * TT + t0 + tid] : -1e30f;
        float Mv = val ? gM[chain * TT + t0 + tid] : 1e30f;
        sM[tid] = Mv;
        sWr[tid] = val ? __expf(Mbprev - Mv) : 0.f;
    }
    if (tid >= 128 && tid < 256) sNb[tid - 128] = nP[(size_t)(c * 32 + chain) * 128 + (tid - 128)];
    __syncthreads();

    int e = tid & 127, rg = (tid >> 7) * 16;   // 4 row-groups x 16 rows
    float acc[16];
#pragma unroll
    for (int r = 0; r < 16; r++) acc[r] = 0.f;

    // ---- Phase 0: inter H = Q @ CB
    {
        float (*sCB)[128] = (float(*)[128])(smem + 384);          // 64x128
        float (*Qh2)[68]  = (float(*)[68])(smem + 384 + 64*128);  // 64x68
        const float* CBbase = P + (((size_t)(c * 32 + chain)) << 14);
        for (int dh = 0; dh < 2; dh++) {
            {
                int dr = tid >> 5, dc = (tid & 31) * 4;
#pragma unroll
                for (int rr = 0; rr < 4; rr++) {
                    int d = dr + rr * 16;
                    *(float4*)&sCB[d][dc] = *(const float4*)(CBbase + (size_t)(dh * 64 + d) * 128 + dc);
                }
                int lr = tid >> 3, c0 = (tid & 7) * 8;
                bool val = lr < nvalid;
                size_t gb = ((size_t)(b * TT + t0 + lr)) * IN + h * DHd + dh * 64 + c0;
                float4 qv0 = val ? *(const float4*)(qq + gb)     : make_float4(0.f,0.f,0.f,0.f);
                float4 qv1 = val ? *(const float4*)(qq + gb + 4) : make_float4(0.f,0.f,0.f,0.f);
                *(float4*)&Qh2[lr][c0]     = qv0;
                *(float4*)&Qh2[lr][c0 + 4] = qv1;
            }
            __syncthreads();
            for (int dd = 0; dd < 64; dd++) {
                float cbv = sCB[dd][e];
#pragma unroll
                for (int r = 0; r < 16; r++) acc[r] += Qh2[rg + r][dd] * cbv;
            }
            __syncthreads();
        }
#pragma unroll
        for (int r = 0; r < 16; r++) acc[r] *= sWr[rg + r];
    }

    // ---- Phase 1: S = Q K^T; weights -> sD; qnb
    float qnb = 0.f;
    {
        float (*Qh)[68] = (float(*)[68])scr;
        float (*Kh)[68] = (float(*)[68])(scr + 64 * 68);
        int j = tid & 63, ig = (tid >> 6) * 8;   // 8 groups x 8 rows
        float accS[8];
#pragma unroll
        for (int i = 0; i < 8; i++) accS[i] = 0.f;
        for (int dh = 0; dh < 2; dh++) {
            {
                int lr = tid >> 3, c0 = (tid & 7) * 8;
                bool val = lr < nvalid;
                size_t gb = ((size_t)(b * TT + t0 + lr)) * IN + h * DHd + dh * 64 + c0;
                float4 qv0 = val ? *(const float4*)(qq + gb)     : make_float4(0.f,0.f,0.f,0.f);
                float4 qv1 = val ? *(const float4*)(qq + gb + 4) : make_float4(0.f,0.f,0.f,0.f);
                float4 kv0 = val ? *(const float4*)(kk + gb)     : make_float4(0.f,0.f,0.f,0.f);
                float4 kv1 = val ? *(const float4*)(kk + gb + 4) : make_float4(0.f,0.f,0.f,0.f);
                *(float4*)&Qh[lr][c0]     = qv0;
                *(float4*)&Qh[lr][c0 + 4] = qv1;
                *(float4*)&Kh[lr][c0]     = kv0;
                *(float4*)&Kh[lr][c0 + 4] = kv1;
            }
            __syncthreads();
#pragma unroll
            for (int d4 = 0; d4 < 16; d4++) {
                float4 kf = *(const float4*)&Kh[j][d4 * 4];
#pragma unroll
                for (int i = 0; i < 8; i++) {
                    float4 qf = *(const float4*)&Qh[ig + i][d4 * 4];
                    accS[i] += qf.x * kf.x + qf.y * kf.y + qf.z * kf.z + qf.w * kf.w;
                }
            }
            if (tid < 64) {
                for (int d = 0; d < 64; d++) qnb += Qh[tid][d] * sNb[dh * 64 + d];
            }
            __syncthreads();
        }
        float Gj = sG[j];
#pragma unroll
        for (int i = 0; i < 8; i++) {
            int irow = ig + i;
            float w = (j <= irow) ? __expf(Gj - sM[irow]) : 0.f;
            sD[irow][j] = accS[i] * w;
        }
    }
    __syncthreads();

    // ---- Phase 2: denominators
    if (tid < 64) {
        float s = 0.f;
        for (int jj = 0; jj < 64; jj++) s += sD[tid][jj];
        float den = s + sWr[tid] * qnb;
        sInv[tid] = 1.f / fmaxf(fabsf(den), 1.f);
    }
    __syncthreads();

    // ---- Phase 3: intra H += D @ V
    {
        float (*sV)[128] = (float(*)[128])scr;
        int lrow = tid >> 5, lcol = (tid & 31) * 4;
#pragma unroll
        for (int rr = 0; rr < 4; rr++) {
            int r = lrow + rr * 16;
            float4 vvv = make_float4(0.f,0.f,0.f,0.f);
            if (r < nvalid) {
                size_t gb = ((size_t)(b * TT + t0 + r)) * IN + h * DHd + lcol;
                vvv = *(const float4*)(vv + gb);
            }
            *(float4*)&sV[r][lcol] = vvv;
        }
        __syncthreads();
        for (int jj = 0; jj < nvalid; jj++) {
            float vvv = sV[jj][e];
#pragma unroll
            for (int r = 0; r < 16; r++) acc[r] += sD[rg + r][jj] * vvv;
        }
    }

    // ---- store
#pragma unroll
    for (int r = 0; r < 16; r++) {
        int irow = rg + r;
        if (irow < nvalid)
            hs[((size_t)(b * TT + t0 + irow)) * IN + h * DHd + e] = acc[r] * sInv[irow];
    }
}

// ---------------------------------------------------------------- per-head norm * hn_s * silu(z)
__global__ __launch_bounds__(64) void headnorm_kernel(const float* __restrict__ hs,
                                                      const float* __restrict__ hn,
                                                      const float* __restrict__ up,
                                                      float* __restrict__ out) {
    int idx = blockIdx.x;
    int h = idx & 7, bt = idx >> 3;
    int tid = threadIdx.x;
    size_t base = (size_t)bt * IN + h * DHd;
    float x0 = hs[base + tid], x1 = hs[base + 64 + tid];
    float sum = x0 + x1, sq = x0 * x0 + x1 * x1;
#pragma unroll
    for (int o = 32; o > 0; o >>= 1) { sum += __shfl_xor(sum, o); sq += __shfl_xor(sq, o); }
    float mu = sum / DHd, var = sq / DHd - mu * mu, inv = rsqrtf(var + EPSV);
    size_t zb = (size_t)bt * (2 * IN) + IN + h * DHd;
    out[base + tid]      = (x0 - mu) * inv * hn[h * DHd + tid]      * siluf(up[zb + tid]);
    out[base + 64 + tid] = (x1 - mu) * inv * hn[h * DHd + 64 + tid] * siluf(up[zb + 64 + tid]);
}

// ---------------------------------------------------------------- final classifier head
__global__ __launch_bounds__(256) void classifier_kernel(const float* __restrict__ hbuf,
                                                         const float* __restrict__ s, const float* __restrict__ bb,
                                                         const float* __restrict__ fw, const float* __restrict__ fb,
                                                         float* __restrict__ out) {
    int b = blockIdx.x, tid = threadIdx.x;
    const float* r = hbuf + ((size_t)b * TT + TT - 1) * Dm;
    __shared__ float vbuf[Dm];
    __shared__ float s1[4], s2[4];
    float x0 = r[tid], x1 = r[tid + 256];
    float sum = x0 + x1, sq = x0 * x0 + x1 * x1;
#pragma unroll
    for (int o = 32; o > 0; o >>= 1) { sum += __shfl_xor(sum, o); sq += __shfl_xor(sq, o); }
    if ((tid & 63) == 0) { s1[tid >> 6] = sum; s2[tid >> 6] = sq; }
    __syncthreads();
    sum = s1[0] + s1[1] + s1[2] + s1[3];
    sq  = s2[0] + s2[1] + s2[2] + s2[3];
    float mu = sum / Dm, var = sq / Dm - mu * mu, inv = rsqrtf(var + EPSV);
    float n0 = (x0 - mu) * inv * s[tid] + bb[tid];
    float n1 = (x1 - mu) * inv * s[tid + 256] + bb[tid + 256];
    vbuf[tid] = fmaxf(n0, 0.f);
    vbuf[tid + 256] = fmaxf(n1, 0.f);
    __syncthreads();
    for (int j = tid; j < NCc; j += 256) {
        float acc = fb[j];
        for (int kk = 0; kk < Dm; kk++) acc += vbuf[kk] * fw[kk * NCc + j];
        out[b * NCc + j] = acc;
    }
}

// ---------------------------------------------------------------- launch
extern "C" void kernel_launch(void* const* d_in, const int* in_sizes, int n_in,
                              void* d_out, int out_size, void* d_ws, size_t ws_size,
                              hipStream_t stream) {
    const float* x      = (const float*)d_in[0];
    const float* cls    = (const float*)d_in[1];
    const float* ln_s   = (const float*)d_in[2];
    const float* ln_b   = (const float*)d_in[3];
    const float* w_up   = (const float*)d_in[4];
    const float* b_up   = (const float*)d_in[5];
    const float* conv_k = (const float*)d_in[6];
    const float* conv_b = (const float*)d_in[7];
    const float* w_q    = (const float*)d_in[8];
    const float* w_k    = (const float*)d_in[9];
    const float* w_v    = (const float*)d_in[10];
    const float* w_ig   = (const float*)d_in[11];
    const float* b_ig   = (const float*)d_in[12];
    const float* w_fg   = (const float*)d_in[13];
    const float* b_fg   = (const float*)d_in[14];
    const float* hn_s   = (const float*)d_in[15];
    const float* w_down = (const float*)d_in[16];
    const float* b_down = (const float*)d_in[17];
    const float* fcls   = (const float*)d_in[18];
    const float* fclb   = (const float*)d_in[19];
    const float* fc_w   = (const float*)d_in[20];
    const float* fc_b   = (const float*)d_in[21];
    float* out = (float*)d_out;

    float* ws = (float*)d_ws;
    size_t off = 0;
    float* f_h  = ws + off; off += (size_t)ROWS * Dm;
    float* f_xn = ws + off; off += (size_t)ROWS * Dm;
    float* f_up = ws + off; off += (size_t)ROWS * 2 * IN;
    float* f_xc = ws + off; off += (size_t)ROWS * IN;
    float* f_q  = ws + off; off += (size_t)ROWS * IN;
    float* f_k  = ws + off; off += (size_t)ROWS * IN;
    float* f_v  = ws + off; off += (size_t)ROWS * IN;
    float* f_hs = ws + off; off += (size_t)ROWS * IN;
    float* f_ip = ws + off; off += (size_t)ROWS * NHh;
    float* f_fp = ws + off; off += (size_t)ROWS * NHh;
    float* g_G  = ws + off; off += 32 * TT;
    float* g_M  = ws + off; off += 32 * TT;
    float* g_Mb = ws + off; off += 32 * NCH;
    float* g_De = ws + off; off += 32 * NCH;
    float* g_P  = ws + off; off += (size_t)NCH * 32 * DHd * DHd;
    float* g_nP = ws + off; off += (size_t)NCH * 32 * DHd;

    const float kscale = 0.08838834764831845f; // DH^-0.5

    concat_kernel<<<(ROWS * Dm + 255) / 256, 256, 0, stream>>>(x, cls, f_h);

    for (int blk = 0; blk < 2; blk++) {
        const float* p_ln_s = ln_s + blk * Dm;
        const float* p_ln_b = ln_b + blk * Dm;
        const float* p_wup  = w_up + (size_t)blk * Dm * 2 * IN;
        const float* p_bup  = b_up + (size_t)blk * 2 * IN;
        const float* p_ck   = conv_k + (size_t)blk * IN * KK;
        const float* p_cb   = conv_b + (size_t)blk * IN;
        const float* p_wq   = w_q + (size_t)blk * IN * IN;
        const float* p_wk   = w_k + (size_t)blk * IN * IN;
        const float* p_wv   = w_v + (size_t)blk * IN * IN;
        const float* p_wig  = w_ig + (size_t)blk * IN * NHh;
        const float* p_big  = b_ig + (size_t)blk * NHh;
        const float* p_wfg  = w_fg + (size_t)blk * IN * NHh;
        const float* p_bfg  = b_fg + (size_t)blk * NHh;
        const float* p_hns  = hn_s + (size_t)blk * NHh * DHd;
        const float* p_wd   = w_down + (size_t)blk * IN * Dm;
        const float* p_bd   = b_down + (size_t)blk * Dm;

        ln_kernel<<<ROWS, 256, 0, stream>>>(f_h, p_ln_s, p_ln_b, f_xn);

        gemm_kernel<<<dim3(2 * IN / 64, (ROWS + 63) / 64), 256, 0, stream>>>(
            f_xn, Dm, p_wup, 2 * IN, p_bup, nullptr, 0, f_up, 2 * IN, ROWS, Dm, 1.f);

        conv_silu_kernel<<<(ROWS * IN + 255) / 256, 256, 0, stream>>>(f_up, p_ck, p_cb, f_xc);

        gemm_kernel<<<dim3(IN / 64, (ROWS + 63) / 64), 256, 0, stream>>>(
            f_xc, IN, p_wq, IN, nullptr, nullptr, 0, f_q, IN, ROWS, IN, 1.f);
        gemm_kernel<<<dim3(IN / 64, (ROWS + 63) / 64), 256, 0, stream>>>(
            f_xc, IN, p_wk, IN, nullptr, nullptr, 0, f_k, IN, ROWS, IN, kscale);
        gemm_kernel<<<dim3(IN / 64, (ROWS + 63) / 64), 256, 0, stream>>>(
            f_up, 2 * IN, p_wv, IN, nullptr, nullptr, 0, f_v, IN, ROWS, IN, 1.f);

        gates_kernel<<<ROWS, 256, 0, stream>>>(f_xc, p_wig, p_big, p_wfg, p_bfg, f_ip, f_fp);

        // chunkwise-parallel mLSTM
        gate_scan_kernel<<<32, 64, 0, stream>>>(f_ip, f_fp, g_G, g_M, g_Mb, g_De);
        chunk_state_kernel<<<dim3(NCH, 32), 256, 0, stream>>>(f_k, f_v, g_G, g_Mb, g_P, g_nP);
        chunk_combine_kernel<<<32 * 64, 256, 0, stream>>>(g_P, g_De);
        n_combine_kernel<<<16, 256, 0, stream>>>(g_nP, g_De);
        chunk_out_kernel<<<dim3(NCH, 32), 512, 0, stream>>>(f_q, f_k, f_v, g_G, g_M, g_Mb,
                                                            g_P, g_nP, f_hs);

        headnorm_kernel<<<ROWS * NHh, 64, 0, stream>>>(f_hs, p_hns, f_up, f_xc);

        gemm_kernel<<<dim3(Dm / 64, (ROWS + 63) / 64), 256, 0, stream>>>(
            f_xc, IN, p_wd, Dm, p_bd, f_h, Dm, f_h, Dm, ROWS, IN, 1.f);
    }

    classifier_kernel<<<Bsz, 256, 0, stream>>>(f_h, fcls, fclb, fc_w, fc_b, out);
}

// Round 7
// 1573.780 us; speedup vs baseline: 2.0323x; 1.1855x over previous
//
#include <hip/hip_runtime.h>

// ---------------------------------------------------------------- constants
#define EPSV 1e-5f
constexpr int Bsz = 4, T0 = 512, Dm = 512, TT = 513, NHh = 8, KK = 4;
constexpr int IN = 1024, DHd = 128, NCc = 1000;
constexpr int ROWS = Bsz * TT; // 2052
constexpr int NCH = 9;         // chunks of 64: 8*64 + 1 = 513

typedef __attribute__((ext_vector_type(8))) short bf16x8;
typedef __attribute__((ext_vector_type(4))) float f32x4;
typedef __attribute__((ext_vector_type(4))) unsigned short ushort4v;

__device__ __forceinline__ float siluf(float x) { return x / (1.f + __expf(-x)); }
__device__ __forceinline__ unsigned short f2bf(float f) {
    unsigned int u = __float_as_uint(f);
    u = (u + 0x7FFFu + ((u >> 16) & 1u)) >> 16;
    return (unsigned short)u;
}

// ---------------------------------------------------------------- concat x + cls
__global__ __launch_bounds__(256) void concat_kernel(const float* __restrict__ x,
                                                     const float* __restrict__ cls,
                                                     float* __restrict__ h) {
    int idx = blockIdx.x * 256 + threadIdx.x;
    if (idx >= Bsz * TT * Dm) return;
    int d = idx & (Dm - 1);
    int bt = idx >> 9;
    int t = bt % TT, b = bt / TT;
    h[idx] = (t < T0) ? x[((size_t)(b * T0 + t)) * Dm + d] : cls[d];
}

// ---------------------------------------------------------------- LayerNorm rows of D=512
__global__ __launch_bounds__(256) void ln_kernel(const float* __restrict__ in,
                                                 const float* __restrict__ s,
                                                 const float* __restrict__ bb,
                                                 float* __restrict__ out) {
    int row = blockIdx.x, tid = threadIdx.x;
    const float* r = in + (size_t)row * Dm;
    __shared__ float s1[4], s2[4];
    float x0 = r[tid], x1 = r[tid + 256];
    float sum = x0 + x1, sq = x0 * x0 + x1 * x1;
#pragma unroll
    for (int o = 32; o > 0; o >>= 1) { sum += __shfl_xor(sum, o); sq += __shfl_xor(sq, o); }
    if ((tid & 63) == 0) { s1[tid >> 6] = sum; s2[tid >> 6] = sq; }
    __syncthreads();
    sum = s1[0] + s1[1] + s1[2] + s1[3];
    sq  = s2[0] + s2[1] + s2[2] + s2[3];
    float mu = sum / Dm, var = sq / Dm - mu * mu, inv = rsqrtf(var + EPSV);
    out[(size_t)row * Dm + tid]       = (x0 - mu) * inv * s[tid] + bb[tid];
    out[(size_t)row * Dm + tid + 256] = (x1 - mu) * inv * s[tid + 256] + bb[tid + 256];
}

// ---------------------------------------------------------------- MFMA bf16 GEMM
// C[M,N] = scale*(A@W) (+bias) (+resid).  A f32 MxK (lda), W f32 KxN (ldw).
// 128x128 tile, BK=32, 4 waves (2x2), per-wave 4x4 mfma_f32_16x16x32_bf16.
// LDS rows padded to 40 shorts (80B = 20-bank stride -> free 2-way conflicts).
__global__ __launch_bounds__(256) void gemm_mfma_kernel(const float* __restrict__ A, int lda,
                                                        const float* __restrict__ W, int ldw,
                                                        const float* __restrict__ bias,
                                                        const float* __restrict__ resid, int ldr,
                                                        float* __restrict__ Cout, int ldc,
                                                        int M, int Kd, float scale) {
    __shared__ __align__(16) unsigned short As[128][40];
    __shared__ __align__(16) unsigned short Bs[128][40];   // Bs[n][k]
    int tid = threadIdx.x;
    int m0 = blockIdx.y * 128, n0 = blockIdx.x * 128;
    int wave = tid >> 6, lane = tid & 63;
    int wm = (wave >> 1) * 64, wn = (wave & 1) * 64;
    int lrow = lane & 15, lquad = lane >> 4;

    f32x4 acc[4][4];
#pragma unroll
    for (int i = 0; i < 4; i++)
#pragma unroll
        for (int j = 0; j < 4; j++)
#pragma unroll
            for (int r = 0; r < 4; r++) acc[i][j][r] = 0.f;

    int am = tid >> 1, ak = (tid & 1) * 16;   // A staging: 128 rows x two 16-col halves
    int bn = tid & 127, bk = (tid >> 7) * 16; // B staging: 128 cols x two 16-row halves

    for (int k0 = 0; k0 < Kd; k0 += 32) {
        // ---- stage A (f32 -> bf16)
        {
            int gm = m0 + am;
            float4 a0, a1, a2, a3;
            if (gm < M) {
                const float4* ap = (const float4*)(A + (size_t)gm * lda + k0 + ak);
                a0 = ap[0]; a1 = ap[1]; a2 = ap[2]; a3 = ap[3];
            } else {
                a0 = a1 = a2 = a3 = make_float4(0.f, 0.f, 0.f, 0.f);
            }
            ushort4v t0 = {f2bf(a0.x), f2bf(a0.y), f2bf(a0.z), f2bf(a0.w)};
            ushort4v t1 = {f2bf(a1.x), f2bf(a1.y), f2bf(a1.z), f2bf(a1.w)};
            ushort4v t2 = {f2bf(a2.x), f2bf(a2.y), f2bf(a2.z), f2bf(a2.w)};
            ushort4v t3 = {f2bf(a3.x), f2bf(a3.y), f2bf(a3.z), f2bf(a3.w)};
            *(ushort4v*)&As[am][ak + 0]  = t0;
            *(ushort4v*)&As[am][ak + 4]  = t1;
            *(ushort4v*)&As[am][ak + 8]  = t2;
            *(ushort4v*)&As[am][ak + 12] = t3;
        }
        // ---- stage B transposed (f32 -> bf16), Bs[n][k]
        {
            const float* wp = W + (size_t)(k0 + bk) * ldw + n0 + bn;
            unsigned short tmp[16];
#pragma unroll
            for (int j = 0; j < 16; j++) tmp[j] = f2bf(wp[(size_t)j * ldw]);
#pragma unroll
            for (int j4 = 0; j4 < 4; j4++) {
                ushort4v tv = {tmp[j4 * 4], tmp[j4 * 4 + 1], tmp[j4 * 4 + 2], tmp[j4 * 4 + 3]};
                *(ushort4v*)&Bs[bn][bk + j4 * 4] = tv;
            }
        }
        __syncthreads();
        // ---- fragments + MFMA
        bf16x8 afr[4], bfr[4];
#pragma unroll
        for (int mt = 0; mt < 4; mt++)
            afr[mt] = *(const bf16x8*)&As[wm + mt * 16 + lrow][lquad * 8];
#pragma unroll
        for (int nt = 0; nt < 4; nt++)
            bfr[nt] = *(const bf16x8*)&Bs[wn + nt * 16 + lrow][lquad * 8];
#pragma unroll
        for (int mt = 0; mt < 4; mt++)
#pragma unroll
            for (int nt = 0; nt < 4; nt++)
                acc[mt][nt] = __builtin_amdgcn_mfma_f32_16x16x32_bf16(
                    afr[mt], bfr[nt], acc[mt][nt], 0, 0, 0);
        __syncthreads();
    }

    // ---- epilogue: C/D layout col=lane&15, row=lquad*4+r
#pragma unroll
    for (int mt = 0; mt < 4; mt++) {
#pragma unroll
        for (int r = 0; r < 4; r++) {
            int gm = m0 + wm + mt * 16 + lquad * 4 + r;
            if (gm >= M) continue;
#pragma unroll
            for (int nt = 0; nt < 4; nt++) {
                int gn = n0 + wn + nt * 16 + lrow;
                float v = acc[mt][nt][r] * scale;
                if (bias) v += bias[gn];
                if (resid) v += resid[(size_t)gm * ldr + gn];
                Cout[(size_t)gm * ldc + gn] = v;
            }
        }
    }
}

// ---------------------------------------------------------------- causal depthwise conv (K=4) + SiLU
__global__ __launch_bounds__(256) void conv_silu_kernel(const float* __restrict__ up,
                                                        const float* __restrict__ ck,
                                                        const float* __restrict__ cb,
                                                        float* __restrict__ xc) {
    int idx = blockIdx.x * 256 + threadIdx.x;
    if (idx >= ROWS * IN) return;
    int c = idx & (IN - 1);
    int bt = idx >> 10;
    int t = bt % TT, b = bt / TT;
    float acc = cb[c];
#pragma unroll
    for (int j = 0; j < KK; j++) {
        int tt = t - (KK - 1) + j;
        if (tt >= 0) acc += up[((size_t)(b * TT + tt)) * (2 * IN) + c] * ck[c * KK + j];
    }
    xc[idx] = siluf(acc);
}

// ---------------------------------------------------------------- input/forget gate projections
__global__ __launch_bounds__(256) void gates_kernel(const float* __restrict__ xc,
                                                    const float* __restrict__ wig, const float* __restrict__ big,
                                                    const float* __restrict__ wfg, const float* __restrict__ bfg,
                                                    float* __restrict__ ip, float* __restrict__ fp) {
    int row = blockIdx.x, tid = threadIdx.x;
    __shared__ float sx[IN];
    for (int i = tid; i < IN; i += 256) sx[i] = xc[(size_t)row * IN + i];
    __syncthreads();
    int g = tid >> 4, l = tid & 15;
    const float* w = (g < 8) ? wig : wfg;
    int h = g & 7;
    float acc = 0.f;
    for (int kk = l; kk < IN; kk += 16) acc += sx[kk] * w[kk * NHh + h];
#pragma unroll
    for (int o = 8; o > 0; o >>= 1) acc += __shfl_down(acc, o, 16);
    if (l == 0) {
        if (g < 8) ip[(size_t)row * NHh + h] = acc + big[h];
        else       fp[(size_t)row * NHh + h] = acc + bfg[h];
    }
}

// ---------------------------------------------------------------- chunkwise mLSTM
// Kernel A (wave-parallel prefix scan): one wave per chain.
__global__ __launch_bounds__(64) void gate_scan_kernel(const float* __restrict__ ip,
        const float* __restrict__ fp, float* __restrict__ gG, float* __restrict__ gM,
        float* __restrict__ gMb, float* __restrict__ gDec) {
    constexpr int PER = 9; // 64*9 = 576 >= 513
    int chain = blockIdx.x;
    int b = chain >> 3, h = chain & 7;
    int lane = threadIdx.x;
    int tbase = lane * PER;
    float lcs[PER];
    float gi[PER];
    float csum = 0.f;
#pragma unroll
    for (int i = 0; i < PER; i++) {
        int t = tbase + i;
        float fpv = 0.f, ipv = 0.f;
        if (t < TT) {
            size_t gidx = (size_t)(b * TT + t) * NHh + h;
            fpv = fp[gidx]; ipv = ip[gidx];
        }
        float flv = (fpv >= 0.f) ? -log1pf(__expf(-fpv)) : (fpv - log1pf(__expf(fpv)));
        if (t >= TT) flv = 0.f;
        csum += flv;
        lcs[i] = csum;
        gi[i] = ipv;
    }
    float ps = csum;
#pragma unroll
    for (int o = 1; o < 64; o <<= 1) {
        float v = __shfl_up(ps, o);
        if (lane >= o) ps += v;
    }
    float Fexcl = ps - csum;
    float G[PER];
    float cmax = -1e30f;
#pragma unroll
    for (int i = 0; i < PER; i++) {
        int t = tbase + i;
        G[i] = (t < TT) ? (gi[i] - (Fexcl + lcs[i])) : -1e30f;
        cmax = fmaxf(cmax, G[i]);
        lcs[i] = cmax;
    }
    float pm = cmax;
#pragma unroll
    for (int o = 1; o < 64; o <<= 1) {
        float v = __shfl_up(pm, o);
        if (lane >= o) pm = fmaxf(pm, v);
    }
    float Me = __shfl_up(pm, 1);
    if (lane == 0) Me = -1e30f;
    __shared__ float sMb[NCH];
#pragma unroll
    for (int i = 0; i < PER; i++) {
        int t = tbase + i;
        if (t < TT) {
            float Mt = fmaxf(0.f, fmaxf(Me, lcs[i]));
            gG[chain * TT + t] = G[i];
            gM[chain * TT + t] = Mt;
            if (((t & 63) == 63) || t == TT - 1) sMb[t >> 6] = Mt;
        }
    }
    __syncthreads();
    if (lane < NCH) {
        float Mb = sMb[lane];
        float Mbp = (lane == 0) ? 0.f : sMb[lane - 1];
        gMb[chain * NCH + lane] = Mb;
        gDec[chain * NCH + lane] = __expf(Mbp - Mb);
    }
}

// Kernel B1: per-chunk local state P[d][e] = sum_j exp(G_j - Mb_c) k_j[d] v_j[e]
__global__ __launch_bounds__(256) void chunk_state_kernel(const float* __restrict__ kk,
        const float* __restrict__ vv, const float* __restrict__ gG,
        const float* __restrict__ gMb, float* __restrict__ P, float* __restrict__ nP) {
    int c = blockIdx.x, chain = blockIdx.y;
    int b = chain >> 3, h = chain & 7;
    int t0 = c * 64;
    int nvalid = min(64, TT - t0);
    __shared__ float sK[32][128], sV[32][128], sw[64];
    int tid = threadIdx.x;
    if (tid < 64) {
        float Mb = gMb[chain * NCH + c];
        sw[tid] = (tid < nvalid) ? __expf(gG[chain * TT + t0 + tid] - Mb) : 0.f;
    }
    int e = tid & 127, dg = (tid >> 7) * 64;
    float4 acc[16];
#pragma unroll
    for (int i = 0; i < 16; i++) acc[i] = make_float4(0.f, 0.f, 0.f, 0.f);
    float na = 0.f;
    for (int jh = 0; jh < 2; jh++) {
        int lrow = tid >> 5, lcol = (tid & 31) * 4;
        for (int rr = 0; rr < 4; rr++) {
            int r = lrow + rr * 8;
            int gr = jh * 32 + r;
            float4 kv = make_float4(0.f,0.f,0.f,0.f), vvv = kv;
            if (gr < nvalid) {
                size_t gb = ((size_t)(b * TT + t0 + gr)) * IN + h * DHd + lcol;
                kv = *(const float4*)(kk + gb);
                vvv = *(const float4*)(vv + gb);
            }
            *(float4*)&sK[r][lcol] = kv;
            *(float4*)&sV[r][lcol] = vvv;
        }
        __syncthreads();
        int jmax = min(32, nvalid - jh * 32);
        for (int j = 0; j < jmax; j++) {
            float wvj = sw[jh * 32 + j] * sV[j][e];
            const float4* kr = (const float4*)&sK[j][dg];
#pragma unroll
            for (int d4 = 0; d4 < 16; d4++) {
                float4 kq = kr[d4];
                acc[d4].x += kq.x * wvj; acc[d4].y += kq.y * wvj;
                acc[d4].z += kq.z * wvj; acc[d4].w += kq.w * wvj;
            }
        }
        if (tid < 128) {
            for (int j = 0; j < jmax; j++) na += sw[jh * 32 + j] * sK[j][tid];
        }
        __syncthreads();
    }
    float* Pbase = P + (((size_t)(c * 32 + chain)) << 14);
#pragma unroll
    for (int d4 = 0; d4 < 16; d4++) {
        Pbase[(size_t)(dg + d4 * 4 + 0) * 128 + e] = acc[d4].x;
        Pbase[(size_t)(dg + d4 * 4 + 1) * 128 + e] = acc[d4].y;
        Pbase[(size_t)(dg + d4 * 4 + 2) * 128 + e] = acc[d4].z;
        Pbase[(size_t)(dg + d4 * 4 + 3) * 128 + e] = acc[d4].w;
    }
    if (tid < 128) nP[(size_t)(c * 32 + chain) * 128 + tid] = na;
}

// Kernel B2: in-place exclusive combine over chunks.
__global__ __launch_bounds__(256) void chunk_combine_kernel(float* __restrict__ P,
        const float* __restrict__ gDec) {
    int chain = blockIdx.x >> 6;
    int idx = (blockIdx.x & 63) * 256 + threadIdx.x;
    float run = 0.f;
    for (int c = 0; c < NCH; c++) {
        size_t a = (((size_t)(c * 32 + chain)) << 14) + idx;
        float tmp = P[a];
        P[a] = run;
        run = run * gDec[chain * NCH + c] + tmp;
    }
}

__global__ __launch_bounds__(256) void n_combine_kernel(float* __restrict__ nP,
        const float* __restrict__ gDec) {
    int gidx = blockIdx.x * 256 + threadIdx.x;
    int chain = gidx >> 7, d = gidx & 127;
    float run = 0.f;
    for (int c = 0; c < NCH; c++) {
        size_t a = (size_t)(c * 32 + chain) * 128 + d;
        float tmp = nP[a];
        nP[a] = run;
        run = run * gDec[chain * NCH + c] + tmp;
    }
}

// Kernel C: per-chunk outputs. __launch_bounds__(512, 2): 2 waves/EU min ->
// 256-VGPR budget -> the allocator stops capping at 128 + spilling (R6: 450MB
// phantom WRITE_SIZE from scratch).
__global__ __launch_bounds__(512, 2) void chunk_out_kernel(const float* __restrict__ qq,
        const float* __restrict__ kk, const float* __restrict__ vv,
        const float* __restrict__ gG, const float* __restrict__ gM,
        const float* __restrict__ gMb, const float* __restrict__ P,
        const float* __restrict__ nP, float* __restrict__ hs) {
    int c = blockIdx.x, chain = blockIdx.y;
    int b = chain >> 3, h = chain & 7;
    int t0 = c * 64;
    int nvalid = min(64, TT - t0);
    __shared__ float smem[13248];
    float* sG  = smem;          // 64
    float* sM  = smem + 64;     // 64
    float* sWr = smem + 128;    // 64
    float* sInv= smem + 192;    // 64
    float* sNb = smem + 256;    // 128
    float (*sD)[65] = (float(*)[65])(smem + 384);          // 64x65
    float* scr = smem + 384 + 64 * 65;                     // 8704 floats scratch
    int tid = threadIdx.x;

    float Mbprev = (c > 0) ? gMb[chain * NCH + c - 1] : 0.f;
    if (tid < 64) {
        bool val = tid < nvalid;
        sG[tid] = val ? gG[chain * TT + t0 + tid] : -1e30f;
        float Mv = val ? gM[chain * TT + t0 + tid] : 1e30f;
        sM[tid] = Mv;
        sWr[tid] = val ? __expf(Mbprev - Mv) : 0.f;
    }
    if (tid >= 128 && tid < 256) sNb[tid - 128] = nP[(size_t)(c * 32 + chain) * 128 + (tid - 128)];
    __syncthreads();

    int e = tid & 127, rg = (tid >> 7) * 16;   // 4 row-groups x 16 rows
    float acc[16];
#pragma unroll
    for (int r = 0; r < 16; r++) acc[r] = 0.f;

    // ---- Phase 0: inter H = Q @ CB
    {
        float (*sCB)[128] = (float(*)[128])(smem + 384);          // 64x128
        float (*Qh2)[68]  = (float(*)[68])(smem + 384 + 64*128);  // 64x68
        const float* CBbase = P + (((size_t)(c * 32 + chain)) << 14);
        for (int dh = 0; dh < 2; dh++) {
            {
                int dr = tid >> 5, dc = (tid & 31) * 4;
#pragma unroll
                for (int rr = 0; rr < 4; rr++) {
                    int d = dr + rr * 16;
                    *(float4*)&sCB[d][dc] = *(const float4*)(CBbase + (size_t)(dh * 64 + d) * 128 + dc);
                }
                int lr = tid >> 3, c0 = (tid & 7) * 8;
                bool val = lr < nvalid;
                size_t gb = ((size_t)(b * TT + t0 + lr)) * IN + h * DHd + dh * 64 + c0;
                float4 qv0 = val ? *(const float4*)(qq + gb)     : make_float4(0.f,0.f,0.f,0.f);
                float4 qv1 = val ? *(const float4*)(qq + gb + 4) : make_float4(0.f,0.f,0.f,0.f);
                *(float4*)&Qh2[lr][c0]     = qv0;
                *(float4*)&Qh2[lr][c0 + 4] = qv1;
            }
            __syncthreads();
            for (int dd = 0; dd < 64; dd++) {
                float cbv = sCB[dd][e];
#pragma unroll
                for (int r = 0; r < 16; r++) acc[r] += Qh2[rg + r][dd] * cbv;
            }
            __syncthreads();
        }
#pragma unroll
        for (int r = 0; r < 16; r++) acc[r] *= sWr[rg + r];
    }

    // ---- Phase 1: S = Q K^T; weights -> sD; qnb
    float qnb = 0.f;
    {
        float (*Qh)[68] = (float(*)[68])scr;
        float (*Kh)[68] = (float(*)[68])(scr + 64 * 68);
        int j = tid & 63, ig = (tid >> 6) * 8;
        float accS[8];
#pragma unroll
        for (int i = 0; i < 8; i++) accS[i] = 0.f;
        for (int dh = 0; dh < 2; dh++) {
            {
                int lr = tid >> 3, c0 = (tid & 7) * 8;
                bool val = lr < nvalid;
                size_t gb = ((size_t)(b * TT + t0 + lr)) * IN + h * DHd + dh * 64 + c0;
                float4 qv0 = val ? *(const float4*)(qq + gb)     : make_float4(0.f,0.f,0.f,0.f);
                float4 qv1 = val ? *(const float4*)(qq + gb + 4) : make_float4(0.f,0.f,0.f,0.f);
                float4 kv0 = val ? *(const float4*)(kk + gb)     : make_float4(0.f,0.f,0.f,0.f);
                float4 kv1 = val ? *(const float4*)(kk + gb + 4) : make_float4(0.f,0.f,0.f,0.f);
                *(float4*)&Qh[lr][c0]     = qv0;
                *(float4*)&Qh[lr][c0 + 4] = qv1;
                *(float4*)&Kh[lr][c0]     = kv0;
                *(float4*)&Kh[lr][c0 + 4] = kv1;
            }
            __syncthreads();
#pragma unroll
            for (int d4 = 0; d4 < 16; d4++) {
                float4 kf = *(const float4*)&Kh[j][d4 * 4];
#pragma unroll
                for (int i = 0; i < 8; i++) {
                    float4 qf = *(const float4*)&Qh[ig + i][d4 * 4];
                    accS[i] += qf.x * kf.x + qf.y * kf.y + qf.z * kf.z + qf.w * kf.w;
                }
            }
            if (tid < 64) {
                for (int d = 0; d < 64; d++) qnb += Qh[tid][d] * sNb[dh * 64 + d];
            }
            __syncthreads();
        }
        float Gj = sG[j];
#pragma unroll
        for (int i = 0; i < 8; i++) {
            int irow = ig + i;
            float w = (j <= irow) ? __expf(Gj - sM[irow]) : 0.f;
            sD[irow][j] = accS[i] * w;
        }
    }
    __syncthreads();

    // ---- Phase 2: denominators
    if (tid < 64) {
        float s = 0.f;
        for (int jj = 0; jj < 64; jj++) s += sD[tid][jj];
        float den = s + sWr[tid] * qnb;
        sInv[tid] = 1.f / fmaxf(fabsf(den), 1.f);
    }
    __syncthreads();

    // ---- Phase 3: intra H += D @ V
    {
        float (*sV)[128] = (float(*)[128])scr;
        int lrow = tid >> 5, lcol = (tid & 31) * 4;
#pragma unroll
        for (int rr = 0; rr < 4; rr++) {
            int r = lrow + rr * 16;
            float4 vvv = make_float4(0.f,0.f,0.f,0.f);
            if (r < nvalid) {
                size_t gb = ((size_t)(b * TT + t0 + r)) * IN + h * DHd + lcol;
                vvv = *(const float4*)(vv + gb);
            }
            *(float4*)&sV[r][lcol] = vvv;
        }
        __syncthreads();
        for (int jj = 0; jj < nvalid; jj++) {
            float vvv = sV[jj][e];
#pragma unroll
            for (int r = 0; r < 16; r++) acc[r] += sD[rg + r][jj] * vvv;
        }
    }

    // ---- store
#pragma unroll
    for (int r = 0; r < 16; r++) {
        int irow = rg + r;
        if (irow < nvalid)
            hs[((size_t)(b * TT + t0 + irow)) * IN + h * DHd + e] = acc[r] * sInv[irow];
    }
}

// ---------------------------------------------------------------- per-head norm * hn_s * silu(z)
__global__ __launch_bounds__(64) void headnorm_kernel(const float* __restrict__ hs,
                                                      const float* __restrict__ hn,
                                                      const float* __restrict__ up,
                                                      float* __restrict__ out) {
    int idx = blockIdx.x;
    int h = idx & 7, bt = idx >> 3;
    int tid = threadIdx.x;
    size_t base = (size_t)bt * IN + h * DHd;
    float x0 = hs[base + tid], x1 = hs[base + 64 + tid];
    float sum = x0 + x1, sq = x0 * x0 + x1 * x1;
#pragma unroll
    for (int o = 32; o > 0; o >>= 1) { sum += __shfl_xor(sum, o); sq += __shfl_xor(sq, o); }
    float mu = sum / DHd, var = sq / DHd - mu * mu, inv = rsqrtf(var + EPSV);
    size_t zb = (size_t)bt * (2 * IN) + IN + h * DHd;
    out[base + tid]      = (x0 - mu) * inv * hn[h * DHd + tid]      * siluf(up[zb + tid]);
    out[base + 64 + tid] = (x1 - mu) * inv * hn[h * DHd + 64 + tid] * siluf(up[zb + 64 + tid]);
}

// ---------------------------------------------------------------- final classifier head
__global__ __launch_bounds__(256) void classifier_kernel(const float* __restrict__ hbuf,
                                                         const float* __restrict__ s, const float* __restrict__ bb,
                                                         const float* __restrict__ fw, const float* __restrict__ fb,
                                                         float* __restrict__ out) {
    int b = blockIdx.x, tid = threadIdx.x;
    const float* r = hbuf + ((size_t)b * TT + TT - 1) * Dm;
    __shared__ float vbuf[Dm];
    __shared__ float s1[4], s2[4];
    float x0 = r[tid], x1 = r[tid + 256];
    float sum = x0 + x1, sq = x0 * x0 + x1 * x1;
#pragma unroll
    for (int o = 32; o > 0; o >>= 1) { sum += __shfl_xor(sum, o); sq += __shfl_xor(sq, o); }
    if ((tid & 63) == 0) { s1[tid >> 6] = sum; s2[tid >> 6] = sq; }
    __syncthreads();
    sum = s1[0] + s1[1] + s1[2] + s1[3];
    sq  = s2[0] + s2[1] + s2[2] + s2[3];
    float mu = sum / Dm, var = sq / Dm - mu * mu, inv = rsqrtf(var + EPSV);
    float n0 = (x0 - mu) * inv * s[tid] + bb[tid];
    float n1 = (x1 - mu) * inv * s[tid + 256] + bb[tid + 256];
    vbuf[tid] = fmaxf(n0, 0.f);
    vbuf[tid + 256] = fmaxf(n1, 0.f);
    __syncthreads();
    for (int j = tid; j < NCc; j += 256) {
        float acc = fb[j];
        for (int kk = 0; kk < Dm; kk++) acc += vbuf[kk] * fw[kk * NCc + j];
        out[b * NCc + j] = acc;
    }
}

// ---------------------------------------------------------------- launch
extern "C" void kernel_launch(void* const* d_in, const int* in_sizes, int n_in,
                              void* d_out, int out_size, void* d_ws, size_t ws_size,
                              hipStream_t stream) {
    const float* x      = (const float*)d_in[0];
    const float* cls    = (const float*)d_in[1];
    const float* ln_s   = (const float*)d_in[2];
    const float* ln_b   = (const float*)d_in[3];
    const float* w_up   = (const float*)d_in[4];
    const float* b_up   = (const float*)d_in[5];
    const float* conv_k = (const float*)d_in[6];
    const float* conv_b = (const float*)d_in[7];
    const float* w_q    = (const float*)d_in[8];
    const float* w_k    = (const float*)d_in[9];
    const float* w_v    = (const float*)d_in[10];
    const float* w_ig   = (const float*)d_in[11];
    const float* b_ig   = (const float*)d_in[12];
    const float* w_fg   = (const float*)d_in[13];
    const float* b_fg   = (const float*)d_in[14];
    const float* hn_s   = (const float*)d_in[15];
    const float* w_down = (const float*)d_in[16];
    const float* b_down = (const float*)d_in[17];
    const float* fcls   = (const float*)d_in[18];
    const float* fclb   = (const float*)d_in[19];
    const float* fc_w   = (const float*)d_in[20];
    const float* fc_b   = (const float*)d_in[21];
    float* out = (float*)d_out;

    float* ws = (float*)d_ws;
    size_t off = 0;
    float* f_h  = ws + off; off += (size_t)ROWS * Dm;
    float* f_xn = ws + off; off += (size_t)ROWS * Dm;
    float* f_up = ws + off; off += (size_t)ROWS * 2 * IN;
    float* f_xc = ws + off; off += (size_t)ROWS * IN;
    float* f_q  = ws + off; off += (size_t)ROWS * IN;
    float* f_k  = ws + off; off += (size_t)ROWS * IN;
    float* f_v  = ws + off; off += (size_t)ROWS * IN;
    float* f_hs = ws + off; off += (size_t)ROWS * IN;
    float* f_ip = ws + off; off += (size_t)ROWS * NHh;
    float* f_fp = ws + off; off += (size_t)ROWS * NHh;
    float* g_G  = ws + off; off += 32 * TT;
    float* g_M  = ws + off; off += 32 * TT;
    float* g_Mb = ws + off; off += 32 * NCH;
    float* g_De = ws + off; off += 32 * NCH;
    float* g_P  = ws + off; off += (size_t)NCH * 32 * DHd * DHd;
    float* g_nP = ws + off; off += (size_t)NCH * 32 * DHd;

    const float kscale = 0.08838834764831845f; // DH^-0.5
    const int MB = (ROWS + 127) / 128;         // 17

    concat_kernel<<<(ROWS * Dm + 255) / 256, 256, 0, stream>>>(x, cls, f_h);

    for (int blk = 0; blk < 2; blk++) {
        const float* p_ln_s = ln_s + blk * Dm;
        const float* p_ln_b = ln_b + blk * Dm;
        const float* p_wup  = w_up + (size_t)blk * Dm * 2 * IN;
        const float* p_bup  = b_up + (size_t)blk * 2 * IN;
        const float* p_ck   = conv_k + (size_t)blk * IN * KK;
        const float* p_cb   = conv_b + (size_t)blk * IN;
        const float* p_wq   = w_q + (size_t)blk * IN * IN;
        const float* p_wk   = w_k + (size_t)blk * IN * IN;
        const float* p_wv   = w_v + (size_t)blk * IN * IN;
        const float* p_wig  = w_ig + (size_t)blk * IN * NHh;
        const float* p_big  = b_ig + (size_t)blk * NHh;
        const float* p_wfg  = w_fg + (size_t)blk * IN * NHh;
        const float* p_bfg  = b_fg + (size_t)blk * NHh;
        const float* p_hns  = hn_s + (size_t)blk * NHh * DHd;
        const float* p_wd   = w_down + (size_t)blk * IN * Dm;
        const float* p_bd   = b_down + (size_t)blk * Dm;

        ln_kernel<<<ROWS, 256, 0, stream>>>(f_h, p_ln_s, p_ln_b, f_xn);

        gemm_mfma_kernel<<<dim3(2 * IN / 128, MB), 256, 0, stream>>>(
            f_xn, Dm, p_wup, 2 * IN, p_bup, nullptr, 0, f_up, 2 * IN, ROWS, Dm, 1.f);

        conv_silu_kernel<<<(ROWS * IN + 255) / 256, 256, 0, stream>>>(f_up, p_ck, p_cb, f_xc);

        gemm_mfma_kernel<<<dim3(IN / 128, MB), 256, 0, stream>>>(
            f_xc, IN, p_wq, IN, nullptr, nullptr, 0, f_q, IN, ROWS, IN, 1.f);
        gemm_mfma_kernel<<<dim3(IN / 128, MB), 256, 0, stream>>>(
            f_xc, IN, p_wk, IN, nullptr, nullptr, 0, f_k, IN, ROWS, IN, kscale);
        gemm_mfma_kernel<<<dim3(IN / 128, MB), 256, 0, stream>>>(
            f_up, 2 * IN, p_wv, IN, nullptr, nullptr, 0, f_v, IN, ROWS, IN, 1.f);

        gates_kernel<<<ROWS, 256, 0, stream>>>(f_xc, p_wig, p_big, p_wfg, p_bfg, f_ip, f_fp);

        // chunkwise-parallel mLSTM
        gate_scan_kernel<<<32, 64, 0, stream>>>(f_ip, f_fp, g_G, g_M, g_Mb, g_De);
        chunk_state_kernel<<<dim3(NCH, 32), 256, 0, stream>>>(f_k, f_v, g_G, g_Mb, g_P, g_nP);
        chunk_combine_kernel<<<32 * 64, 256, 0, stream>>>(g_P, g_De);
        n_combine_kernel<<<16, 256, 0, stream>>>(g_nP, g_De);
        chunk_out_kernel<<<dim3(NCH, 32), 512, 0, stream>>>(f_q, f_k, f_v, g_G, g_M, g_Mb,
                                                            g_P, g_nP, f_hs);

        headnorm_kernel<<<ROWS * NHh, 64, 0, stream>>>(f_hs, p_hns, f_up, f_xc);

        gemm_mfma_kernel<<<dim3(Dm / 128, MB), 256, 0, stream>>>(
            f_xc, IN, p_wd, Dm, p_bd, f_h, Dm, f_h, Dm, ROWS, IN, 1.f);
    }

    classifier_kernel<<<Bsz, 256, 0, stream>>>(f_h, fcls, fclb, fc_w, fc_b, out);
}

// Round 8
// 1413.943 us; speedup vs baseline: 2.2620x; 1.1130x over previous
//
#include <hip/hip_runtime.h>

// ---------------------------------------------------------------- constants
#define EPSV 1e-5f
constexpr int Bsz = 4, T0 = 512, Dm = 512, TT = 513, NHh = 8, KK = 4;
constexpr int IN = 1024, DHd = 128, NCc = 1000;
constexpr int ROWS = Bsz * TT; // 2052
constexpr int NCH = 9;         // chunks of 64: 8*64 + 1 = 513

typedef __attribute__((ext_vector_type(8))) short bf16x8;
typedef __attribute__((ext_vector_type(4))) float f32x4;
typedef __attribute__((ext_vector_type(4))) unsigned short ushort4v;

__device__ __forceinline__ float siluf(float x) { return x / (1.f + __expf(-x)); }
__device__ __forceinline__ unsigned short f2bf(float f) {
    unsigned int u = __float_as_uint(f);
    u = (u + 0x7FFFu + ((u >> 16) & 1u)) >> 16;
    return (unsigned short)u;
}

// ---------------------------------------------------------------- concat x + cls
__global__ __launch_bounds__(256) void concat_kernel(const float* __restrict__ x,
                                                     const float* __restrict__ cls,
                                                     float* __restrict__ h) {
    int idx = blockIdx.x * 256 + threadIdx.x;
    if (idx >= Bsz * TT * Dm) return;
    int d = idx & (Dm - 1);
    int bt = idx >> 9;
    int t = bt % TT, b = bt / TT;
    h[idx] = (t < T0) ? x[((size_t)(b * T0 + t)) * Dm + d] : cls[d];
}

// ---------------------------------------------------------------- LayerNorm rows of D=512
__global__ __launch_bounds__(256) void ln_kernel(const float* __restrict__ in,
                                                 const float* __restrict__ s,
                                                 const float* __restrict__ bb,
                                                 float* __restrict__ out) {
    int row = blockIdx.x, tid = threadIdx.x;
    const float* r = in + (size_t)row * Dm;
    __shared__ float s1[4], s2[4];
    float x0 = r[tid], x1 = r[tid + 256];
    float sum = x0 + x1, sq = x0 * x0 + x1 * x1;
#pragma unroll
    for (int o = 32; o > 0; o >>= 1) { sum += __shfl_xor(sum, o); sq += __shfl_xor(sq, o); }
    if ((tid & 63) == 0) { s1[tid >> 6] = sum; s2[tid >> 6] = sq; }
    __syncthreads();
    sum = s1[0] + s1[1] + s1[2] + s1[3];
    sq  = s2[0] + s2[1] + s2[2] + s2[3];
    float mu = sum / Dm, var = sq / Dm - mu * mu, inv = rsqrtf(var + EPSV);
    out[(size_t)row * Dm + tid]       = (x0 - mu) * inv * s[tid] + bb[tid];
    out[(size_t)row * Dm + tid + 256] = (x1 - mu) * inv * s[tid + 256] + bb[tid + 256];
}

// ---------------------------------------------------------------- MFMA bf16 GEMM
__global__ __launch_bounds__(256) void gemm_mfma_kernel(const float* __restrict__ A, int lda,
                                                        const float* __restrict__ W, int ldw,
                                                        const float* __restrict__ bias,
                                                        const float* __restrict__ resid, int ldr,
                                                        float* __restrict__ Cout, int ldc,
                                                        int M, int Kd, float scale) {
    __shared__ __align__(16) unsigned short As[128][40];
    __shared__ __align__(16) unsigned short Bs[128][40];   // Bs[n][k]
    int tid = threadIdx.x;
    int m0 = blockIdx.y * 128, n0 = blockIdx.x * 128;
    int wave = tid >> 6, lane = tid & 63;
    int wm = (wave >> 1) * 64, wn = (wave & 1) * 64;
    int lrow = lane & 15, lquad = lane >> 4;

    f32x4 acc[4][4];
#pragma unroll
    for (int i = 0; i < 4; i++)
#pragma unroll
        for (int j = 0; j < 4; j++)
#pragma unroll
            for (int r = 0; r < 4; r++) acc[i][j][r] = 0.f;

    int am = tid >> 1, ak = (tid & 1) * 16;
    int bn = tid & 127, bk = (tid >> 7) * 16;

    for (int k0 = 0; k0 < Kd; k0 += 32) {
        // ---- stage A (f32 -> bf16)
        {
            int gm = m0 + am;
            float4 a0, a1, a2, a3;
            if (gm < M) {
                const float4* ap = (const float4*)(A + (size_t)gm * lda + k0 + ak);
                a0 = ap[0]; a1 = ap[1]; a2 = ap[2]; a3 = ap[3];
            } else {
                a0 = a1 = a2 = a3 = make_float4(0.f, 0.f, 0.f, 0.f);
            }
            ushort4v t0 = {f2bf(a0.x), f2bf(a0.y), f2bf(a0.z), f2bf(a0.w)};
            ushort4v t1 = {f2bf(a1.x), f2bf(a1.y), f2bf(a1.z), f2bf(a1.w)};
            ushort4v t2 = {f2bf(a2.x), f2bf(a2.y), f2bf(a2.z), f2bf(a2.w)};
            ushort4v t3 = {f2bf(a3.x), f2bf(a3.y), f2bf(a3.z), f2bf(a3.w)};
            *(ushort4v*)&As[am][ak + 0]  = t0;
            *(ushort4v*)&As[am][ak + 4]  = t1;
            *(ushort4v*)&As[am][ak + 8]  = t2;
            *(ushort4v*)&As[am][ak + 12] = t3;
        }
        // ---- stage B transposed (f32 -> bf16), Bs[n][k]
        {
            const float* wp = W + (size_t)(k0 + bk) * ldw + n0 + bn;
            unsigned short tmp[16];
#pragma unroll
            for (int j = 0; j < 16; j++) tmp[j] = f2bf(wp[(size_t)j * ldw]);
#pragma unroll
            for (int j4 = 0; j4 < 4; j4++) {
                ushort4v tv = {tmp[j4 * 4], tmp[j4 * 4 + 1], tmp[j4 * 4 + 2], tmp[j4 * 4 + 3]};
                *(ushort4v*)&Bs[bn][bk + j4 * 4] = tv;
            }
        }
        __syncthreads();
        bf16x8 afr[4], bfr[4];
#pragma unroll
        for (int mt = 0; mt < 4; mt++)
            afr[mt] = *(const bf16x8*)&As[wm + mt * 16 + lrow][lquad * 8];
#pragma unroll
        for (int nt = 0; nt < 4; nt++)
            bfr[nt] = *(const bf16x8*)&Bs[wn + nt * 16 + lrow][lquad * 8];
#pragma unroll
        for (int mt = 0; mt < 4; mt++)
#pragma unroll
            for (int nt = 0; nt < 4; nt++)
                acc[mt][nt] = __builtin_amdgcn_mfma_f32_16x16x32_bf16(
                    afr[mt], bfr[nt], acc[mt][nt], 0, 0, 0);
        __syncthreads();
    }

#pragma unroll
    for (int mt = 0; mt < 4; mt++) {
#pragma unroll
        for (int r = 0; r < 4; r++) {
            int gm = m0 + wm + mt * 16 + lquad * 4 + r;
            if (gm >= M) continue;
#pragma unroll
            for (int nt = 0; nt < 4; nt++) {
                int gn = n0 + wn + nt * 16 + lrow;
                float v = acc[mt][nt][r] * scale;
                if (bias) v += bias[gn];
                if (resid) v += resid[(size_t)gm * ldr + gn];
                Cout[(size_t)gm * ldc + gn] = v;
            }
        }
    }
}

// ---------------------------------------------------------------- causal depthwise conv (K=4) + SiLU
__global__ __launch_bounds__(256) void conv_silu_kernel(const float* __restrict__ up,
                                                        const float* __restrict__ ck,
                                                        const float* __restrict__ cb,
                                                        float* __restrict__ xc) {
    int idx = blockIdx.x * 256 + threadIdx.x;
    if (idx >= ROWS * IN) return;
    int c = idx & (IN - 1);
    int bt = idx >> 10;
    int t = bt % TT, b = bt / TT;
    float acc = cb[c];
#pragma unroll
    for (int j = 0; j < KK; j++) {
        int tt = t - (KK - 1) + j;
        if (tt >= 0) acc += up[((size_t)(b * TT + tt)) * (2 * IN) + c] * ck[c * KK + j];
    }
    xc[idx] = siluf(acc);
}

// ---------------------------------------------------------------- input/forget gate projections
__global__ __launch_bounds__(256) void gates_kernel(const float* __restrict__ xc,
                                                    const float* __restrict__ wig, const float* __restrict__ big,
                                                    const float* __restrict__ wfg, const float* __restrict__ bfg,
                                                    float* __restrict__ ip, float* __restrict__ fp) {
    int row = blockIdx.x, tid = threadIdx.x;
    __shared__ float sx[IN];
    for (int i = tid; i < IN; i += 256) sx[i] = xc[(size_t)row * IN + i];
    __syncthreads();
    int g = tid >> 4, l = tid & 15;
    const float* w = (g < 8) ? wig : wfg;
    int h = g & 7;
    float acc = 0.f;
    for (int kk = l; kk < IN; kk += 16) acc += sx[kk] * w[kk * NHh + h];
#pragma unroll
    for (int o = 8; o > 0; o >>= 1) acc += __shfl_down(acc, o, 16);
    if (l == 0) {
        if (g < 8) ip[(size_t)row * NHh + h] = acc + big[h];
        else       fp[(size_t)row * NHh + h] = acc + bfg[h];
    }
}

// ---------------------------------------------------------------- chunkwise mLSTM
// Kernel A (wave-parallel prefix scan): one wave per chain.
__global__ __launch_bounds__(64) void gate_scan_kernel(const float* __restrict__ ip,
        const float* __restrict__ fp, float* __restrict__ gG, float* __restrict__ gM,
        float* __restrict__ gMb, float* __restrict__ gDec) {
    constexpr int PER = 9; // 64*9 = 576 >= 513
    int chain = blockIdx.x;
    int b = chain >> 3, h = chain & 7;
    int lane = threadIdx.x;
    int tbase = lane * PER;
    float lcs[PER];
    float gi[PER];
    float csum = 0.f;
#pragma unroll
    for (int i = 0; i < PER; i++) {
        int t = tbase + i;
        float fpv = 0.f, ipv = 0.f;
        if (t < TT) {
            size_t gidx = (size_t)(b * TT + t) * NHh + h;
            fpv = fp[gidx]; ipv = ip[gidx];
        }
        float flv = (fpv >= 0.f) ? -log1pf(__expf(-fpv)) : (fpv - log1pf(__expf(fpv)));
        if (t >= TT) flv = 0.f;
        csum += flv;
        lcs[i] = csum;
        gi[i] = ipv;
    }
    float ps = csum;
#pragma unroll
    for (int o = 1; o < 64; o <<= 1) {
        float v = __shfl_up(ps, o);
        if (lane >= o) ps += v;
    }
    float Fexcl = ps - csum;
    float G[PER];
    float cmax = -1e30f;
#pragma unroll
    for (int i = 0; i < PER; i++) {
        int t = tbase + i;
        G[i] = (t < TT) ? (gi[i] - (Fexcl + lcs[i])) : -1e30f;
        cmax = fmaxf(cmax, G[i]);
        lcs[i] = cmax;
    }
    float pm = cmax;
#pragma unroll
    for (int o = 1; o < 64; o <<= 1) {
        float v = __shfl_up(pm, o);
        if (lane >= o) pm = fmaxf(pm, v);
    }
    float Me = __shfl_up(pm, 1);
    if (lane == 0) Me = -1e30f;
    __shared__ float sMb[NCH];
#pragma unroll
    for (int i = 0; i < PER; i++) {
        int t = tbase + i;
        if (t < TT) {
            float Mt = fmaxf(0.f, fmaxf(Me, lcs[i]));
            gG[chain * TT + t] = G[i];
            gM[chain * TT + t] = Mt;
            if (((t & 63) == 63) || t == TT - 1) sMb[t >> 6] = Mt;
        }
    }
    __syncthreads();
    if (lane < NCH) {
        float Mb = sMb[lane];
        float Mbp = (lane == 0) ? 0.f : sMb[lane - 1];
        gMb[chain * NCH + lane] = Mb;
        gDec[chain * NCH + lane] = __expf(Mbp - Mb);
    }
}

// Kernel B1: per-chunk local state P[d][e] = sum_j exp(G_j - Mb_c) k_j[d] v_j[e]
// #pragma unroll 1 on the j-loops: auto-unroll of long LDS loops spills (R7 lesson).
__global__ __launch_bounds__(256) void chunk_state_kernel(const float* __restrict__ kk,
        const float* __restrict__ vv, const float* __restrict__ gG,
        const float* __restrict__ gMb, float* __restrict__ P, float* __restrict__ nP) {
    int c = blockIdx.x, chain = blockIdx.y;
    int b = chain >> 3, h = chain & 7;
    int t0 = c * 64;
    int nvalid = min(64, TT - t0);
    __shared__ float sK[32][128], sV[32][128], sw[64];
    int tid = threadIdx.x;
    if (tid < 64) {
        float Mb = gMb[chain * NCH + c];
        sw[tid] = (tid < nvalid) ? __expf(gG[chain * TT + t0 + tid] - Mb) : 0.f;
    }
    int e = tid & 127, dg = (tid >> 7) * 64;
    float4 acc[16];
#pragma unroll
    for (int i = 0; i < 16; i++) acc[i] = make_float4(0.f, 0.f, 0.f, 0.f);
    float na = 0.f;
    for (int jh = 0; jh < 2; jh++) {
        int lrow = tid >> 5, lcol = (tid & 31) * 4;
        for (int rr = 0; rr < 4; rr++) {
            int r = lrow + rr * 8;
            int gr = jh * 32 + r;
            float4 kv = make_float4(0.f,0.f,0.f,0.f), vvv = kv;
            if (gr < nvalid) {
                size_t gb = ((size_t)(b * TT + t0 + gr)) * IN + h * DHd + lcol;
                kv = *(const float4*)(kk + gb);
                vvv = *(const float4*)(vv + gb);
            }
            *(float4*)&sK[r][lcol] = kv;
            *(float4*)&sV[r][lcol] = vvv;
        }
        __syncthreads();
        int jmax = min(32, nvalid - jh * 32);
#pragma unroll 1
        for (int j = 0; j < jmax; j++) {
            float wvj = sw[jh * 32 + j] * sV[j][e];
            const float4* kr = (const float4*)&sK[j][dg];
#pragma unroll
            for (int d4 = 0; d4 < 16; d4++) {
                float4 kq = kr[d4];
                acc[d4].x += kq.x * wvj; acc[d4].y += kq.y * wvj;
                acc[d4].z += kq.z * wvj; acc[d4].w += kq.w * wvj;
            }
        }
        if (tid < 128) {
#pragma unroll 1
            for (int j = 0; j < jmax; j++) na += sw[jh * 32 + j] * sK[j][tid];
        }
        __syncthreads();
    }
    float* Pbase = P + (((size_t)(c * 32 + chain)) << 14);
#pragma unroll
    for (int d4 = 0; d4 < 16; d4++) {
        Pbase[(size_t)(dg + d4 * 4 + 0) * 128 + e] = acc[d4].x;
        Pbase[(size_t)(dg + d4 * 4 + 1) * 128 + e] = acc[d4].y;
        Pbase[(size_t)(dg + d4 * 4 + 2) * 128 + e] = acc[d4].z;
        Pbase[(size_t)(dg + d4 * 4 + 3) * 128 + e] = acc[d4].w;
    }
    if (tid < 128) nP[(size_t)(c * 32 + chain) * 128 + tid] = na;
}

// Kernel B2: in-place exclusive combine over chunks.
__global__ __launch_bounds__(256) void chunk_combine_kernel(float* __restrict__ P,
        const float* __restrict__ gDec) {
    int chain = blockIdx.x >> 6;
    int idx = (blockIdx.x & 63) * 256 + threadIdx.x;
    float run = 0.f;
    for (int c = 0; c < NCH; c++) {
        size_t a = (((size_t)(c * 32 + chain)) << 14) + idx;
        float tmp = P[a];
        P[a] = run;
        run = run * gDec[chain * NCH + c] + tmp;
    }
}

__global__ __launch_bounds__(256) void n_combine_kernel(float* __restrict__ nP,
        const float* __restrict__ gDec) {
    int gidx = blockIdx.x * 256 + threadIdx.x;
    int chain = gidx >> 7, d = gidx & 127;
    float run = 0.f;
    for (int c = 0; c < NCH; c++) {
        size_t a = (size_t)(c * 32 + chain) * 128 + d;
        float tmp = nP[a];
        nP[a] = run;
        run = run * gDec[chain * NCH + c] + tmp;
    }
}

// Kernel C: per-chunk outputs. Long LDS loops pinned with #pragma unroll 1
// (auto-unroll was hoisting 100s of LDS loads -> scratch spill, the 450MB
// phantom traffic of R5-R7). Inner 16-wide acc loops stay fully unrolled.
// sD padded to 68 for 16B-aligned b128 row reads.
__global__ __launch_bounds__(512, 2) void chunk_out_kernel(const float* __restrict__ qq,
        const float* __restrict__ kk, const float* __restrict__ vv,
        const float* __restrict__ gG, const float* __restrict__ gM,
        const float* __restrict__ gMb, const float* __restrict__ P,
        const float* __restrict__ nP, float* __restrict__ hs) {
    int c = blockIdx.x, chain = blockIdx.y;
    int b = chain >> 3, h = chain & 7;
    int t0 = c * 64;
    int nvalid = min(64, TT - t0);
    __shared__ __align__(16) float smem[13440];
    float* sG  = smem;          // 64
    float* sM  = smem + 64;     // 64
    float* sWr = smem + 128;    // 64
    float* sInv= smem + 192;    // 64
    float* sNb = smem + 256;    // 128
    float (*sD)[68] = (float(*)[68])(smem + 384);          // 64x68
    float* scr = smem + 384 + 64 * 68;                     // scratch base (4736)
    int tid = threadIdx.x;

    float Mbprev = (c > 0) ? gMb[chain * NCH + c - 1] : 0.f;
    if (tid < 64) {
        bool val = tid < nvalid;
        sG[tid] = val ? gG[chain * TT + t0 + tid] : -1e30f;
        float Mv = val ? gM[chain * TT + t0 + tid] : 1e30f;
        sM[tid] = Mv;
        sWr[tid] = val ? __expf(Mbprev - Mv) : 0.f;
    }
    if (tid >= 128 && tid < 256) sNb[tid - 128] = nP[(size_t)(c * 32 + chain) * 128 + (tid - 128)];
    __syncthreads();

    int e = tid & 127, rg = (tid >> 7) * 16;   // 4 row-groups x 16 rows
    float acc[16];
#pragma unroll
    for (int r = 0; r < 16; r++) acc[r] = 0.f;

    // ---- Phase 0: inter H = Q @ CB
    {
        float (*sCB)[128] = (float(*)[128])(smem + 384);          // 64x128
        float (*Qh2)[68]  = (float(*)[68])(smem + 384 + 64*128);  // 64x68
        const float* CBbase = P + (((size_t)(c * 32 + chain)) << 14);
        for (int dh = 0; dh < 2; dh++) {
            {
                int dr = tid >> 5, dc = (tid & 31) * 4;
#pragma unroll
                for (int rr = 0; rr < 4; rr++) {
                    int d = dr + rr * 16;
                    *(float4*)&sCB[d][dc] = *(const float4*)(CBbase + (size_t)(dh * 64 + d) * 128 + dc);
                }
                int lr = tid >> 3, c0 = (tid & 7) * 8;
                bool val = lr < nvalid;
                size_t gb = ((size_t)(b * TT + t0 + lr)) * IN + h * DHd + dh * 64 + c0;
                float4 qv0 = val ? *(const float4*)(qq + gb)     : make_float4(0.f,0.f,0.f,0.f);
                float4 qv1 = val ? *(const float4*)(qq + gb + 4) : make_float4(0.f,0.f,0.f,0.f);
                *(float4*)&Qh2[lr][c0]     = qv0;
                *(float4*)&Qh2[lr][c0 + 4] = qv1;
            }
            __syncthreads();
#pragma unroll 1
            for (int dd4 = 0; dd4 < 16; dd4++) {
                float c0v = sCB[dd4 * 4 + 0][e];
                float c1v = sCB[dd4 * 4 + 1][e];
                float c2v = sCB[dd4 * 4 + 2][e];
                float c3v = sCB[dd4 * 4 + 3][e];
#pragma unroll
                for (int r = 0; r < 16; r++) {
                    float4 qf = *(const float4*)&Qh2[rg + r][dd4 * 4];
                    acc[r] += qf.x * c0v + qf.y * c1v + qf.z * c2v + qf.w * c3v;
                }
            }
            __syncthreads();
        }
#pragma unroll
        for (int r = 0; r < 16; r++) acc[r] *= sWr[rg + r];
    }

    // ---- Phase 1: S = Q K^T; weights -> sD; qnb
    float qnb = 0.f;
    {
        float (*Qh)[68] = (float(*)[68])scr;               // 64x68
        float (*Kh)[68] = (float(*)[68])(scr + 64 * 68);   // 64x68
        int j = tid & 63, ig = (tid >> 6) * 8;
        float accS[8];
#pragma unroll
        for (int i = 0; i < 8; i++) accS[i] = 0.f;
        for (int dh = 0; dh < 2; dh++) {
            {
                int lr = tid >> 3, c0 = (tid & 7) * 8;
                bool val = lr < nvalid;
                size_t gb = ((size_t)(b * TT + t0 + lr)) * IN + h * DHd + dh * 64 + c0;
                float4 qv0 = val ? *(const float4*)(qq + gb)     : make_float4(0.f,0.f,0.f,0.f);
                float4 qv1 = val ? *(const float4*)(qq + gb + 4) : make_float4(0.f,0.f,0.f,0.f);
                float4 kv0 = val ? *(const float4*)(kk + gb)     : make_float4(0.f,0.f,0.f,0.f);
                float4 kv1 = val ? *(const float4*)(kk + gb + 4) : make_float4(0.f,0.f,0.f,0.f);
                *(float4*)&Qh[lr][c0]     = qv0;
                *(float4*)&Qh[lr][c0 + 4] = qv1;
                *(float4*)&Kh[lr][c0]     = kv0;
                *(float4*)&Kh[lr][c0 + 4] = kv1;
            }
            __syncthreads();
#pragma unroll 1
            for (int d4 = 0; d4 < 16; d4++) {
                float4 kf = *(const float4*)&Kh[j][d4 * 4];
#pragma unroll
                for (int i = 0; i < 8; i++) {
                    float4 qf = *(const float4*)&Qh[ig + i][d4 * 4];
                    accS[i] += qf.x * kf.x + qf.y * kf.y + qf.z * kf.z + qf.w * kf.w;
                }
            }
            if (tid < 64) {
#pragma unroll 1
                for (int d4 = 0; d4 < 16; d4++) {
                    float4 qf = *(const float4*)&Qh[tid][d4 * 4];
                    float4 nb = *(const float4*)&sNb[dh * 64 + d4 * 4];
                    qnb += qf.x * nb.x + qf.y * nb.y + qf.z * nb.z + qf.w * nb.w;
                }
            }
            __syncthreads();
        }
        float Gj = sG[j];
#pragma unroll
        for (int i = 0; i < 8; i++) {
            int irow = ig + i;
            float w = (j <= irow) ? __expf(Gj - sM[irow]) : 0.f;
            sD[irow][j] = accS[i] * w;
        }
    }
    __syncthreads();

    // ---- Phase 2: denominators
    if (tid < 64) {
        float s = 0.f;
#pragma unroll 1
        for (int j4 = 0; j4 < 16; j4++) {
            float4 d = *(const float4*)&sD[tid][j4 * 4];
            s += d.x + d.y + d.z + d.w;
        }
        float den = s + sWr[tid] * qnb;
        sInv[tid] = 1.f / fmaxf(fabsf(den), 1.f);
    }
    __syncthreads();

    // ---- Phase 3: intra H += D @ V
    {
        float (*sV)[128] = (float(*)[128])scr;             // 64x128
        int lrow = tid >> 5, lcol = (tid & 31) * 4;
#pragma unroll
        for (int rr = 0; rr < 4; rr++) {
            int r = lrow + rr * 16;
            float4 vvv = make_float4(0.f,0.f,0.f,0.f);
            if (r < nvalid) {
                size_t gb = ((size_t)(b * TT + t0 + r)) * IN + h * DHd + lcol;
                vvv = *(const float4*)(vv + gb);
            }
            *(float4*)&sV[r][lcol] = vvv;
        }
        __syncthreads();
#pragma unroll 1
        for (int jj4 = 0; jj4 < 16; jj4++) {
            float v0 = sV[jj4 * 4 + 0][e];
            float v1 = sV[jj4 * 4 + 1][e];
            float v2 = sV[jj4 * 4 + 2][e];
            float v3 = sV[jj4 * 4 + 3][e];
#pragma unroll
            for (int r = 0; r < 16; r++) {
                float4 d = *(const float4*)&sD[rg + r][jj4 * 4];
                acc[r] += d.x * v0 + d.y * v1 + d.z * v2 + d.w * v3;
            }
        }
    }

    // ---- store
#pragma unroll
    for (int r = 0; r < 16; r++) {
        int irow = rg + r;
        if (irow < nvalid)
            hs[((size_t)(b * TT + t0 + irow)) * IN + h * DHd + e] = acc[r] * sInv[irow];
    }
}

// ---------------------------------------------------------------- per-head norm * hn_s * silu(z)
__global__ __launch_bounds__(64) void headnorm_kernel(const float* __restrict__ hs,
                                                      const float* __restrict__ hn,
                                                      const float* __restrict__ up,
                                                      float* __restrict__ out) {
    int idx = blockIdx.x;
    int h = idx & 7, bt = idx >> 3;
    int tid = threadIdx.x;
    size_t base = (size_t)bt * IN + h * DHd;
    float x0 = hs[base + tid], x1 = hs[base + 64 + tid];
    float sum = x0 + x1, sq = x0 * x0 + x1 * x1;
#pragma unroll
    for (int o = 32; o > 0; o >>= 1) { sum += __shfl_xor(sum, o); sq += __shfl_xor(sq, o); }
    float mu = sum / DHd, var = sq / DHd - mu * mu, inv = rsqrtf(var + EPSV);
    size_t zb = (size_t)bt * (2 * IN) + IN + h * DHd;
    out[base + tid]      = (x0 - mu) * inv * hn[h * DHd + tid]      * siluf(up[zb + tid]);
    out[base + 64 + tid] = (x1 - mu) * inv * hn[h * DHd + 64 + tid] * siluf(up[zb + 64 + tid]);
}

// ---------------------------------------------------------------- final classifier head
__global__ __launch_bounds__(256) void classifier_kernel(const float* __restrict__ hbuf,
                                                         const float* __restrict__ s, const float* __restrict__ bb,
                                                         const float* __restrict__ fw, const float* __restrict__ fb,
                                                         float* __restrict__ out) {
    int b = blockIdx.x, tid = threadIdx.x;
    const float* r = hbuf + ((size_t)b * TT + TT - 1) * Dm;
    __shared__ float vbuf[Dm];
    __shared__ float s1[4], s2[4];
    float x0 = r[tid], x1 = r[tid + 256];
    float sum = x0 + x1, sq = x0 * x0 + x1 * x1;
#pragma unroll
    for (int o = 32; o > 0; o >>= 1) { sum += __shfl_xor(sum, o); sq += __shfl_xor(sq, o); }
    if ((tid & 63) == 0) { s1[tid >> 6] = sum; s2[tid >> 6] = sq; }
    __syncthreads();
    sum = s1[0] + s1[1] + s1[2] + s1[3];
    sq  = s2[0] + s2[1] + s2[2] + s2[3];
    float mu = sum / Dm, var = sq / Dm - mu * mu, inv = rsqrtf(var + EPSV);
    float n0 = (x0 - mu) * inv * s[tid] + bb[tid];
    float n1 = (x1 - mu) * inv * s[tid + 256] + bb[tid + 256];
    vbuf[tid] = fmaxf(n0, 0.f);
    vbuf[tid + 256] = fmaxf(n1, 0.f);
    __syncthreads();
    for (int j = tid; j < NCc; j += 256) {
        float acc = fb[j];
#pragma unroll 1
        for (int kk = 0; kk < Dm; kk++) acc += vbuf[kk] * fw[kk * NCc + j];
        out[b * NCc + j] = acc;
    }
}

// ---------------------------------------------------------------- launch
extern "C" void kernel_launch(void* const* d_in, const int* in_sizes, int n_in,
                              void* d_out, int out_size, void* d_ws, size_t ws_size,
                              hipStream_t stream) {
    const float* x      = (const float*)d_in[0];
    const float* cls    = (const float*)d_in[1];
    const float* ln_s   = (const float*)d_in[2];
    const float* ln_b   = (const float*)d_in[3];
    const float* w_up   = (const float*)d_in[4];
    const float* b_up   = (const float*)d_in[5];
    const float* conv_k = (const float*)d_in[6];
    const float* conv_b = (const float*)d_in[7];
    const float* w_q    = (const float*)d_in[8];
    const float* w_k    = (const float*)d_in[9];
    const float* w_v    = (const float*)d_in[10];
    const float* w_ig   = (const float*)d_in[11];
    const float* b_ig   = (const float*)d_in[12];
    const float* w_fg   = (const float*)d_in[13];
    const float* b_fg   = (const float*)d_in[14];
    const float* hn_s   = (const float*)d_in[15];
    const float* w_down = (const float*)d_in[16];
    const float* b_down = (const float*)d_in[17];
    const float* fcls   = (const float*)d_in[18];
    const float* fclb   = (const float*)d_in[19];
    const float* fc_w   = (const float*)d_in[20];
    const float* fc_b   = (const float*)d_in[21];
    float* out = (float*)d_out;

    float* ws = (float*)d_ws;
    size_t off = 0;
    float* f_h  = ws + off; off += (size_t)ROWS * Dm;
    float* f_xn = ws + off; off += (size_t)ROWS * Dm;
    float* f_up = ws + off; off += (size_t)ROWS * 2 * IN;
    float* f_xc = ws + off; off += (size_t)ROWS * IN;
    float* f_q  = ws + off; off += (size_t)ROWS * IN;
    float* f_k  = ws + off; off += (size_t)ROWS * IN;
    float* f_v  = ws + off; off += (size_t)ROWS * IN;
    float* f_hs = ws + off; off += (size_t)ROWS * IN;
    float* f_ip = ws + off; off += (size_t)ROWS * NHh;
    float* f_fp = ws + off; off += (size_t)ROWS * NHh;
    float* g_G  = ws + off; off += 32 * TT;
    float* g_M  = ws + off; off += 32 * TT;
    float* g_Mb = ws + off; off += 32 * NCH;
    float* g_De = ws + off; off += 32 * NCH;
    float* g_P  = ws + off; off += (size_t)NCH * 32 * DHd * DHd;
    float* g_nP = ws + off; off += (size_t)NCH * 32 * DHd;

    const float kscale = 0.08838834764831845f; // DH^-0.5
    const int MB = (ROWS + 127) / 128;         // 17

    concat_kernel<<<(ROWS * Dm + 255) / 256, 256, 0, stream>>>(x, cls, f_h);

    for (int blk = 0; blk < 2; blk++) {
        const float* p_ln_s = ln_s + blk * Dm;
        const float* p_ln_b = ln_b + blk * Dm;
        const float* p_wup  = w_up + (size_t)blk * Dm * 2 * IN;
        const float* p_bup  = b_up + (size_t)blk * 2 * IN;
        const float* p_ck   = conv_k + (size_t)blk * IN * KK;
        const float* p_cb   = conv_b + (size_t)blk * IN;
        const float* p_wq   = w_q + (size_t)blk * IN * IN;
        const float* p_wk   = w_k + (size_t)blk * IN * IN;
        const float* p_wv   = w_v + (size_t)blk * IN * IN;
        const float* p_wig  = w_ig + (size_t)blk * IN * NHh;
        const float* p_big  = b_ig + (size_t)blk * NHh;
        const float* p_wfg  = w_fg + (size_t)blk * IN * NHh;
        const float* p_bfg  = b_fg + (size_t)blk * NHh;
        const float* p_hns  = hn_s + (size_t)blk * NHh * DHd;
        const float* p_wd   = w_down + (size_t)blk * IN * Dm;
        const float* p_bd   = b_down + (size_t)blk * Dm;

        ln_kernel<<<ROWS, 256, 0, stream>>>(f_h, p_ln_s, p_ln_b, f_xn);

        gemm_mfma_kernel<<<dim3(2 * IN / 128, MB), 256, 0, stream>>>(
            f_xn, Dm, p_wup, 2 * IN, p_bup, nullptr, 0, f_up, 2 * IN, ROWS, Dm, 1.f);

        conv_silu_kernel<<<(ROWS * IN + 255) / 256, 256, 0, stream>>>(f_up, p_ck, p_cb, f_xc);

        gemm_mfma_kernel<<<dim3(IN / 128, MB), 256, 0, stream>>>(
            f_xc, IN, p_wq, IN, nullptr, nullptr, 0, f_q, IN, ROWS, IN, 1.f);
        gemm_mfma_kernel<<<dim3(IN / 128, MB), 256, 0, stream>>>(
            f_xc, IN, p_wk, IN, nullptr, nullptr, 0, f_k, IN, ROWS, IN, kscale);
        gemm_mfma_kernel<<<dim3(IN / 128, MB), 256, 0, stream>>>(
            f_up, 2 * IN, p_wv, IN, nullptr, nullptr, 0, f_v, IN, ROWS, IN, 1.f);

        gates_kernel<<<ROWS, 256, 0, stream>>>(f_xc, p_wig, p_big, p_wfg, p_bfg, f_ip, f_fp);

        // chunkwise-parallel mLSTM
        gate_scan_kernel<<<32, 64, 0, stream>>>(f_ip, f_fp, g_G, g_M, g_Mb, g_De);
        chunk_state_kernel<<<dim3(NCH, 32), 256, 0, stream>>>(f_k, f_v, g_G, g_Mb, g_P, g_nP);
        chunk_combine_kernel<<<32 * 64, 256, 0, stream>>>(g_P, g_De);
        n_combine_kernel<<<16, 256, 0, stream>>>(g_nP, g_De);
        chunk_out_kernel<<<dim3(NCH, 32), 512, 0, stream>>>(f_q, f_k, f_v, g_G, g_M, g_Mb,
                                                            g_P, g_nP, f_hs);

        headnorm_kernel<<<ROWS * NHh, 64, 0, stream>>>(f_hs, p_hns, f_up, f_xc);

        gemm_mfma_kernel<<<dim3(Dm / 128, MB), 256, 0, stream>>>(
            f_xc, IN, p_wd, Dm, p_bd, f_h, Dm, f_h, Dm, ROWS, IN, 1.f);
    }

    classifier_kernel<<<Bsz, 256, 0, stream>>>(f_h, fcls, fclb, fc_w, fc_b, out);
}

// Round 9
// 951.261 us; speedup vs baseline: 3.3622x; 1.4864x over previous
//
#include <hip/hip_runtime.h>

// ---------------------------------------------------------------- constants
#define EPSV 1e-5f
constexpr int Bsz = 4, T0 = 512, Dm = 512, TT = 513, NHh = 8, KK = 4;
constexpr int IN = 1024, DHd = 128, NCc = 1000;
constexpr int ROWS = Bsz * TT; // 2052
constexpr int NCH = 9;         // chunks of 64: 8*64 + 1 = 513

typedef __attribute__((ext_vector_type(8))) short bf16x8;
typedef __attribute__((ext_vector_type(4))) float f32x4;
typedef __attribute__((ext_vector_type(4))) unsigned short ushort4v;

__device__ __forceinline__ float siluf(float x) { return x / (1.f + __expf(-x)); }
__device__ __forceinline__ unsigned short f2bf(float f) {
    unsigned int u = __float_as_uint(f);
    u = (u + 0x7FFFu + ((u >> 16) & 1u)) >> 16;
    return (unsigned short)u;
}

// ---------------------------------------------------------------- concat x + cls
__global__ __launch_bounds__(256) void concat_kernel(const float* __restrict__ x,
                                                     const float* __restrict__ cls,
                                                     float* __restrict__ h) {
    int idx = blockIdx.x * 256 + threadIdx.x;
    if (idx >= Bsz * TT * Dm) return;
    int d = idx & (Dm - 1);
    int bt = idx >> 9;
    int t = bt % TT, b = bt / TT;
    h[idx] = (t < T0) ? x[((size_t)(b * T0 + t)) * Dm + d] : cls[d];
}

// ---------------------------------------------------------------- LayerNorm rows of D=512
__global__ __launch_bounds__(256) void ln_kernel(const float* __restrict__ in,
                                                 const float* __restrict__ s,
                                                 const float* __restrict__ bb,
                                                 float* __restrict__ out) {
    int row = blockIdx.x, tid = threadIdx.x;
    const float* r = in + (size_t)row * Dm;
    __shared__ float s1[4], s2[4];
    float x0 = r[tid], x1 = r[tid + 256];
    float sum = x0 + x1, sq = x0 * x0 + x1 * x1;
#pragma unroll
    for (int o = 32; o > 0; o >>= 1) { sum += __shfl_xor(sum, o); sq += __shfl_xor(sq, o); }
    if ((tid & 63) == 0) { s1[tid >> 6] = sum; s2[tid >> 6] = sq; }
    __syncthreads();
    sum = s1[0] + s1[1] + s1[2] + s1[3];
    sq  = s2[0] + s2[1] + s2[2] + s2[3];
    float mu = sum / Dm, var = sq / Dm - mu * mu, inv = rsqrtf(var + EPSV);
    out[(size_t)row * Dm + tid]       = (x0 - mu) * inv * s[tid] + bb[tid];
    out[(size_t)row * Dm + tid + 256] = (x1 - mu) * inv * s[tid + 256] + bb[tid + 256];
}

// ---------------------------------------------------------------- MFMA bf16 GEMM
__global__ __launch_bounds__(256) void gemm_mfma_kernel(const float* __restrict__ A, int lda,
                                                        const float* __restrict__ W, int ldw,
                                                        const float* __restrict__ bias,
                                                        const float* __restrict__ resid, int ldr,
                                                        float* __restrict__ Cout, int ldc,
                                                        int M, int Kd, float scale) {
    __shared__ __align__(16) unsigned short As[128][40];
    __shared__ __align__(16) unsigned short Bs[128][40];   // Bs[n][k]
    int tid = threadIdx.x;
    int m0 = blockIdx.y * 128, n0 = blockIdx.x * 128;
    int wave = tid >> 6, lane = tid & 63;
    int wm = (wave >> 1) * 64, wn = (wave & 1) * 64;
    int lrow = lane & 15, lquad = lane >> 4;

    f32x4 acc[4][4];
#pragma unroll
    for (int i = 0; i < 4; i++)
#pragma unroll
        for (int j = 0; j < 4; j++)
#pragma unroll
            for (int r = 0; r < 4; r++) acc[i][j][r] = 0.f;

    int am = tid >> 1, ak = (tid & 1) * 16;
    int bn = tid & 127, bk = (tid >> 7) * 16;

    for (int k0 = 0; k0 < Kd; k0 += 32) {
        // ---- stage A (f32 -> bf16)
        {
            int gm = m0 + am;
            float4 a0, a1, a2, a3;
            if (gm < M) {
                const float4* ap = (const float4*)(A + (size_t)gm * lda + k0 + ak);
                a0 = ap[0]; a1 = ap[1]; a2 = ap[2]; a3 = ap[3];
            } else {
                a0 = a1 = a2 = a3 = make_float4(0.f, 0.f, 0.f, 0.f);
            }
            ushort4v t0 = {f2bf(a0.x), f2bf(a0.y), f2bf(a0.z), f2bf(a0.w)};
            ushort4v t1 = {f2bf(a1.x), f2bf(a1.y), f2bf(a1.z), f2bf(a1.w)};
            ushort4v t2 = {f2bf(a2.x), f2bf(a2.y), f2bf(a2.z), f2bf(a2.w)};
            ushort4v t3 = {f2bf(a3.x), f2bf(a3.y), f2bf(a3.z), f2bf(a3.w)};
            *(ushort4v*)&As[am][ak + 0]  = t0;
            *(ushort4v*)&As[am][ak + 4]  = t1;
            *(ushort4v*)&As[am][ak + 8]  = t2;
            *(ushort4v*)&As[am][ak + 12] = t3;
        }
        // ---- stage B transposed (f32 -> bf16), Bs[n][k]
        {
            const float* wp = W + (size_t)(k0 + bk) * ldw + n0 + bn;
            unsigned short tmp[16];
#pragma unroll
            for (int j = 0; j < 16; j++) tmp[j] = f2bf(wp[(size_t)j * ldw]);
#pragma unroll
            for (int j4 = 0; j4 < 4; j4++) {
                ushort4v tv = {tmp[j4 * 4], tmp[j4 * 4 + 1], tmp[j4 * 4 + 2], tmp[j4 * 4 + 3]};
                *(ushort4v*)&Bs[bn][bk + j4 * 4] = tv;
            }
        }
        __syncthreads();
        bf16x8 afr[4], bfr[4];
#pragma unroll
        for (int mt = 0; mt < 4; mt++)
            afr[mt] = *(const bf16x8*)&As[wm + mt * 16 + lrow][lquad * 8];
#pragma unroll
        for (int nt = 0; nt < 4; nt++)
            bfr[nt] = *(const bf16x8*)&Bs[wn + nt * 16 + lrow][lquad * 8];
#pragma unroll
        for (int mt = 0; mt < 4; mt++)
#pragma unroll
            for (int nt = 0; nt < 4; nt++)
                acc[mt][nt] = __builtin_amdgcn_mfma_f32_16x16x32_bf16(
                    afr[mt], bfr[nt], acc[mt][nt], 0, 0, 0);
        __syncthreads();
    }

#pragma unroll
    for (int mt = 0; mt < 4; mt++) {
#pragma unroll
        for (int r = 0; r < 4; r++) {
            int gm = m0 + wm + mt * 16 + lquad * 4 + r;
            if (gm >= M) continue;
#pragma unroll
            for (int nt = 0; nt < 4; nt++) {
                int gn = n0 + wn + nt * 16 + lrow;
                float v = acc[mt][nt][r] * scale;
                if (bias) v += bias[gn];
                if (resid) v += resid[(size_t)gm * ldr + gn];
                Cout[(size_t)gm * ldc + gn] = v;
            }
        }
    }
}

// ---------------------------------------------------------------- causal depthwise conv (K=4) + SiLU
__global__ __launch_bounds__(256) void conv_silu_kernel(const float* __restrict__ up,
                                                        const float* __restrict__ ck,
                                                        const float* __restrict__ cb,
                                                        float* __restrict__ xc) {
    int idx = blockIdx.x * 256 + threadIdx.x;
    if (idx >= ROWS * IN) return;
    int c = idx & (IN - 1);
    int bt = idx >> 10;
    int t = bt % TT, b = bt / TT;
    float acc = cb[c];
#pragma unroll
    for (int j = 0; j < KK; j++) {
        int tt = t - (KK - 1) + j;
        if (tt >= 0) acc += up[((size_t)(b * TT + tt)) * (2 * IN) + c] * ck[c * KK + j];
    }
    xc[idx] = siluf(acc);
}

// ---------------------------------------------------------------- input/forget gate projections
__global__ __launch_bounds__(256) void gates_kernel(const float* __restrict__ xc,
                                                    const float* __restrict__ wig, const float* __restrict__ big,
                                                    const float* __restrict__ wfg, const float* __restrict__ bfg,
                                                    float* __restrict__ ip, float* __restrict__ fp) {
    int row = blockIdx.x, tid = threadIdx.x;
    __shared__ float sx[IN];
    for (int i = tid; i < IN; i += 256) sx[i] = xc[(size_t)row * IN + i];
    __syncthreads();
    int g = tid >> 4, l = tid & 15;
    const float* w = (g < 8) ? wig : wfg;
    int h = g & 7;
    float acc = 0.f;
    for (int kk = l; kk < IN; kk += 16) acc += sx[kk] * w[kk * NHh + h];
#pragma unroll
    for (int o = 8; o > 0; o >>= 1) acc += __shfl_down(acc, o, 16);
    if (l == 0) {
        if (g < 8) ip[(size_t)row * NHh + h] = acc + big[h];
        else       fp[(size_t)row * NHh + h] = acc + bfg[h];
    }
}

// ---------------------------------------------------------------- chunkwise mLSTM
// Kernel A (wave-parallel prefix scan): one wave per chain.
__global__ __launch_bounds__(64) void gate_scan_kernel(const float* __restrict__ ip,
        const float* __restrict__ fp, float* __restrict__ gG, float* __restrict__ gM,
        float* __restrict__ gMb, float* __restrict__ gDec) {
    constexpr int PER = 9; // 64*9 = 576 >= 513
    int chain = blockIdx.x;
    int b = chain >> 3, h = chain & 7;
    int lane = threadIdx.x;
    int tbase = lane * PER;
    float lcs[PER];
    float gi[PER];
    float csum = 0.f;
#pragma unroll
    for (int i = 0; i < PER; i++) {
        int t = tbase + i;
        float fpv = 0.f, ipv = 0.f;
        if (t < TT) {
            size_t gidx = (size_t)(b * TT + t) * NHh + h;
            fpv = fp[gidx]; ipv = ip[gidx];
        }
        float flv = (fpv >= 0.f) ? -log1pf(__expf(-fpv)) : (fpv - log1pf(__expf(fpv)));
        if (t >= TT) flv = 0.f;
        csum += flv;
        lcs[i] = csum;
        gi[i] = ipv;
    }
    float ps = csum;
#pragma unroll
    for (int o = 1; o < 64; o <<= 1) {
        float v = __shfl_up(ps, o);
        if (lane >= o) ps += v;
    }
    float Fexcl = ps - csum;
    float G[PER];
    float cmax = -1e30f;
#pragma unroll
    for (int i = 0; i < PER; i++) {
        int t = tbase + i;
        G[i] = (t < TT) ? (gi[i] - (Fexcl + lcs[i])) : -1e30f;
        cmax = fmaxf(cmax, G[i]);
        lcs[i] = cmax;
    }
    float pm = cmax;
#pragma unroll
    for (int o = 1; o < 64; o <<= 1) {
        float v = __shfl_up(pm, o);
        if (lane >= o) pm = fmaxf(pm, v);
    }
    float Me = __shfl_up(pm, 1);
    if (lane == 0) Me = -1e30f;
    __shared__ float sMb[NCH];
#pragma unroll
    for (int i = 0; i < PER; i++) {
        int t = tbase + i;
        if (t < TT) {
            float Mt = fmaxf(0.f, fmaxf(Me, lcs[i]));
            gG[chain * TT + t] = G[i];
            gM[chain * TT + t] = Mt;
            if (((t & 63) == 63) || t == TT - 1) sMb[t >> 6] = Mt;
        }
    }
    __syncthreads();
    if (lane < NCH) {
        float Mb = sMb[lane];
        float Mbp = (lane == 0) ? 0.f : sMb[lane - 1];
        gMb[chain * NCH + lane] = Mb;
        gDec[chain * NCH + lane] = __expf(Mbp - Mb);
    }
}

// Kernel B1: per-chunk local state P[d][e] = sum_j exp(G_j - Mb_c) k_j[d] v_j[e]
// #pragma unroll 1 on the j-loops: auto-unroll of long LDS loops spills (R7 lesson).
__global__ __launch_bounds__(256) void chunk_state_kernel(const float* __restrict__ kk,
        const float* __restrict__ vv, const float* __restrict__ gG,
        const float* __restrict__ gMb, float* __restrict__ P, float* __restrict__ nP) {
    int c = blockIdx.x, chain = blockIdx.y;
    int b = chain >> 3, h = chain & 7;
    int t0 = c * 64;
    int nvalid = min(64, TT - t0);
    __shared__ float sK[32][128], sV[32][128], sw[64];
    int tid = threadIdx.x;
    if (tid < 64) {
        float Mb = gMb[chain * NCH + c];
        sw[tid] = (tid < nvalid) ? __expf(gG[chain * TT + t0 + tid] - Mb) : 0.f;
    }
    int e = tid & 127, dg = (tid >> 7) * 64;
    float4 acc[16];
#pragma unroll
    for (int i = 0; i < 16; i++) acc[i] = make_float4(0.f, 0.f, 0.f, 0.f);
    float na = 0.f;
    for (int jh = 0; jh < 2; jh++) {
        int lrow = tid >> 5, lcol = (tid & 31) * 4;
        for (int rr = 0; rr < 4; rr++) {
            int r = lrow + rr * 8;
            int gr = jh * 32 + r;
            float4 kv = make_float4(0.f,0.f,0.f,0.f), vvv = kv;
            if (gr < nvalid) {
                size_t gb = ((size_t)(b * TT + t0 + gr)) * IN + h * DHd + lcol;
                kv = *(const float4*)(kk + gb);
                vvv = *(const float4*)(vv + gb);
            }
            *(float4*)&sK[r][lcol] = kv;
            *(float4*)&sV[r][lcol] = vvv;
        }
        __syncthreads();
        int jmax = min(32, nvalid - jh * 32);
#pragma unroll 1
        for (int j = 0; j < jmax; j++) {
            float wvj = sw[jh * 32 + j] * sV[j][e];
            const float4* kr = (const float4*)&sK[j][dg];
#pragma unroll
            for (int d4 = 0; d4 < 16; d4++) {
                float4 kq = kr[d4];
                acc[d4].x += kq.x * wvj; acc[d4].y += kq.y * wvj;
                acc[d4].z += kq.z * wvj; acc[d4].w += kq.w * wvj;
            }
        }
        if (tid < 128) {
#pragma unroll 1
            for (int j = 0; j < jmax; j++) na += sw[jh * 32 + j] * sK[j][tid];
        }
        __syncthreads();
    }
    float* Pbase = P + (((size_t)(c * 32 + chain)) << 14);
#pragma unroll
    for (int d4 = 0; d4 < 16; d4++) {
        Pbase[(size_t)(dg + d4 * 4 + 0) * 128 + e] = acc[d4].x;
        Pbase[(size_t)(dg + d4 * 4 + 1) * 128 + e] = acc[d4].y;
        Pbase[(size_t)(dg + d4 * 4 + 2) * 128 + e] = acc[d4].z;
        Pbase[(size_t)(dg + d4 * 4 + 3) * 128 + e] = acc[d4].w;
    }
    if (tid < 128) nP[(size_t)(c * 32 + chain) * 128 + tid] = na;
}

// Kernel B2: in-place exclusive combine over chunks.
__global__ __launch_bounds__(256) void chunk_combine_kernel(float* __restrict__ P,
        const float* __restrict__ gDec) {
    int chain = blockIdx.x >> 6;
    int idx = (blockIdx.x & 63) * 256 + threadIdx.x;
    float run = 0.f;
    for (int c = 0; c < NCH; c++) {
        size_t a = (((size_t)(c * 32 + chain)) << 14) + idx;
        float tmp = P[a];
        P[a] = run;
        run = run * gDec[chain * NCH + c] + tmp;
    }
}

__global__ __launch_bounds__(256) void n_combine_kernel(float* __restrict__ nP,
        const float* __restrict__ gDec) {
    int gidx = blockIdx.x * 256 + threadIdx.x;
    int chain = gidx >> 7, d = gidx & 127;
    float run = 0.f;
    for (int c = 0; c < NCH; c++) {
        size_t a = (size_t)(c * 32 + chain) * 128 + d;
        float tmp = nP[a];
        nP[a] = run;
        run = run * gDec[chain * NCH + c] + tmp;
    }
}

// Kernel C: per-chunk outputs.
__global__ __launch_bounds__(512, 2) void chunk_out_kernel(const float* __restrict__ qq,
        const float* __restrict__ kk, const float* __restrict__ vv,
        const float* __restrict__ gG, const float* __restrict__ gM,
        const float* __restrict__ gMb, const float* __restrict__ P,
        const float* __restrict__ nP, float* __restrict__ hs) {
    int c = blockIdx.x, chain = blockIdx.y;
    int b = chain >> 3, h = chain & 7;
    int t0 = c * 64;
    int nvalid = min(64, TT - t0);
    __shared__ __align__(16) float smem[13440];
    float* sG  = smem;          // 64
    float* sM  = smem + 64;     // 64
    float* sWr = smem + 128;    // 64
    float* sInv= smem + 192;    // 64
    float* sNb = smem + 256;    // 128
    float (*sD)[68] = (float(*)[68])(smem + 384);          // 64x68
    float* scr = smem + 384 + 64 * 68;                     // scratch base (4736)
    int tid = threadIdx.x;

    float Mbprev = (c > 0) ? gMb[chain * NCH + c - 1] : 0.f;
    if (tid < 64) {
        bool val = tid < nvalid;
        sG[tid] = val ? gG[chain * TT + t0 + tid] : -1e30f;
        float Mv = val ? gM[chain * TT + t0 + tid] : 1e30f;
        sM[tid] = Mv;
        sWr[tid] = val ? __expf(Mbprev - Mv) : 0.f;
    }
    if (tid >= 128 && tid < 256) sNb[tid - 128] = nP[(size_t)(c * 32 + chain) * 128 + (tid - 128)];
    __syncthreads();

    int e = tid & 127, rg = (tid >> 7) * 16;   // 4 row-groups x 16 rows
    float acc[16];
#pragma unroll
    for (int r = 0; r < 16; r++) acc[r] = 0.f;

    // ---- Phase 0: inter H = Q @ CB
    {
        float (*sCB)[128] = (float(*)[128])(smem + 384);          // 64x128
        float (*Qh2)[68]  = (float(*)[68])(smem + 384 + 64*128);  // 64x68
        const float* CBbase = P + (((size_t)(c * 32 + chain)) << 14);
        for (int dh = 0; dh < 2; dh++) {
            {
                int dr = tid >> 5, dc = (tid & 31) * 4;
#pragma unroll
                for (int rr = 0; rr < 4; rr++) {
                    int d = dr + rr * 16;
                    *(float4*)&sCB[d][dc] = *(const float4*)(CBbase + (size_t)(dh * 64 + d) * 128 + dc);
                }
                int lr = tid >> 3, c0 = (tid & 7) * 8;
                bool val = lr < nvalid;
                size_t gb = ((size_t)(b * TT + t0 + lr)) * IN + h * DHd + dh * 64 + c0;
                float4 qv0 = val ? *(const float4*)(qq + gb)     : make_float4(0.f,0.f,0.f,0.f);
                float4 qv1 = val ? *(const float4*)(qq + gb + 4) : make_float4(0.f,0.f,0.f,0.f);
                *(float4*)&Qh2[lr][c0]     = qv0;
                *(float4*)&Qh2[lr][c0 + 4] = qv1;
            }
            __syncthreads();
#pragma unroll 1
            for (int dd4 = 0; dd4 < 16; dd4++) {
                float c0v = sCB[dd4 * 4 + 0][e];
                float c1v = sCB[dd4 * 4 + 1][e];
                float c2v = sCB[dd4 * 4 + 2][e];
                float c3v = sCB[dd4 * 4 + 3][e];
#pragma unroll
                for (int r = 0; r < 16; r++) {
                    float4 qf = *(const float4*)&Qh2[rg + r][dd4 * 4];
                    acc[r] += qf.x * c0v + qf.y * c1v + qf.z * c2v + qf.w * c3v;
                }
            }
            __syncthreads();
        }
#pragma unroll
        for (int r = 0; r < 16; r++) acc[r] *= sWr[rg + r];
    }

    // ---- Phase 1: S = Q K^T; weights -> sD; qnb
    float qnb = 0.f;
    {
        float (*Qh)[68] = (float(*)[68])scr;               // 64x68
        float (*Kh)[68] = (float(*)[68])(scr + 64 * 68);   // 64x68
        int j = tid & 63, ig = (tid >> 6) * 8;
        float accS[8];
#pragma unroll
        for (int i = 0; i < 8; i++) accS[i] = 0.f;
        for (int dh = 0; dh < 2; dh++) {
            {
                int lr = tid >> 3, c0 = (tid & 7) * 8;
                bool val = lr < nvalid;
                size_t gb = ((size_t)(b * TT + t0 + lr)) * IN + h * DHd + dh * 64 + c0;
                float4 qv0 = val ? *(const float4*)(qq + gb)     : make_float4(0.f,0.f,0.f,0.f);
                float4 qv1 = val ? *(const float4*)(qq + gb + 4) : make_float4(0.f,0.f,0.f,0.f);
                float4 kv0 = val ? *(const float4*)(kk + gb)     : make_float4(0.f,0.f,0.f,0.f);
                float4 kv1 = val ? *(const float4*)(kk + gb + 4) : make_float4(0.f,0.f,0.f,0.f);
                *(float4*)&Qh[lr][c0]     = qv0;
                *(float4*)&Qh[lr][c0 + 4] = qv1;
                *(float4*)&Kh[lr][c0]     = kv0;
                *(float4*)&Kh[lr][c0 + 4] = kv1;
            }
            __syncthreads();
#pragma unroll 1
            for (int d4 = 0; d4 < 16; d4++) {
                float4 kf = *(const float4*)&Kh[j][d4 * 4];
#pragma unroll
                for (int i = 0; i < 8; i++) {
                    float4 qf = *(const float4*)&Qh[ig + i][d4 * 4];
                    accS[i] += qf.x * kf.x + qf.y * kf.y + qf.z * kf.z + qf.w * kf.w;
                }
            }
            if (tid < 64) {
#pragma unroll 1
                for (int d4 = 0; d4 < 16; d4++) {
                    float4 qf = *(const float4*)&Qh[tid][d4 * 4];
                    float4 nb = *(const float4*)&sNb[dh * 64 + d4 * 4];
                    qnb += qf.x * nb.x + qf.y * nb.y + qf.z * nb.z + qf.w * nb.w;
                }
            }
            __syncthreads();
        }
        float Gj = sG[j];
#pragma unroll
        for (int i = 0; i < 8; i++) {
            int irow = ig + i;
            float w = (j <= irow) ? __expf(Gj - sM[irow]) : 0.f;
            sD[irow][j] = accS[i] * w;
        }
    }
    __syncthreads();

    // ---- Phase 2: denominators
    if (tid < 64) {
        float s = 0.f;
#pragma unroll 1
        for (int j4 = 0; j4 < 16; j4++) {
            float4 d = *(const float4*)&sD[tid][j4 * 4];
            s += d.x + d.y + d.z + d.w;
        }
        float den = s + sWr[tid] * qnb;
        sInv[tid] = 1.f / fmaxf(fabsf(den), 1.f);
    }
    __syncthreads();

    // ---- Phase 3: intra H += D @ V
    {
        float (*sV)[128] = (float(*)[128])scr;             // 64x128
        int lrow = tid >> 5, lcol = (tid & 31) * 4;
#pragma unroll
        for (int rr = 0; rr < 4; rr++) {
            int r = lrow + rr * 16;
            float4 vvv = make_float4(0.f,0.f,0.f,0.f);
            if (r < nvalid) {
                size_t gb = ((size_t)(b * TT + t0 + r)) * IN + h * DHd + lcol;
                vvv = *(const float4*)(vv + gb);
            }
            *(float4*)&sV[r][lcol] = vvv;
        }
        __syncthreads();
#pragma unroll 1
        for (int jj4 = 0; jj4 < 16; jj4++) {
            float v0 = sV[jj4 * 4 + 0][e];
            float v1 = sV[jj4 * 4 + 1][e];
            float v2 = sV[jj4 * 4 + 2][e];
            float v3 = sV[jj4 * 4 + 3][e];
#pragma unroll
            for (int r = 0; r < 16; r++) {
                float4 d = *(const float4*)&sD[rg + r][jj4 * 4];
                acc[r] += d.x * v0 + d.y * v1 + d.z * v2 + d.w * v3;
            }
        }
    }

    // ---- store
#pragma unroll
    for (int r = 0; r < 16; r++) {
        int irow = rg + r;
        if (irow < nvalid)
            hs[((size_t)(b * TT + t0 + irow)) * IN + h * DHd + e] = acc[r] * sInv[irow];
    }
}

// ---------------------------------------------------------------- per-head norm * hn_s * silu(z)
__global__ __launch_bounds__(64) void headnorm_kernel(const float* __restrict__ hs,
                                                      const float* __restrict__ hn,
                                                      const float* __restrict__ up,
                                                      float* __restrict__ out) {
    int idx = blockIdx.x;
    int h = idx & 7, bt = idx >> 3;
    int tid = threadIdx.x;
    size_t base = (size_t)bt * IN + h * DHd;
    float x0 = hs[base + tid], x1 = hs[base + 64 + tid];
    float sum = x0 + x1, sq = x0 * x0 + x1 * x1;
#pragma unroll
    for (int o = 32; o > 0; o >>= 1) { sum += __shfl_xor(sum, o); sq += __shfl_xor(sq, o); }
    float mu = sum / DHd, var = sq / DHd - mu * mu, inv = rsqrtf(var + EPSV);
    size_t zb = (size_t)bt * (2 * IN) + IN + h * DHd;
    out[base + tid]      = (x0 - mu) * inv * hn[h * DHd + tid]      * siluf(up[zb + tid]);
    out[base + 64 + tid] = (x1 - mu) * inv * hn[h * DHd + 64 + tid] * siluf(up[zb + 64 + tid]);
}

// ---------------------------------------------------------------- head: LN+ReLU of cls rows -> vcls
__global__ __launch_bounds__(256) void cls_ln_kernel(const float* __restrict__ hbuf,
                                                     const float* __restrict__ s, const float* __restrict__ bb,
                                                     float* __restrict__ vcls) {
    int b = blockIdx.x, tid = threadIdx.x;
    const float* r = hbuf + ((size_t)b * TT + TT - 1) * Dm;
    __shared__ float s1[4], s2[4];
    float x0 = r[tid], x1 = r[tid + 256];
    float sum = x0 + x1, sq = x0 * x0 + x1 * x1;
#pragma unroll
    for (int o = 32; o > 0; o >>= 1) { sum += __shfl_xor(sum, o); sq += __shfl_xor(sq, o); }
    if ((tid & 63) == 0) { s1[tid >> 6] = sum; s2[tid >> 6] = sq; }
    __syncthreads();
    sum = s1[0] + s1[1] + s1[2] + s1[3];
    sq  = s2[0] + s2[1] + s2[2] + s2[3];
    float mu = sum / Dm, var = sq / Dm - mu * mu, inv = rsqrtf(var + EPSV);
    float n0 = (x0 - mu) * inv * s[tid] + bb[tid];
    float n1 = (x1 - mu) * inv * s[tid + 256] + bb[tid + 256];
    vcls[b * Dm + tid]       = fmaxf(n0, 0.f);
    vcls[b * Dm + tid + 256] = fmaxf(n1, 0.f);
}

// ---------------------------------------------------------------- head: FC. 16 blocks x 64 classes,
// all 4 batches per block (fw element reused 4x). Thread = (j lane, k-chunk of 128).
__global__ __launch_bounds__(256) void fc_kernel(const float* __restrict__ vcls,
                                                 const float* __restrict__ fw,
                                                 const float* __restrict__ fb,
                                                 float* __restrict__ out) {
    __shared__ float svc[Bsz][Dm];
    __shared__ float sred[4][256];
    int tid = threadIdx.x;
    int j0 = blockIdx.x * 64;
    // stage vcls: 2048 floats
    {
        const float4* src = (const float4*)vcls;
        float4* dst = (float4*)&svc[0][0];
        dst[tid] = src[tid];
        dst[tid + 256] = src[tid + 256];
    }
    __syncthreads();
    int j = j0 + (tid & 63);
    int chunk = tid >> 6;            // 4 chunks x 128 K
    int kbase = chunk * 128;
    float a0 = 0.f, a1 = 0.f, a2 = 0.f, a3 = 0.f;
    if (j < NCc) {
        const float* fwp = fw + (size_t)kbase * NCc + j;
#pragma unroll 4
        for (int kk = 0; kk < 128; kk++) {
            float w = fwp[(size_t)kk * NCc];
            a0 += svc[0][kbase + kk] * w;
            a1 += svc[1][kbase + kk] * w;
            a2 += svc[2][kbase + kk] * w;
            a3 += svc[3][kbase + kk] * w;
        }
    }
    int jl = tid & 63;
    sred[chunk][jl * 4 + 0] = a0;
    sred[chunk][jl * 4 + 1] = a1;
    sred[chunk][jl * 4 + 2] = a2;
    sred[chunk][jl * 4 + 3] = a3;
    __syncthreads();
    if (tid < 64) {
        int jj = j0 + tid;
        if (jj < NCc) {
            float bias = fb[jj];
#pragma unroll
            for (int b = 0; b < Bsz; b++) {
                float v = sred[0][tid * 4 + b] + sred[1][tid * 4 + b]
                        + sred[2][tid * 4 + b] + sred[3][tid * 4 + b];
                out[b * NCc + jj] = v + bias;
            }
        }
    }
}

// ---------------------------------------------------------------- launch
extern "C" void kernel_launch(void* const* d_in, const int* in_sizes, int n_in,
                              void* d_out, int out_size, void* d_ws, size_t ws_size,
                              hipStream_t stream) {
    const float* x      = (const float*)d_in[0];
    const float* cls    = (const float*)d_in[1];
    const float* ln_s   = (const float*)d_in[2];
    const float* ln_b   = (const float*)d_in[3];
    const float* w_up   = (const float*)d_in[4];
    const float* b_up   = (const float*)d_in[5];
    const float* conv_k = (const float*)d_in[6];
    const float* conv_b = (const float*)d_in[7];
    const float* w_q    = (const float*)d_in[8];
    const float* w_k    = (const float*)d_in[9];
    const float* w_v    = (const float*)d_in[10];
    const float* w_ig   = (const float*)d_in[11];
    const float* b_ig   = (const float*)d_in[12];
    const float* w_fg   = (const float*)d_in[13];
    const float* b_fg   = (const float*)d_in[14];
    const float* hn_s   = (const float*)d_in[15];
    const float* w_down = (const float*)d_in[16];
    const float* b_down = (const float*)d_in[17];
    const float* fcls   = (const float*)d_in[18];
    const float* fclb   = (const float*)d_in[19];
    const float* fc_w   = (const float*)d_in[20];
    const float* fc_b   = (const float*)d_in[21];
    float* out = (float*)d_out;

    float* ws = (float*)d_ws;
    size_t off = 0;
    float* f_h  = ws + off; off += (size_t)ROWS * Dm;
    float* f_xn = ws + off; off += (size_t)ROWS * Dm;
    float* f_up = ws + off; off += (size_t)ROWS * 2 * IN;
    float* f_xc = ws + off; off += (size_t)ROWS * IN;
    float* f_q  = ws + off; off += (size_t)ROWS * IN;
    float* f_k  = ws + off; off += (size_t)ROWS * IN;
    float* f_v  = ws + off; off += (size_t)ROWS * IN;
    float* f_hs = ws + off; off += (size_t)ROWS * IN;
    float* f_ip = ws + off; off += (size_t)ROWS * NHh;
    float* f_fp = ws + off; off += (size_t)ROWS * NHh;
    float* g_G  = ws + off; off += 32 * TT;
    float* g_M  = ws + off; off += 32 * TT;
    float* g_Mb = ws + off; off += 32 * NCH;
    float* g_De = ws + off; off += 32 * NCH;
    float* g_P  = ws + off; off += (size_t)NCH * 32 * DHd * DHd;
    float* g_nP = ws + off; off += (size_t)NCH * 32 * DHd;
    float* f_vc = ws + off; off += Bsz * Dm;

    const float kscale = 0.08838834764831845f; // DH^-0.5
    const int MB = (ROWS + 127) / 128;         // 17

    concat_kernel<<<(ROWS * Dm + 255) / 256, 256, 0, stream>>>(x, cls, f_h);

    for (int blk = 0; blk < 2; blk++) {
        const float* p_ln_s = ln_s + blk * Dm;
        const float* p_ln_b = ln_b + blk * Dm;
        const float* p_wup  = w_up + (size_t)blk * Dm * 2 * IN;
        const float* p_bup  = b_up + (size_t)blk * 2 * IN;
        const float* p_ck   = conv_k + (size_t)blk * IN * KK;
        const float* p_cb   = conv_b + (size_t)blk * IN;
        const float* p_wq   = w_q + (size_t)blk * IN * IN;
        const float* p_wk   = w_k + (size_t)blk * IN * IN;
        const float* p_wv   = w_v + (size_t)blk * IN * IN;
        const float* p_wig  = w_ig + (size_t)blk * IN * NHh;
        const float* p_big  = b_ig + (size_t)blk * NHh;
        const float* p_wfg  = w_fg + (size_t)blk * IN * NHh;
        const float* p_bfg  = b_fg + (size_t)blk * NHh;
        const float* p_hns  = hn_s + (size_t)blk * NHh * DHd;
        const float* p_wd   = w_down + (size_t)blk * IN * Dm;
        const float* p_bd   = b_down + (size_t)blk * Dm;

        ln_kernel<<<ROWS, 256, 0, stream>>>(f_h, p_ln_s, p_ln_b, f_xn);

        gemm_mfma_kernel<<<dim3(2 * IN / 128, MB), 256, 0, stream>>>(
            f_xn, Dm, p_wup, 2 * IN, p_bup, nullptr, 0, f_up, 2 * IN, ROWS, Dm, 1.f);

        conv_silu_kernel<<<(ROWS * IN + 255) / 256, 256, 0, stream>>>(f_up, p_ck, p_cb, f_xc);

        gemm_mfma_kernel<<<dim3(IN / 128, MB), 256, 0, stream>>>(
            f_xc, IN, p_wq, IN, nullptr, nullptr, 0, f_q, IN, ROWS, IN, 1.f);
        gemm_mfma_kernel<<<dim3(IN / 128, MB), 256, 0, stream>>>(
            f_xc, IN, p_wk, IN, nullptr, nullptr, 0, f_k, IN, ROWS, IN, kscale);
        gemm_mfma_kernel<<<dim3(IN / 128, MB), 256, 0, stream>>>(
            f_up, 2 * IN, p_wv, IN, nullptr, nullptr, 0, f_v, IN, ROWS, IN, 1.f);

        gates_kernel<<<ROWS, 256, 0, stream>>>(f_xc, p_wig, p_big, p_wfg, p_bfg, f_ip, f_fp);

        // chunkwise-parallel mLSTM
        gate_scan_kernel<<<32, 64, 0, stream>>>(f_ip, f_fp, g_G, g_M, g_Mb, g_De);
        chunk_state_kernel<<<dim3(NCH, 32), 256, 0, stream>>>(f_k, f_v, g_G, g_Mb, g_P, g_nP);
        chunk_combine_kernel<<<32 * 64, 256, 0, stream>>>(g_P, g_De);
        n_combine_kernel<<<16, 256, 0, stream>>>(g_nP, g_De);
        chunk_out_kernel<<<dim3(NCH, 32), 512, 0, stream>>>(f_q, f_k, f_v, g_G, g_M, g_Mb,
                                                            g_P, g_nP, f_hs);

        headnorm_kernel<<<ROWS * NHh, 64, 0, stream>>>(f_hs, p_hns, f_up, f_xc);

        gemm_mfma_kernel<<<dim3(Dm / 128, MB), 256, 0, stream>>>(
            f_xc, IN, p_wd, Dm, p_bd, f_h, Dm, f_h, Dm, ROWS, IN, 1.f);
    }

    cls_ln_kernel<<<Bsz, 256, 0, stream>>>(f_h, fcls, fclb, f_vc);
    fc_kernel<<<(NCc + 63) / 64, 256, 0, stream>>>(f_vc, fc_w, fc_b, out);
}

// Round 10
// 690.520 us; speedup vs baseline: 4.6318x; 1.3776x over previous
//
#include <hip/hip_runtime.h>

// ---------------------------------------------------------------- constants
#define EPSV 1e-5f
constexpr int Bsz = 4, T0 = 512, Dm = 512, TT = 513, NHh = 8, KK = 4;
constexpr int IN = 1024, DHd = 128, NCc = 1000;
constexpr int ROWS = Bsz * TT; // 2052
constexpr int NCH = 9;         // chunks of 64: 8*64 + 1 = 513

typedef __attribute__((ext_vector_type(8))) short bf16x8;
typedef __attribute__((ext_vector_type(4))) float f32x4;
typedef __attribute__((ext_vector_type(4))) unsigned short ushort4v;

__device__ __forceinline__ float siluf(float x) { return x / (1.f + __expf(-x)); }
__device__ __forceinline__ unsigned short f2bf(float f) {
    unsigned int u = __float_as_uint(f);
    u = (u + 0x7FFFu + ((u >> 16) & 1u)) >> 16;
    return (unsigned short)u;
}

// ---------------------------------------------------------------- concat x + cls
__global__ __launch_bounds__(256) void concat_kernel(const float* __restrict__ x,
                                                     const float* __restrict__ cls,
                                                     float* __restrict__ h) {
    int idx = blockIdx.x * 256 + threadIdx.x;
    if (idx >= Bsz * TT * Dm) return;
    int d = idx & (Dm - 1);
    int bt = idx >> 9;
    int t = bt % TT, b = bt / TT;
    h[idx] = (t < T0) ? x[((size_t)(b * T0 + t)) * Dm + d] : cls[d];
}

// ---------------------------------------------------------------- LayerNorm rows of D=512
__global__ __launch_bounds__(256) void ln_kernel(const float* __restrict__ in,
                                                 const float* __restrict__ s,
                                                 const float* __restrict__ bb,
                                                 float* __restrict__ out) {
    int row = blockIdx.x, tid = threadIdx.x;
    const float* r = in + (size_t)row * Dm;
    __shared__ float s1[4], s2[4];
    float x0 = r[tid], x1 = r[tid + 256];
    float sum = x0 + x1, sq = x0 * x0 + x1 * x1;
#pragma unroll
    for (int o = 32; o > 0; o >>= 1) { sum += __shfl_xor(sum, o); sq += __shfl_xor(sq, o); }
    if ((tid & 63) == 0) { s1[tid >> 6] = sum; s2[tid >> 6] = sq; }
    __syncthreads();
    sum = s1[0] + s1[1] + s1[2] + s1[3];
    sq  = s2[0] + s2[1] + s2[2] + s2[3];
    float mu = sum / Dm, var = sq / Dm - mu * mu, inv = rsqrtf(var + EPSV);
    out[(size_t)row * Dm + tid]       = (x0 - mu) * inv * s[tid] + bb[tid];
    out[(size_t)row * Dm + tid + 256] = (x1 - mu) * inv * s[tid + 256] + bb[tid + 256];
}

// ---------------------------------------------------------------- MFMA bf16 GEMM tile body
__device__ __forceinline__ void gemm_tile_body(const float* __restrict__ A, int lda,
                                               const float* __restrict__ W, int ldw,
                                               const float* __restrict__ bias,
                                               const float* __restrict__ resid, int ldr,
                                               float* __restrict__ Cout, int ldc,
                                               int M, int Kd, float scale,
                                               int m0, int n0,
                                               unsigned short (*As)[40],
                                               unsigned short (*Bs)[40]) {
    int tid = threadIdx.x;
    int wave = tid >> 6, lane = tid & 63;
    int wm = (wave >> 1) * 64, wn = (wave & 1) * 64;
    int lrow = lane & 15, lquad = lane >> 4;

    f32x4 acc[4][4];
#pragma unroll
    for (int i = 0; i < 4; i++)
#pragma unroll
        for (int j = 0; j < 4; j++)
#pragma unroll
            for (int r = 0; r < 4; r++) acc[i][j][r] = 0.f;

    int am = tid >> 1, ak = (tid & 1) * 16;
    int bn = tid & 127, bk = (tid >> 7) * 16;

    for (int k0 = 0; k0 < Kd; k0 += 32) {
        {
            int gm = m0 + am;
            float4 a0, a1, a2, a3;
            if (gm < M) {
                const float4* ap = (const float4*)(A + (size_t)gm * lda + k0 + ak);
                a0 = ap[0]; a1 = ap[1]; a2 = ap[2]; a3 = ap[3];
            } else {
                a0 = a1 = a2 = a3 = make_float4(0.f, 0.f, 0.f, 0.f);
            }
            ushort4v t0 = {f2bf(a0.x), f2bf(a0.y), f2bf(a0.z), f2bf(a0.w)};
            ushort4v t1 = {f2bf(a1.x), f2bf(a1.y), f2bf(a1.z), f2bf(a1.w)};
            ushort4v t2 = {f2bf(a2.x), f2bf(a2.y), f2bf(a2.z), f2bf(a2.w)};
            ushort4v t3 = {f2bf(a3.x), f2bf(a3.y), f2bf(a3.z), f2bf(a3.w)};
            *(ushort4v*)&As[am][ak + 0]  = t0;
            *(ushort4v*)&As[am][ak + 4]  = t1;
            *(ushort4v*)&As[am][ak + 8]  = t2;
            *(ushort4v*)&As[am][ak + 12] = t3;
        }
        {
            const float* wp = W + (size_t)(k0 + bk) * ldw + n0 + bn;
            unsigned short tmp[16];
#pragma unroll
            for (int j = 0; j < 16; j++) tmp[j] = f2bf(wp[(size_t)j * ldw]);
#pragma unroll
            for (int j4 = 0; j4 < 4; j4++) {
                ushort4v tv = {tmp[j4 * 4], tmp[j4 * 4 + 1], tmp[j4 * 4 + 2], tmp[j4 * 4 + 3]};
                *(ushort4v*)&Bs[bn][bk + j4 * 4] = tv;
            }
        }
        __syncthreads();
        bf16x8 afr[4], bfr[4];
#pragma unroll
        for (int mt = 0; mt < 4; mt++)
            afr[mt] = *(const bf16x8*)&As[wm + mt * 16 + lrow][lquad * 8];
#pragma unroll
        for (int nt = 0; nt < 4; nt++)
            bfr[nt] = *(const bf16x8*)&Bs[wn + nt * 16 + lrow][lquad * 8];
#pragma unroll
        for (int mt = 0; mt < 4; mt++)
#pragma unroll
            for (int nt = 0; nt < 4; nt++)
                acc[mt][nt] = __builtin_amdgcn_mfma_f32_16x16x32_bf16(
                    afr[mt], bfr[nt], acc[mt][nt], 0, 0, 0);
        __syncthreads();
    }

#pragma unroll
    for (int mt = 0; mt < 4; mt++) {
#pragma unroll
        for (int r = 0; r < 4; r++) {
            int gm = m0 + wm + mt * 16 + lquad * 4 + r;
            if (gm >= M) continue;
#pragma unroll
            for (int nt = 0; nt < 4; nt++) {
                int gn = n0 + wn + nt * 16 + lrow;
                float v = acc[mt][nt][r] * scale;
                if (bias) v += bias[gn];
                if (resid) v += resid[(size_t)gm * ldr + gn];
                Cout[(size_t)gm * ldc + gn] = v;
            }
        }
    }
}

__global__ __launch_bounds__(256) void gemm_mfma_kernel(const float* __restrict__ A, int lda,
                                                        const float* __restrict__ W, int ldw,
                                                        const float* __restrict__ bias,
                                                        const float* __restrict__ resid, int ldr,
                                                        float* __restrict__ Cout, int ldc,
                                                        int M, int Kd, float scale) {
    __shared__ __align__(16) unsigned short As[128][40];
    __shared__ __align__(16) unsigned short Bs[128][40];
    gemm_tile_body(A, lda, W, ldw, bias, resid, ldr, Cout, ldc, M, Kd, scale,
                   blockIdx.y * 128, blockIdx.x * 128, As, Bs);
}

// q/k/v in ONE dispatch: blockIdx.x in [0,24): sel = x>>3 chooses {q,k,v}.
__global__ __launch_bounds__(256) void qkv_mfma_kernel(const float* __restrict__ xc,
                                                       const float* __restrict__ up,
                                                       const float* __restrict__ wq,
                                                       const float* __restrict__ wk,
                                                       const float* __restrict__ wv,
                                                       float* __restrict__ fq,
                                                       float* __restrict__ fk,
                                                       float* __restrict__ fv,
                                                       float kscale) {
    __shared__ __align__(16) unsigned short As[128][40];
    __shared__ __align__(16) unsigned short Bs[128][40];
    int sel = blockIdx.x >> 3, nx = blockIdx.x & 7;
    const float* A = (sel == 2) ? up : xc;
    int lda = (sel == 2) ? 2 * IN : IN;
    const float* W = (sel == 0) ? wq : (sel == 1) ? wk : wv;
    float* C = (sel == 0) ? fq : (sel == 1) ? fk : fv;
    float scale = (sel == 1) ? kscale : 1.f;
    gemm_tile_body(A, lda, W, IN, nullptr, nullptr, 0, C, IN, ROWS, IN, scale,
                   blockIdx.y * 128, nx * 128, As, Bs);
}

// ---------------------------------------------------------------- causal depthwise conv (K=4) + SiLU
__global__ __launch_bounds__(256) void conv_silu_kernel(const float* __restrict__ up,
                                                        const float* __restrict__ ck,
                                                        const float* __restrict__ cb,
                                                        float* __restrict__ xc) {
    int idx = blockIdx.x * 256 + threadIdx.x;
    if (idx >= ROWS * IN) return;
    int c = idx & (IN - 1);
    int bt = idx >> 10;
    int t = bt % TT, b = bt / TT;
    float acc = cb[c];
#pragma unroll
    for (int j = 0; j < KK; j++) {
        int tt = t - (KK - 1) + j;
        if (tt >= 0) acc += up[((size_t)(b * TT + tt)) * (2 * IN) + c] * ck[c * KK + j];
    }
    xc[idx] = siluf(acc);
}

// ---------------------------------------------------------------- gate weight transpose: wt[blk][g][k]
__global__ __launch_bounds__(256) void gate_w_transpose(const float* __restrict__ wig,
                                                        const float* __restrict__ wfg,
                                                        float* __restrict__ wt) {
    int idx = blockIdx.x * 256 + threadIdx.x;   // 0..32767
    int k = idx & 1023;
    int g = (idx >> 10) & 15;
    int blk = idx >> 14;
    const float* w = (g < 8) ? (wig + (size_t)blk * IN * NHh) : (wfg + (size_t)blk * IN * NHh);
    wt[idx] = w[k * NHh + (g & 7)];
}

// ---------------------------------------------------------------- gate projections (coalesced wt)
__global__ __launch_bounds__(256) void gates_kernel(const float* __restrict__ xc,
                                                    const float* __restrict__ wt,
                                                    const float* __restrict__ big,
                                                    const float* __restrict__ bfg,
                                                    float* __restrict__ ip, float* __restrict__ fp) {
    int row = blockIdx.x, tid = threadIdx.x;
    __shared__ float sx[IN];
    *(float4*)&sx[tid * 4] = *(const float4*)(xc + (size_t)row * IN + tid * 4);
    __syncthreads();
    int g = tid >> 4, l = tid & 15;
    const float* wrow = wt + g * IN;
    float acc = 0.f;
#pragma unroll
    for (int j = 0; j < 16; j++) {
        int k = j * 64 + l * 4;   // interleaved: lanes coalesce on wt, 2-way LDS alias (free)
        float4 w4 = *(const float4*)(wrow + k);
        float4 x4 = *(const float4*)&sx[k];
        acc += w4.x * x4.x + w4.y * x4.y + w4.z * x4.z + w4.w * x4.w;
    }
#pragma unroll
    for (int o = 8; o > 0; o >>= 1) acc += __shfl_down(acc, o, 16);
    if (l == 0) {
        if (g < 8) ip[(size_t)row * NHh + g] = acc + big[g];
        else       fp[(size_t)row * NHh + (g - 8)] = acc + bfg[g - 8];
    }
}

// ---------------------------------------------------------------- chunkwise mLSTM
// Kernel A (wave-parallel prefix scan): one wave per chain.
__global__ __launch_bounds__(64) void gate_scan_kernel(const float* __restrict__ ip,
        const float* __restrict__ fp, float* __restrict__ gG, float* __restrict__ gM,
        float* __restrict__ gMb, float* __restrict__ gDec) {
    constexpr int PER = 9; // 64*9 = 576 >= 513
    int chain = blockIdx.x;
    int b = chain >> 3, h = chain & 7;
    int lane = threadIdx.x;
    int tbase = lane * PER;
    float lcs[PER];
    float gi[PER];
    float csum = 0.f;
#pragma unroll
    for (int i = 0; i < PER; i++) {
        int t = tbase + i;
        float fpv = 0.f, ipv = 0.f;
        if (t < TT) {
            size_t gidx = (size_t)(b * TT + t) * NHh + h;
            fpv = fp[gidx]; ipv = ip[gidx];
        }
        float flv = (fpv >= 0.f) ? -log1pf(__expf(-fpv)) : (fpv - log1pf(__expf(fpv)));
        if (t >= TT) flv = 0.f;
        csum += flv;
        lcs[i] = csum;
        gi[i] = ipv;
    }
    float ps = csum;
#pragma unroll
    for (int o = 1; o < 64; o <<= 1) {
        float v = __shfl_up(ps, o);
        if (lane >= o) ps += v;
    }
    float Fexcl = ps - csum;
    float G[PER];
    float cmax = -1e30f;
#pragma unroll
    for (int i = 0; i < PER; i++) {
        int t = tbase + i;
        G[i] = (t < TT) ? (gi[i] - (Fexcl + lcs[i])) : -1e30f;
        cmax = fmaxf(cmax, G[i]);
        lcs[i] = cmax;
    }
    float pm = cmax;
#pragma unroll
    for (int o = 1; o < 64; o <<= 1) {
        float v = __shfl_up(pm, o);
        if (lane >= o) pm = fmaxf(pm, v);
    }
    float Me = __shfl_up(pm, 1);
    if (lane == 0) Me = -1e30f;
    __shared__ float sMb[NCH];
#pragma unroll
    for (int i = 0; i < PER; i++) {
        int t = tbase + i;
        if (t < TT) {
            float Mt = fmaxf(0.f, fmaxf(Me, lcs[i]));
            gG[chain * TT + t] = G[i];
            gM[chain * TT + t] = Mt;
            if (((t & 63) == 63) || t == TT - 1) sMb[t >> 6] = Mt;
        }
    }
    __syncthreads();
    if (lane < NCH) {
        float Mb = sMb[lane];
        float Mbp = (lane == 0) ? 0.f : sMb[lane - 1];
        gMb[chain * NCH + lane] = Mb;
        gDec[chain * NCH + lane] = __expf(Mbp - Mb);
    }
}

// Kernel B1: per-chunk local state P[d][e] = sum_j exp(G_j - Mb_c) k_j[d] v_j[e]
__global__ __launch_bounds__(256) void chunk_state_kernel(const float* __restrict__ kk,
        const float* __restrict__ vv, const float* __restrict__ gG,
        const float* __restrict__ gMb, float* __restrict__ P, float* __restrict__ nP) {
    int c = blockIdx.x, chain = blockIdx.y;
    int b = chain >> 3, h = chain & 7;
    int t0 = c * 64;
    int nvalid = min(64, TT - t0);
    __shared__ float sK[32][128], sV[32][128], sw[64];
    int tid = threadIdx.x;
    if (tid < 64) {
        float Mb = gMb[chain * NCH + c];
        sw[tid] = (tid < nvalid) ? __expf(gG[chain * TT + t0 + tid] - Mb) : 0.f;
    }
    int e = tid & 127, dg = (tid >> 7) * 64;
    float4 acc[16];
#pragma unroll
    for (int i = 0; i < 16; i++) acc[i] = make_float4(0.f, 0.f, 0.f, 0.f);
    float na = 0.f;
    for (int jh = 0; jh < 2; jh++) {
        int lrow = tid >> 5, lcol = (tid & 31) * 4;
        for (int rr = 0; rr < 4; rr++) {
            int r = lrow + rr * 8;
            int gr = jh * 32 + r;
            float4 kv = make_float4(0.f,0.f,0.f,0.f), vvv = kv;
            if (gr < nvalid) {
                size_t gb = ((size_t)(b * TT + t0 + gr)) * IN + h * DHd + lcol;
                kv = *(const float4*)(kk + gb);
                vvv = *(const float4*)(vv + gb);
            }
            *(float4*)&sK[r][lcol] = kv;
            *(float4*)&sV[r][lcol] = vvv;
        }
        __syncthreads();
        int jmax = min(32, nvalid - jh * 32);
#pragma unroll 1
        for (int j = 0; j < jmax; j++) {
            float wvj = sw[jh * 32 + j] * sV[j][e];
            const float4* kr = (const float4*)&sK[j][dg];
#pragma unroll
            for (int d4 = 0; d4 < 16; d4++) {
                float4 kq = kr[d4];
                acc[d4].x += kq.x * wvj; acc[d4].y += kq.y * wvj;
                acc[d4].z += kq.z * wvj; acc[d4].w += kq.w * wvj;
            }
        }
        if (tid < 128) {
#pragma unroll 1
            for (int j = 0; j < jmax; j++) na += sw[jh * 32 + j] * sK[j][tid];
        }
        __syncthreads();
    }
    float* Pbase = P + (((size_t)(c * 32 + chain)) << 14);
#pragma unroll
    for (int d4 = 0; d4 < 16; d4++) {
        Pbase[(size_t)(dg + d4 * 4 + 0) * 128 + e] = acc[d4].x;
        Pbase[(size_t)(dg + d4 * 4 + 1) * 128 + e] = acc[d4].y;
        Pbase[(size_t)(dg + d4 * 4 + 2) * 128 + e] = acc[d4].z;
        Pbase[(size_t)(dg + d4 * 4 + 3) * 128 + e] = acc[d4].w;
    }
    if (tid < 128) nP[(size_t)(c * 32 + chain) * 128 + tid] = na;
}

// Kernel B2: in-place exclusive combine over chunks.
__global__ __launch_bounds__(256) void chunk_combine_kernel(float* __restrict__ P,
        const float* __restrict__ gDec) {
    int chain = blockIdx.x >> 6;
    int idx = (blockIdx.x & 63) * 256 + threadIdx.x;
    float run = 0.f;
    for (int c = 0; c < NCH; c++) {
        size_t a = (((size_t)(c * 32 + chain)) << 14) + idx;
        float tmp = P[a];
        P[a] = run;
        run = run * gDec[chain * NCH + c] + tmp;
    }
}

__global__ __launch_bounds__(256) void n_combine_kernel(float* __restrict__ nP,
        const float* __restrict__ gDec) {
    int gidx = blockIdx.x * 256 + threadIdx.x;
    int chain = gidx >> 7, d = gidx & 127;
    float run = 0.f;
    for (int c = 0; c < NCH; c++) {
        size_t a = (size_t)(c * 32 + chain) * 128 + d;
        float tmp = nP[a];
        nP[a] = run;
        run = run * gDec[chain * NCH + c] + tmp;
    }
}

// Kernel C: per-chunk outputs.
__global__ __launch_bounds__(512, 2) void chunk_out_kernel(const float* __restrict__ qq,
        const float* __restrict__ kk, const float* __restrict__ vv,
        const float* __restrict__ gG, const float* __restrict__ gM,
        const float* __restrict__ gMb, const float* __restrict__ P,
        const float* __restrict__ nP, float* __restrict__ hs) {
    int c = blockIdx.x, chain = blockIdx.y;
    int b = chain >> 3, h = chain & 7;
    int t0 = c * 64;
    int nvalid = min(64, TT - t0);
    __shared__ __align__(16) float smem[13440];
    float* sG  = smem;          // 64
    float* sM  = smem + 64;     // 64
    float* sWr = smem + 128;    // 64
    float* sInv= smem + 192;    // 64
    float* sNb = smem + 256;    // 128
    float (*sD)[68] = (float(*)[68])(smem + 384);          // 64x68
    float* scr = smem + 384 + 64 * 68;                     // scratch base
    int tid = threadIdx.x;

    float Mbprev = (c > 0) ? gMb[chain * NCH + c - 1] : 0.f;
    if (tid < 64) {
        bool val = tid < nvalid;
        sG[tid] = val ? gG[chain * TT + t0 + tid] : -1e30f;
        float Mv = val ? gM[chain * TT + t0 + tid] : 1e30f;
        sM[tid] = Mv;
        sWr[tid] = val ? __expf(Mbprev - Mv) : 0.f;
    }
    if (tid >= 128 && tid < 256) sNb[tid - 128] = nP[(size_t)(c * 32 + chain) * 128 + (tid - 128)];
    __syncthreads();

    int e = tid & 127, rg = (tid >> 7) * 16;   // 4 row-groups x 16 rows
    float acc[16];
#pragma unroll
    for (int r = 0; r < 16; r++) acc[r] = 0.f;

    // ---- Phase 0: inter H = Q @ CB
    {
        float (*sCB)[128] = (float(*)[128])(smem + 384);          // 64x128
        float (*Qh2)[68]  = (float(*)[68])(smem + 384 + 64*128);  // 64x68
        const float* CBbase = P + (((size_t)(c * 32 + chain)) << 14);
        for (int dh = 0; dh < 2; dh++) {
            {
                int dr = tid >> 5, dc = (tid & 31) * 4;
#pragma unroll
                for (int rr = 0; rr < 4; rr++) {
                    int d = dr + rr * 16;
                    *(float4*)&sCB[d][dc] = *(const float4*)(CBbase + (size_t)(dh * 64 + d) * 128 + dc);
                }
                int lr = tid >> 3, c0 = (tid & 7) * 8;
                bool val = lr < nvalid;
                size_t gb = ((size_t)(b * TT + t0 + lr)) * IN + h * DHd + dh * 64 + c0;
                float4 qv0 = val ? *(const float4*)(qq + gb)     : make_float4(0.f,0.f,0.f,0.f);
                float4 qv1 = val ? *(const float4*)(qq + gb + 4) : make_float4(0.f,0.f,0.f,0.f);
                *(float4*)&Qh2[lr][c0]     = qv0;
                *(float4*)&Qh2[lr][c0 + 4] = qv1;
            }
            __syncthreads();
#pragma unroll 1
            for (int dd4 = 0; dd4 < 16; dd4++) {
                float c0v = sCB[dd4 * 4 + 0][e];
                float c1v = sCB[dd4 * 4 + 1][e];
                float c2v = sCB[dd4 * 4 + 2][e];
                float c3v = sCB[dd4 * 4 + 3][e];
#pragma unroll
                for (int r = 0; r < 16; r++) {
                    float4 qf = *(const float4*)&Qh2[rg + r][dd4 * 4];
                    acc[r] += qf.x * c0v + qf.y * c1v + qf.z * c2v + qf.w * c3v;
                }
            }
            __syncthreads();
        }
#pragma unroll
        for (int r = 0; r < 16; r++) acc[r] *= sWr[rg + r];
    }

    // ---- Phase 1: S = Q K^T; weights -> sD; qnb
    float qnb = 0.f;
    {
        float (*Qh)[68] = (float(*)[68])scr;               // 64x68
        float (*Kh)[68] = (float(*)[68])(scr + 64 * 68);   // 64x68
        int j = tid & 63, ig = (tid >> 6) * 8;
        float accS[8];
#pragma unroll
        for (int i = 0; i < 8; i++) accS[i] = 0.f;
        for (int dh = 0; dh < 2; dh++) {
            {
                int lr = tid >> 3, c0 = (tid & 7) * 8;
                bool val = lr < nvalid;
                size_t gb = ((size_t)(b * TT + t0 + lr)) * IN + h * DHd + dh * 64 + c0;
                float4 qv0 = val ? *(const float4*)(qq + gb)     : make_float4(0.f,0.f,0.f,0.f);
                float4 qv1 = val ? *(const float4*)(qq + gb + 4) : make_float4(0.f,0.f,0.f,0.f);
                float4 kv0 = val ? *(const float4*)(kk + gb)     : make_float4(0.f,0.f,0.f,0.f);
                float4 kv1 = val ? *(const float4*)(kk + gb + 4) : make_float4(0.f,0.f,0.f,0.f);
                *(float4*)&Qh[lr][c0]     = qv0;
                *(float4*)&Qh[lr][c0 + 4] = qv1;
                *(float4*)&Kh[lr][c0]     = kv0;
                *(float4*)&Kh[lr][c0 + 4] = kv1;
            }
            __syncthreads();
#pragma unroll 1
            for (int d4 = 0; d4 < 16; d4++) {
                float4 kf = *(const float4*)&Kh[j][d4 * 4];
#pragma unroll
                for (int i = 0; i < 8; i++) {
                    float4 qf = *(const float4*)&Qh[ig + i][d4 * 4];
                    accS[i] += qf.x * kf.x + qf.y * kf.y + qf.z * kf.z + qf.w * kf.w;
                }
            }
            if (tid < 64) {
#pragma unroll 1
                for (int d4 = 0; d4 < 16; d4++) {
                    float4 qf = *(const float4*)&Qh[tid][d4 * 4];
                    float4 nb = *(const float4*)&sNb[dh * 64 + d4 * 4];
                    qnb += qf.x * nb.x + qf.y * nb.y + qf.z * nb.z + qf.w * nb.w;
                }
            }
            __syncthreads();
        }
        float Gj = sG[j];
#pragma unroll
        for (int i = 0; i < 8; i++) {
            int irow = ig + i;
            float w = (j <= irow) ? __expf(Gj - sM[irow]) : 0.f;
            sD[irow][j] = accS[i] * w;
        }
    }
    __syncthreads();

    // ---- Phase 2: denominators
    if (tid < 64) {
        float s = 0.f;
#pragma unroll 1
        for (int j4 = 0; j4 < 16; j4++) {
            float4 d = *(const float4*)&sD[tid][j4 * 4];
            s += d.x + d.y + d.z + d.w;
        }
        float den = s + sWr[tid] * qnb;
        sInv[tid] = 1.f / fmaxf(fabsf(den), 1.f);
    }
    __syncthreads();

    // ---- Phase 3: intra H += D @ V
    {
        float (*sV)[128] = (float(*)[128])scr;             // 64x128
        int lrow = tid >> 5, lcol = (tid & 31) * 4;
#pragma unroll
        for (int rr = 0; rr < 4; rr++) {
            int r = lrow + rr * 16;
            float4 vvv = make_float4(0.f,0.f,0.f,0.f);
            if (r < nvalid) {
                size_t gb = ((size_t)(b * TT + t0 + r)) * IN + h * DHd + lcol;
                vvv = *(const float4*)(vv + gb);
            }
            *(float4*)&sV[r][lcol] = vvv;
        }
        __syncthreads();
#pragma unroll 1
        for (int jj4 = 0; jj4 < 16; jj4++) {
            float v0 = sV[jj4 * 4 + 0][e];
            float v1 = sV[jj4 * 4 + 1][e];
            float v2 = sV[jj4 * 4 + 2][e];
            float v3 = sV[jj4 * 4 + 3][e];
#pragma unroll
            for (int r = 0; r < 16; r++) {
                float4 d = *(const float4*)&sD[rg + r][jj4 * 4];
                acc[r] += d.x * v0 + d.y * v1 + d.z * v2 + d.w * v3;
            }
        }
    }

    // ---- store
#pragma unroll
    for (int r = 0; r < 16; r++) {
        int irow = rg + r;
        if (irow < nvalid)
            hs[((size_t)(b * TT + t0 + irow)) * IN + h * DHd + e] = acc[r] * sInv[irow];
    }
}

// ---------------------------------------------------------------- per-head norm * hn_s * silu(z)
__global__ __launch_bounds__(64) void headnorm_kernel(const float* __restrict__ hs,
                                                      const float* __restrict__ hn,
                                                      const float* __restrict__ up,
                                                      float* __restrict__ out) {
    int idx = blockIdx.x;
    int h = idx & 7, bt = idx >> 3;
    int tid = threadIdx.x;
    size_t base = (size_t)bt * IN + h * DHd;
    float x0 = hs[base + tid], x1 = hs[base + 64 + tid];
    float sum = x0 + x1, sq = x0 * x0 + x1 * x1;
#pragma unroll
    for (int o = 32; o > 0; o >>= 1) { sum += __shfl_xor(sum, o); sq += __shfl_xor(sq, o); }
    float mu = sum / DHd, var = sq / DHd - mu * mu, inv = rsqrtf(var + EPSV);
    size_t zb = (size_t)bt * (2 * IN) + IN + h * DHd;
    out[base + tid]      = (x0 - mu) * inv * hn[h * DHd + tid]      * siluf(up[zb + tid]);
    out[base + 64 + tid] = (x1 - mu) * inv * hn[h * DHd + 64 + tid] * siluf(up[zb + 64 + tid]);
}

// ---------------------------------------------------------------- head: LN+ReLU of cls rows -> vcls
__global__ __launch_bounds__(256) void cls_ln_kernel(const float* __restrict__ hbuf,
                                                     const float* __restrict__ s, const float* __restrict__ bb,
                                                     float* __restrict__ vcls) {
    int b = blockIdx.x, tid = threadIdx.x;
    const float* r = hbuf + ((size_t)b * TT + TT - 1) * Dm;
    __shared__ float s1[4], s2[4];
    float x0 = r[tid], x1 = r[tid + 256];
    float sum = x0 + x1, sq = x0 * x0 + x1 * x1;
#pragma unroll
    for (int o = 32; o > 0; o >>= 1) { sum += __shfl_xor(sum, o); sq += __shfl_xor(sq, o); }
    if ((tid & 63) == 0) { s1[tid >> 6] = sum; s2[tid >> 6] = sq; }
    __syncthreads();
    sum = s1[0] + s1[1] + s1[2] + s1[3];
    sq  = s2[0] + s2[1] + s2[2] + s2[3];
    float mu = sum / Dm, var = sq / Dm - mu * mu, inv = rsqrtf(var + EPSV);
    float n0 = (x0 - mu) * inv * s[tid] + bb[tid];
    float n1 = (x1 - mu) * inv * s[tid + 256] + bb[tid + 256];
    vcls[b * Dm + tid]       = fmaxf(n0, 0.f);
    vcls[b * Dm + tid + 256] = fmaxf(n1, 0.f);
}

// ---------------------------------------------------------------- head: FC
__global__ __launch_bounds__(256) void fc_kernel(const float* __restrict__ vcls,
                                                 const float* __restrict__ fw,
                                                 const float* __restrict__ fb,
                                                 float* __restrict__ out) {
    __shared__ float svc[Bsz][Dm];
    __shared__ float sred[4][256];
    int tid = threadIdx.x;
    int j0 = blockIdx.x * 64;
    {
        const float4* src = (const float4*)vcls;
        float4* dst = (float4*)&svc[0][0];
        dst[tid] = src[tid];
        dst[tid + 256] = src[tid + 256];
    }
    __syncthreads();
    int j = j0 + (tid & 63);
    int chunk = tid >> 6;            // 4 chunks x 128 K
    int kbase = chunk * 128;
    float a0 = 0.f, a1 = 0.f, a2 = 0.f, a3 = 0.f;
    if (j < NCc) {
        const float* fwp = fw + (size_t)kbase * NCc + j;
#pragma unroll 4
        for (int kk = 0; kk < 128; kk++) {
            float w = fwp[(size_t)kk * NCc];
            a0 += svc[0][kbase + kk] * w;
            a1 += svc[1][kbase + kk] * w;
            a2 += svc[2][kbase + kk] * w;
            a3 += svc[3][kbase + kk] * w;
        }
    }
    int jl = tid & 63;
    sred[chunk][jl * 4 + 0] = a0;
    sred[chunk][jl * 4 + 1] = a1;
    sred[chunk][jl * 4 + 2] = a2;
    sred[chunk][jl * 4 + 3] = a3;
    __syncthreads();
    if (tid < 64) {
        int jj = j0 + tid;
        if (jj < NCc) {
            float bias = fb[jj];
#pragma unroll
            for (int b = 0; b < Bsz; b++) {
                float v = sred[0][tid * 4 + b] + sred[1][tid * 4 + b]
                        + sred[2][tid * 4 + b] + sred[3][tid * 4 + b];
                out[b * NCc + jj] = v + bias;
            }
        }
    }
}

// ---------------------------------------------------------------- launch
extern "C" void kernel_launch(void* const* d_in, const int* in_sizes, int n_in,
                              void* d_out, int out_size, void* d_ws, size_t ws_size,
                              hipStream_t stream) {
    const float* x      = (const float*)d_in[0];
    const float* cls    = (const float*)d_in[1];
    const float* ln_s   = (const float*)d_in[2];
    const float* ln_b   = (const float*)d_in[3];
    const float* w_up   = (const float*)d_in[4];
    const float* b_up   = (const float*)d_in[5];
    const float* conv_k = (const float*)d_in[6];
    const float* conv_b = (const float*)d_in[7];
    const float* w_q    = (const float*)d_in[8];
    const float* w_k    = (const float*)d_in[9];
    const float* w_v    = (const float*)d_in[10];
    const float* w_ig   = (const float*)d_in[11];
    const float* b_ig   = (const float*)d_in[12];
    const float* w_fg   = (const float*)d_in[13];
    const float* b_fg   = (const float*)d_in[14];
    const float* hn_s   = (const float*)d_in[15];
    const float* w_down = (const float*)d_in[16];
    const float* b_down = (const float*)d_in[17];
    const float* fcls   = (const float*)d_in[18];
    const float* fclb   = (const float*)d_in[19];
    const float* fc_w   = (const float*)d_in[20];
    const float* fc_b   = (const float*)d_in[21];
    float* out = (float*)d_out;

    float* ws = (float*)d_ws;
    size_t off = 0;
    float* f_h  = ws + off; off += (size_t)ROWS * Dm;
    float* f_xn = ws + off; off += (size_t)ROWS * Dm;
    float* f_up = ws + off; off += (size_t)ROWS * 2 * IN;
    float* f_xc = ws + off; off += (size_t)ROWS * IN;
    float* f_q  = ws + off; off += (size_t)ROWS * IN;
    float* f_k  = ws + off; off += (size_t)ROWS * IN;
    float* f_v  = ws + off; off += (size_t)ROWS * IN;
    float* f_hs = ws + off; off += (size_t)ROWS * IN;
    float* f_ip = ws + off; off += (size_t)ROWS * NHh;
    float* f_fp = ws + off; off += (size_t)ROWS * NHh;
    float* g_G  = ws + off; off += 32 * TT;
    float* g_M  = ws + off; off += 32 * TT;
    float* g_Mb = ws + off; off += 32 * NCH;
    float* g_De = ws + off; off += 32 * NCH;
    float* g_P  = ws + off; off += (size_t)NCH * 32 * DHd * DHd;
    float* g_nP = ws + off; off += (size_t)NCH * 32 * DHd;
    float* f_vc = ws + off; off += Bsz * Dm;
    float* g_wt = ws + off; off += 2 * 16 * IN;

    const float kscale = 0.08838834764831845f; // DH^-0.5
    const int MB = (ROWS + 127) / 128;         // 17

    concat_kernel<<<(ROWS * Dm + 255) / 256, 256, 0, stream>>>(x, cls, f_h);
    gate_w_transpose<<<(2 * 16 * IN + 255) / 256, 256, 0, stream>>>(w_ig, w_fg, g_wt);

    for (int blk = 0; blk < 2; blk++) {
        const float* p_ln_s = ln_s + blk * Dm;
        const float* p_ln_b = ln_b + blk * Dm;
        const float* p_wup  = w_up + (size_t)blk * Dm * 2 * IN;
        const float* p_bup  = b_up + (size_t)blk * 2 * IN;
        const float* p_ck   = conv_k + (size_t)blk * IN * KK;
        const float* p_cb   = conv_b + (size_t)blk * IN;
        const float* p_wq   = w_q + (size_t)blk * IN * IN;
        const float* p_wk   = w_k + (size_t)blk * IN * IN;
        const float* p_wv   = w_v + (size_t)blk * IN * IN;
        const float* p_big  = b_ig + (size_t)blk * NHh;
        const float* p_bfg  = b_fg + (size_t)blk * NHh;
        const float* p_hns  = hn_s + (size_t)blk * NHh * DHd;
        const float* p_wd   = w_down + (size_t)blk * IN * Dm;
        const float* p_bd   = b_down + (size_t)blk * Dm;

        ln_kernel<<<ROWS, 256, 0, stream>>>(f_h, p_ln_s, p_ln_b, f_xn);

        gemm_mfma_kernel<<<dim3(2 * IN / 128, MB), 256, 0, stream>>>(
            f_xn, Dm, p_wup, 2 * IN, p_bup, nullptr, 0, f_up, 2 * IN, ROWS, Dm, 1.f);

        conv_silu_kernel<<<(ROWS * IN + 255) / 256, 256, 0, stream>>>(f_up, p_ck, p_cb, f_xc);

        qkv_mfma_kernel<<<dim3(24, MB), 256, 0, stream>>>(
            f_xc, f_up, p_wq, p_wk, p_wv, f_q, f_k, f_v, kscale);

        gates_kernel<<<ROWS, 256, 0, stream>>>(f_xc, g_wt + blk * 16 * IN, p_big, p_bfg,
                                               f_ip, f_fp);

        // chunkwise-parallel mLSTM
        gate_scan_kernel<<<32, 64, 0, stream>>>(f_ip, f_fp, g_G, g_M, g_Mb, g_De);
        chunk_state_kernel<<<dim3(NCH, 32), 256, 0, stream>>>(f_k, f_v, g_G, g_Mb, g_P, g_nP);
        chunk_combine_kernel<<<32 * 64, 256, 0, stream>>>(g_P, g_De);
        n_combine_kernel<<<16, 256, 0, stream>>>(g_nP, g_De);
        chunk_out_kernel<<<dim3(NCH, 32), 512, 0, stream>>>(f_q, f_k, f_v, g_G, g_M, g_Mb,
                                                            g_P, g_nP, f_hs);

        headnorm_kernel<<<ROWS * NHh, 64, 0, stream>>>(f_hs, p_hns, f_up, f_xc);

        gemm_mfma_kernel<<<dim3(Dm / 128, MB), 256, 0, stream>>>(
            f_xc, IN, p_wd, Dm, p_bd, f_h, Dm, f_h, Dm, ROWS, IN, 1.f);
    }

    cls_ln_kernel<<<Bsz, 256, 0, stream>>>(f_h, fcls, fclb, f_vc);
    fc_kernel<<<(NCc + 63) / 64, 256, 0, stream>>>(f_vc, fc_w, fc_b, out);
}

// Round 11
// 665.590 us; speedup vs baseline: 4.8052x; 1.0375x over previous
//
#include <hip/hip_runtime.h>

// ---------------------------------------------------------------- constants
#define EPSV 1e-5f
constexpr int Bsz = 4, T0 = 512, Dm = 512, TT = 513, NHh = 8, KK = 4;
constexpr int IN = 1024, DHd = 128, NCc = 1000;
constexpr int ROWS = Bsz * TT; // 2052
constexpr int NCH = 9;         // chunks of 64: 8*64 + 1 = 513

// bf16 k-major weight buffer offsets (u16 elements), per transformer block
constexpr size_t WT_UP = 0;                      // [2048][512]
constexpr size_t WT_Q  = WT_UP + 2048 * 512;     // [1024][1024]
constexpr size_t WT_K  = WT_Q + 1024 * 1024;
constexpr size_t WT_V  = WT_K + 1024 * 1024;
constexpr size_t WT_DN = WT_V + 1024 * 1024;     // [512][1024]
constexpr size_t WT_STRIDE = WT_DN + 512 * 1024; // 4,718,592 u16

typedef __attribute__((ext_vector_type(8))) short bf16x8;
typedef __attribute__((ext_vector_type(4))) float f32x4;
typedef __attribute__((ext_vector_type(4))) unsigned short ushort4v;
typedef __attribute__((ext_vector_type(8))) unsigned short ushort8v;
typedef unsigned short u16;

__device__ __forceinline__ float siluf(float x) { return x / (1.f + __expf(-x)); }
__device__ __forceinline__ u16 f2bf(float f) {
    unsigned int u = __float_as_uint(f);
    u = (u + 0x7FFFu + ((u >> 16) & 1u)) >> 16;
    return (u16)u;
}

// ---------------------------------------------------------------- concat x + cls
__global__ __launch_bounds__(256) void concat_kernel(const float* __restrict__ x,
                                                     const float* __restrict__ cls,
                                                     float* __restrict__ h) {
    int idx = blockIdx.x * 256 + threadIdx.x;
    if (idx >= Bsz * TT * Dm) return;
    int d = idx & (Dm - 1);
    int bt = idx >> 9;
    int t = bt % TT, b = bt / TT;
    h[idx] = (t < T0) ? x[((size_t)(b * T0 + t)) * Dm + d] : cls[d];
}

// ---------------------------------------------------------------- LayerNorm rows of D=512
__global__ __launch_bounds__(256) void ln_kernel(const float* __restrict__ in,
                                                 const float* __restrict__ s,
                                                 const float* __restrict__ bb,
                                                 float* __restrict__ out) {
    int row = blockIdx.x, tid = threadIdx.x;
    const float* r = in + (size_t)row * Dm;
    __shared__ float s1[4], s2[4];
    float x0 = r[tid], x1 = r[tid + 256];
    float sum = x0 + x1, sq = x0 * x0 + x1 * x1;
#pragma unroll
    for (int o = 32; o > 0; o >>= 1) { sum += __shfl_xor(sum, o); sq += __shfl_xor(sq, o); }
    if ((tid & 63) == 0) { s1[tid >> 6] = sum; s2[tid >> 6] = sq; }
    __syncthreads();
    sum = s1[0] + s1[1] + s1[2] + s1[3];
    sq  = s2[0] + s2[1] + s2[2] + s2[3];
    float mu = sum / Dm, var = sq / Dm - mu * mu, inv = rsqrtf(var + EPSV);
    out[(size_t)row * Dm + tid]       = (x0 - mu) * inv * s[tid] + bb[tid];
    out[(size_t)row * Dm + tid + 256] = (x1 - mu) * inv * s[tid + 256] + bb[tid + 256];
}

// ---------------------------------------------------------------- weight transpose f32 KxN -> bf16 [N][K]
__global__ __launch_bounds__(256) void w_transpose_kernel(const float* __restrict__ wup,
        const float* __restrict__ wq, const float* __restrict__ wk,
        const float* __restrict__ wv, const float* __restrict__ wdn,
        u16* __restrict__ wt) {
    int y = blockIdx.y;             // 0..9
    int blk = y / 5, sel = y - blk * 5;
    int Kd, N; const float* src; size_t doff;
    if (sel == 0)      { Kd = 512;  N = 2048; src = wup + (size_t)blk * 512 * 2048; doff = WT_UP; }
    else if (sel == 1) { Kd = 1024; N = 1024; src = wq  + (size_t)blk * 1024 * 1024; doff = WT_Q; }
    else if (sel == 2) { Kd = 1024; N = 1024; src = wk  + (size_t)blk * 1024 * 1024; doff = WT_K; }
    else if (sel == 3) { Kd = 1024; N = 1024; src = wv  + (size_t)blk * 1024 * 1024; doff = WT_V; }
    else               { Kd = 1024; N = 512;  src = wdn + (size_t)blk * 1024 * 512;  doff = WT_DN; }
    u16* dst = wt + (size_t)blk * WT_STRIDE + doff;
    int ntx = N >> 5;
    int ntiles = ntx * (Kd >> 5);
    int ti = blockIdx.x;
    if (ti >= ntiles) return;
    int tk = ti / ntx, tn = ti - tk * ntx;
    __shared__ u16 s[32][33];
    int tx = threadIdx.x & 31, ty = threadIdx.x >> 5;
#pragma unroll
    for (int i = 0; i < 4; i++) {
        int k = tk * 32 + ty + i * 8;
        s[ty + i * 8][tx] = f2bf(src[(size_t)k * N + tn * 32 + tx]);
    }
    __syncthreads();
#pragma unroll
    for (int i = 0; i < 4; i++) {
        int n = tn * 32 + ty + i * 8;
        dst[(size_t)n * Kd + tk * 32 + tx] = s[tx][ty + i * 8];
    }
}

// ---------------------------------------------------------------- MFMA bf16 GEMM, double-buffered
// A: f32 MxK (lda). Wt: bf16 [N][Kd] k-contiguous. 128x128 tile, BK=32.
__device__ __forceinline__ void gemm_tile_body(const float* __restrict__ A, int lda,
                                               const u16* __restrict__ Wt, int Kd,
                                               const float* __restrict__ bias,
                                               const float* __restrict__ resid, int ldr,
                                               float* __restrict__ Cout, int ldc,
                                               int M, float scale, int m0, int n0,
                                               u16 (*As)[128][40], u16 (*Bs)[128][40]) {
    int tid = threadIdx.x;
    int wave = tid >> 6, lane = tid & 63;
    int wm = (wave >> 1) * 64, wn = (wave & 1) * 64;
    int lrow = lane & 15, lquad = lane >> 4;

    f32x4 acc[4][4];
#pragma unroll
    for (int i = 0; i < 4; i++)
#pragma unroll
        for (int j = 0; j < 4; j++)
#pragma unroll
            for (int r = 0; r < 4; r++) acc[i][j][r] = 0.f;

    int am = tid >> 1, ak = (tid & 1) * 16;
    int bn = tid & 127, bk = (tid >> 7) * 16;
    int gm = m0 + am;
    const u16* wrow = Wt + (size_t)(n0 + bn) * Kd + bk;

    float4 a0, a1, a2, a3;
    ushort8v b0, b1;

    auto load_tile = [&](int k0) {
        if (gm < M) {
            const float4* ap = (const float4*)(A + (size_t)gm * lda + k0 + ak);
            a0 = ap[0]; a1 = ap[1]; a2 = ap[2]; a3 = ap[3];
        } else {
            a0 = a1 = a2 = a3 = make_float4(0.f, 0.f, 0.f, 0.f);
        }
        b0 = *(const ushort8v*)(wrow + k0);
        b1 = *(const ushort8v*)(wrow + k0 + 8);
    };
    auto store_tile = [&](int buf) {
        ushort4v t0 = {f2bf(a0.x), f2bf(a0.y), f2bf(a0.z), f2bf(a0.w)};
        ushort4v t1 = {f2bf(a1.x), f2bf(a1.y), f2bf(a1.z), f2bf(a1.w)};
        ushort4v t2 = {f2bf(a2.x), f2bf(a2.y), f2bf(a2.z), f2bf(a2.w)};
        ushort4v t3 = {f2bf(a3.x), f2bf(a3.y), f2bf(a3.z), f2bf(a3.w)};
        *(ushort4v*)&As[buf][am][ak + 0]  = t0;
        *(ushort4v*)&As[buf][am][ak + 4]  = t1;
        *(ushort4v*)&As[buf][am][ak + 8]  = t2;
        *(ushort4v*)&As[buf][am][ak + 12] = t3;
        *(ushort8v*)&Bs[buf][bn][bk]     = b0;
        *(ushort8v*)&Bs[buf][bn][bk + 8] = b1;
    };

    load_tile(0);
    store_tile(0);
    __syncthreads();

    int nk = Kd >> 5;
#pragma unroll 1
    for (int it = 0; it < nk; it++) {
        int cur = it & 1;
        bool more = (it + 1 < nk);
        if (more) load_tile((it + 1) << 5);   // VMEM issued before MFMA phase
        bf16x8 afr[4], bfr[4];
#pragma unroll
        for (int mt = 0; mt < 4; mt++)
            afr[mt] = *(const bf16x8*)&As[cur][wm + mt * 16 + lrow][lquad * 8];
#pragma unroll
        for (int nt = 0; nt < 4; nt++)
            bfr[nt] = *(const bf16x8*)&Bs[cur][wn + nt * 16 + lrow][lquad * 8];
#pragma unroll
        for (int mt = 0; mt < 4; mt++)
#pragma unroll
            for (int nt = 0; nt < 4; nt++)
                acc[mt][nt] = __builtin_amdgcn_mfma_f32_16x16x32_bf16(
                    afr[mt], bfr[nt], acc[mt][nt], 0, 0, 0);
        if (more) store_tile(cur ^ 1);        // vmcnt consumed here, after MFMA
        __syncthreads();
    }

#pragma unroll
    for (int mt = 0; mt < 4; mt++) {
#pragma unroll
        for (int r = 0; r < 4; r++) {
            int gmr = m0 + wm + mt * 16 + lquad * 4 + r;
            if (gmr >= M) continue;
#pragma unroll
            for (int nt = 0; nt < 4; nt++) {
                int gn = n0 + wn + nt * 16 + lrow;
                float v = acc[mt][nt][r] * scale;
                if (bias) v += bias[gn];
                if (resid) v += resid[(size_t)gmr * ldr + gn];
                Cout[(size_t)gmr * ldc + gn] = v;
            }
        }
    }
}

__global__ __launch_bounds__(256, 2) void gemm_mfma_kernel(const float* __restrict__ A, int lda,
                                                           const u16* __restrict__ Wt, int Kd,
                                                           const float* __restrict__ bias,
                                                           const float* __restrict__ resid, int ldr,
                                                           float* __restrict__ Cout, int ldc,
                                                           int M, float scale) {
    __shared__ __align__(16) u16 As[2][128][40];
    __shared__ __align__(16) u16 Bs[2][128][40];
    gemm_tile_body(A, lda, Wt, Kd, bias, resid, ldr, Cout, ldc, M, scale,
                   blockIdx.y * 128, blockIdx.x * 128, As, Bs);
}

// q/k/v in ONE dispatch: blockIdx.x in [0,24): sel = x>>3 chooses {q,k,v}.
__global__ __launch_bounds__(256, 2) void qkv_mfma_kernel(const float* __restrict__ xc,
                                                          const float* __restrict__ up,
                                                          const u16* __restrict__ wtblk,
                                                          float* __restrict__ fq,
                                                          float* __restrict__ fk,
                                                          float* __restrict__ fv,
                                                          float kscale) {
    __shared__ __align__(16) u16 As[2][128][40];
    __shared__ __align__(16) u16 Bs[2][128][40];
    int sel = blockIdx.x >> 3, nx = blockIdx.x & 7;
    const float* A = (sel == 2) ? up : xc;
    int lda = (sel == 2) ? 2 * IN : IN;
    const u16* Wt = wtblk + ((sel == 0) ? WT_Q : (sel == 1) ? WT_K : WT_V);
    float* C = (sel == 0) ? fq : (sel == 1) ? fk : fv;
    float scale = (sel == 1) ? kscale : 1.f;
    gemm_tile_body(A, lda, Wt, IN, nullptr, nullptr, 0, C, IN, ROWS, scale,
                   blockIdx.y * 128, nx * 128, As, Bs);
}

// ---------------------------------------------------------------- causal depthwise conv (K=4) + SiLU
__global__ __launch_bounds__(256) void conv_silu_kernel(const float* __restrict__ up,
                                                        const float* __restrict__ ck,
                                                        const float* __restrict__ cb,
                                                        float* __restrict__ xc) {
    int idx = blockIdx.x * 256 + threadIdx.x;
    if (idx >= ROWS * IN) return;
    int c = idx & (IN - 1);
    int bt = idx >> 10;
    int t = bt % TT, b = bt / TT;
    float acc = cb[c];
#pragma unroll
    for (int j = 0; j < KK; j++) {
        int tt = t - (KK - 1) + j;
        if (tt >= 0) acc += up[((size_t)(b * TT + tt)) * (2 * IN) + c] * ck[c * KK + j];
    }
    xc[idx] = siluf(acc);
}

// ---------------------------------------------------------------- gate weight transpose: wt[blk][g][k]
__global__ __launch_bounds__(256) void gate_w_transpose(const float* __restrict__ wig,
                                                        const float* __restrict__ wfg,
                                                        float* __restrict__ wt) {
    int idx = blockIdx.x * 256 + threadIdx.x;   // 0..32767
    int k = idx & 1023;
    int g = (idx >> 10) & 15;
    int blk = idx >> 14;
    const float* w = (g < 8) ? (wig + (size_t)blk * IN * NHh) : (wfg + (size_t)blk * IN * NHh);
    wt[idx] = w[k * NHh + (g & 7)];
}

// ---------------------------------------------------------------- gate projections (coalesced wt)
__global__ __launch_bounds__(256) void gates_kernel(const float* __restrict__ xc,
                                                    const float* __restrict__ wt,
                                                    const float* __restrict__ big,
                                                    const float* __restrict__ bfg,
                                                    float* __restrict__ ip, float* __restrict__ fp) {
    int row = blockIdx.x, tid = threadIdx.x;
    __shared__ float sx[IN];
    *(float4*)&sx[tid * 4] = *(const float4*)(xc + (size_t)row * IN + tid * 4);
    __syncthreads();
    int g = tid >> 4, l = tid & 15;
    const float* wrow = wt + g * IN;
    float acc = 0.f;
#pragma unroll
    for (int j = 0; j < 16; j++) {
        int k = j * 64 + l * 4;
        float4 w4 = *(const float4*)(wrow + k);
        float4 x4 = *(const float4*)&sx[k];
        acc += w4.x * x4.x + w4.y * x4.y + w4.z * x4.z + w4.w * x4.w;
    }
#pragma unroll
    for (int o = 8; o > 0; o >>= 1) acc += __shfl_down(acc, o, 16);
    if (l == 0) {
        if (g < 8) ip[(size_t)row * NHh + g] = acc + big[g];
        else       fp[(size_t)row * NHh + (g - 8)] = acc + bfg[g - 8];
    }
}

// ---------------------------------------------------------------- chunkwise mLSTM
__global__ __launch_bounds__(64) void gate_scan_kernel(const float* __restrict__ ip,
        const float* __restrict__ fp, float* __restrict__ gG, float* __restrict__ gM,
        float* __restrict__ gMb, float* __restrict__ gDec) {
    constexpr int PER = 9;
    int chain = blockIdx.x;
    int b = chain >> 3, h = chain & 7;
    int lane = threadIdx.x;
    int tbase = lane * PER;
    float lcs[PER];
    float gi[PER];
    float csum = 0.f;
#pragma unroll
    for (int i = 0; i < PER; i++) {
        int t = tbase + i;
        float fpv = 0.f, ipv = 0.f;
        if (t < TT) {
            size_t gidx = (size_t)(b * TT + t) * NHh + h;
            fpv = fp[gidx]; ipv = ip[gidx];
        }
        float flv = (fpv >= 0.f) ? -log1pf(__expf(-fpv)) : (fpv - log1pf(__expf(fpv)));
        if (t >= TT) flv = 0.f;
        csum += flv;
        lcs[i] = csum;
        gi[i] = ipv;
    }
    float ps = csum;
#pragma unroll
    for (int o = 1; o < 64; o <<= 1) {
        float v = __shfl_up(ps, o);
        if (lane >= o) ps += v;
    }
    float Fexcl = ps - csum;
    float G[PER];
    float cmax = -1e30f;
#pragma unroll
    for (int i = 0; i < PER; i++) {
        int t = tbase + i;
        G[i] = (t < TT) ? (gi[i] - (Fexcl + lcs[i])) : -1e30f;
        cmax = fmaxf(cmax, G[i]);
        lcs[i] = cmax;
    }
    float pm = cmax;
#pragma unroll
    for (int o = 1; o < 64; o <<= 1) {
        float v = __shfl_up(pm, o);
        if (lane >= o) pm = fmaxf(pm, v);
    }
    float Me = __shfl_up(pm, 1);
    if (lane == 0) Me = -1e30f;
    __shared__ float sMb[NCH];
#pragma unroll
    for (int i = 0; i < PER; i++) {
        int t = tbase + i;
        if (t < TT) {
            float Mt = fmaxf(0.f, fmaxf(Me, lcs[i]));
            gG[chain * TT + t] = G[i];
            gM[chain * TT + t] = Mt;
            if (((t & 63) == 63) || t == TT - 1) sMb[t >> 6] = Mt;
        }
    }
    __syncthreads();
    if (lane < NCH) {
        float Mb = sMb[lane];
        float Mbp = (lane == 0) ? 0.f : sMb[lane - 1];
        gMb[chain * NCH + lane] = Mb;
        gDec[chain * NCH + lane] = __expf(Mbp - Mb);
    }
}

// Kernel B1: per-chunk local state
__global__ __launch_bounds__(256) void chunk_state_kernel(const float* __restrict__ kk,
        const float* __restrict__ vv, const float* __restrict__ gG,
        const float* __restrict__ gMb, float* __restrict__ P, float* __restrict__ nP) {
    int c = blockIdx.x, chain = blockIdx.y;
    int b = chain >> 3, h = chain & 7;
    int t0 = c * 64;
    int nvalid = min(64, TT - t0);
    __shared__ float sK[32][128], sV[32][128], sw[64];
    int tid = threadIdx.x;
    if (tid < 64) {
        float Mb = gMb[chain * NCH + c];
        sw[tid] = (tid < nvalid) ? __expf(gG[chain * TT + t0 + tid] - Mb) : 0.f;
    }
    int e = tid & 127, dg = (tid >> 7) * 64;
    float4 acc[16];
#pragma unroll
    for (int i = 0; i < 16; i++) acc[i] = make_float4(0.f, 0.f, 0.f, 0.f);
    float na = 0.f;
    for (int jh = 0; jh < 2; jh++) {
        int lrow = tid >> 5, lcol = (tid & 31) * 4;
        for (int rr = 0; rr < 4; rr++) {
            int r = lrow + rr * 8;
            int gr = jh * 32 + r;
            float4 kv = make_float4(0.f,0.f,0.f,0.f), vvv = kv;
            if (gr < nvalid) {
                size_t gb = ((size_t)(b * TT + t0 + gr)) * IN + h * DHd + lcol;
                kv = *(const float4*)(kk + gb);
                vvv = *(const float4*)(vv + gb);
            }
            *(float4*)&sK[r][lcol] = kv;
            *(float4*)&sV[r][lcol] = vvv;
        }
        __syncthreads();
        int jmax = min(32, nvalid - jh * 32);
#pragma unroll 1
        for (int j = 0; j < jmax; j++) {
            float wvj = sw[jh * 32 + j] * sV[j][e];
            const float4* kr = (const float4*)&sK[j][dg];
#pragma unroll
            for (int d4 = 0; d4 < 16; d4++) {
                float4 kq = kr[d4];
                acc[d4].x += kq.x * wvj; acc[d4].y += kq.y * wvj;
                acc[d4].z += kq.z * wvj; acc[d4].w += kq.w * wvj;
            }
        }
        if (tid < 128) {
#pragma unroll 1
            for (int j = 0; j < jmax; j++) na += sw[jh * 32 + j] * sK[j][tid];
        }
        __syncthreads();
    }
    float* Pbase = P + (((size_t)(c * 32 + chain)) << 14);
#pragma unroll
    for (int d4 = 0; d4 < 16; d4++) {
        Pbase[(size_t)(dg + d4 * 4 + 0) * 128 + e] = acc[d4].x;
        Pbase[(size_t)(dg + d4 * 4 + 1) * 128 + e] = acc[d4].y;
        Pbase[(size_t)(dg + d4 * 4 + 2) * 128 + e] = acc[d4].z;
        Pbase[(size_t)(dg + d4 * 4 + 3) * 128 + e] = acc[d4].w;
    }
    if (tid < 128) nP[(size_t)(c * 32 + chain) * 128 + tid] = na;
}

// Kernel B2: in-place exclusive combine over chunks.
__global__ __launch_bounds__(256) void chunk_combine_kernel(float* __restrict__ P,
        const float* __restrict__ gDec) {
    int chain = blockIdx.x >> 6;
    int idx = (blockIdx.x & 63) * 256 + threadIdx.x;
    float run = 0.f;
    for (int c = 0; c < NCH; c++) {
        size_t a = (((size_t)(c * 32 + chain)) << 14) + idx;
        float tmp = P[a];
        P[a] = run;
        run = run * gDec[chain * NCH + c] + tmp;
    }
}

__global__ __launch_bounds__(256) void n_combine_kernel(float* __restrict__ nP,
        const float* __restrict__ gDec) {
    int gidx = blockIdx.x * 256 + threadIdx.x;
    int chain = gidx >> 7, d = gidx & 127;
    float run = 0.f;
    for (int c = 0; c < NCH; c++) {
        size_t a = (size_t)(c * 32 + chain) * 128 + d;
        float tmp = nP[a];
        nP[a] = run;
        run = run * gDec[chain * NCH + c] + tmp;
    }
}

// Kernel C: per-chunk outputs.
__global__ __launch_bounds__(512, 2) void chunk_out_kernel(const float* __restrict__ qq,
        const float* __restrict__ kk, const float* __restrict__ vv,
        const float* __restrict__ gG, const float* __restrict__ gM,
        const float* __restrict__ gMb, const float* __restrict__ P,
        const float* __restrict__ nP, float* __restrict__ hs) {
    int c = blockIdx.x, chain = blockIdx.y;
    int b = chain >> 3, h = chain & 7;
    int t0 = c * 64;
    int nvalid = min(64, TT - t0);
    __shared__ __align__(16) float smem[13440];
    float* sG  = smem;
    float* sM  = smem + 64;
    float* sWr = smem + 128;
    float* sInv= smem + 192;
    float* sNb = smem + 256;
    float (*sD)[68] = (float(*)[68])(smem + 384);
    float* scr = smem + 384 + 64 * 68;
    int tid = threadIdx.x;

    float Mbprev = (c > 0) ? gMb[chain * NCH + c - 1] : 0.f;
    if (tid < 64) {
        bool val = tid < nvalid;
        sG[tid] = val ? gG[chain * TT + t0 + tid] : -1e30f;
        float Mv = val ? gM[chain * TT + t0 + tid] : 1e30f;
        sM[tid] = Mv;
        sWr[tid] = val ? __expf(Mbprev - Mv) : 0.f;
    }
    if (tid >= 128 && tid < 256) sNb[tid - 128] = nP[(size_t)(c * 32 + chain) * 128 + (tid - 128)];
    __syncthreads();

    int e = tid & 127, rg = (tid >> 7) * 16;
    float acc[16];
#pragma unroll
    for (int r = 0; r < 16; r++) acc[r] = 0.f;

    // ---- Phase 0: inter H = Q @ CB
    {
        float (*sCB)[128] = (float(*)[128])(smem + 384);
        float (*Qh2)[68]  = (float(*)[68])(smem + 384 + 64*128);
        const float* CBbase = P + (((size_t)(c * 32 + chain)) << 14);
        for (int dh = 0; dh < 2; dh++) {
            {
                int dr = tid >> 5, dc = (tid & 31) * 4;
#pragma unroll
                for (int rr = 0; rr < 4; rr++) {
                    int d = dr + rr * 16;
                    *(float4*)&sCB[d][dc] = *(const float4*)(CBbase + (size_t)(dh * 64 + d) * 128 + dc);
                }
                int lr = tid >> 3, c0 = (tid & 7) * 8;
                bool val = lr < nvalid;
                size_t gb = ((size_t)(b * TT + t0 + lr)) * IN + h * DHd + dh * 64 + c0;
                float4 qv0 = val ? *(const float4*)(qq + gb)     : make_float4(0.f,0.f,0.f,0.f);
                float4 qv1 = val ? *(const float4*)(qq + gb + 4) : make_float4(0.f,0.f,0.f,0.f);
                *(float4*)&Qh2[lr][c0]     = qv0;
                *(float4*)&Qh2[lr][c0 + 4] = qv1;
            }
            __syncthreads();
#pragma unroll 1
            for (int dd4 = 0; dd4 < 16; dd4++) {
                float c0v = sCB[dd4 * 4 + 0][e];
                float c1v = sCB[dd4 * 4 + 1][e];
                float c2v = sCB[dd4 * 4 + 2][e];
                float c3v = sCB[dd4 * 4 + 3][e];
#pragma unroll
                for (int r = 0; r < 16; r++) {
                    float4 qf = *(const float4*)&Qh2[rg + r][dd4 * 4];
                    acc[r] += qf.x * c0v + qf.y * c1v + qf.z * c2v + qf.w * c3v;
                }
            }
            __syncthreads();
        }
#pragma unroll
        for (int r = 0; r < 16; r++) acc[r] *= sWr[rg + r];
    }

    // ---- Phase 1: S = Q K^T; weights -> sD; qnb
    float qnb = 0.f;
    {
        float (*Qh)[68] = (float(*)[68])scr;
        float (*Kh)[68] = (float(*)[68])(scr + 64 * 68);
        int j = tid & 63, ig = (tid >> 6) * 8;
        float accS[8];
#pragma unroll
        for (int i = 0; i < 8; i++) accS[i] = 0.f;
        for (int dh = 0; dh < 2; dh++) {
            {
                int lr = tid >> 3, c0 = (tid & 7) * 8;
                bool val = lr < nvalid;
                size_t gb = ((size_t)(b * TT + t0 + lr)) * IN + h * DHd + dh * 64 + c0;
                float4 qv0 = val ? *(const float4*)(qq + gb)     : make_float4(0.f,0.f,0.f,0.f);
                float4 qv1 = val ? *(const float4*)(qq + gb + 4) : make_float4(0.f,0.f,0.f,0.f);
                float4 kv0 = val ? *(const float4*)(kk + gb)     : make_float4(0.f,0.f,0.f,0.f);
                float4 kv1 = val ? *(const float4*)(kk + gb + 4) : make_float4(0.f,0.f,0.f,0.f);
                *(float4*)&Qh[lr][c0]     = qv0;
                *(float4*)&Qh[lr][c0 + 4] = qv1;
                *(float4*)&Kh[lr][c0]     = kv0;
                *(float4*)&Kh[lr][c0 + 4] = kv1;
            }
            __syncthreads();
#pragma unroll 1
            for (int d4 = 0; d4 < 16; d4++) {
                float4 kf = *(const float4*)&Kh[j][d4 * 4];
#pragma unroll
                for (int i = 0; i < 8; i++) {
                    float4 qf = *(const float4*)&Qh[ig + i][d4 * 4];
                    accS[i] += qf.x * kf.x + qf.y * kf.y + qf.z * kf.z + qf.w * kf.w;
                }
            }
            if (tid < 64) {
#pragma unroll 1
                for (int d4 = 0; d4 < 16; d4++) {
                    float4 qf = *(const float4*)&Qh[tid][d4 * 4];
                    float4 nb = *(const float4*)&sNb[dh * 64 + d4 * 4];
                    qnb += qf.x * nb.x + qf.y * nb.y + qf.z * nb.z + qf.w * nb.w;
                }
            }
            __syncthreads();
        }
        float Gj = sG[j];
#pragma unroll
        for (int i = 0; i < 8; i++) {
            int irow = ig + i;
            float w = (j <= irow) ? __expf(Gj - sM[irow]) : 0.f;
            sD[irow][j] = accS[i] * w;
        }
    }
    __syncthreads();

    // ---- Phase 2: denominators
    if (tid < 64) {
        float s = 0.f;
#pragma unroll 1
        for (int j4 = 0; j4 < 16; j4++) {
            float4 d = *(const float4*)&sD[tid][j4 * 4];
            s += d.x + d.y + d.z + d.w;
        }
        float den = s + sWr[tid] * qnb;
        sInv[tid] = 1.f / fmaxf(fabsf(den), 1.f);
    }
    __syncthreads();

    // ---- Phase 3: intra H += D @ V
    {
        float (*sV)[128] = (float(*)[128])scr;
        int lrow = tid >> 5, lcol = (tid & 31) * 4;
#pragma unroll
        for (int rr = 0; rr < 4; rr++) {
            int r = lrow + rr * 16;
            float4 vvv = make_float4(0.f,0.f,0.f,0.f);
            if (r < nvalid) {
                size_t gb = ((size_t)(b * TT + t0 + r)) * IN + h * DHd + lcol;
                vvv = *(const float4*)(vv + gb);
            }
            *(float4*)&sV[r][lcol] = vvv;
        }
        __syncthreads();
#pragma unroll 1
        for (int jj4 = 0; jj4 < 16; jj4++) {
            float v0 = sV[jj4 * 4 + 0][e];
            float v1 = sV[jj4 * 4 + 1][e];
            float v2 = sV[jj4 * 4 + 2][e];
            float v3 = sV[jj4 * 4 + 3][e];
#pragma unroll
            for (int r = 0; r < 16; r++) {
                float4 d = *(const float4*)&sD[rg + r][jj4 * 4];
                acc[r] += d.x * v0 + d.y * v1 + d.z * v2 + d.w * v3;
            }
        }
    }

#pragma unroll
    for (int r = 0; r < 16; r++) {
        int irow = rg + r;
        if (irow < nvalid)
            hs[((size_t)(b * TT + t0 + irow)) * IN + h * DHd + e] = acc[r] * sInv[irow];
    }
}

// ---------------------------------------------------------------- per-head norm * hn_s * silu(z)
__global__ __launch_bounds__(64) void headnorm_kernel(const float* __restrict__ hs,
                                                      const float* __restrict__ hn,
                                                      const float* __restrict__ up,
                                                      float* __restrict__ out) {
    int idx = blockIdx.x;
    int h = idx & 7, bt = idx >> 3;
    int tid = threadIdx.x;
    size_t base = (size_t)bt * IN + h * DHd;
    float x0 = hs[base + tid], x1 = hs[base + 64 + tid];
    float sum = x0 + x1, sq = x0 * x0 + x1 * x1;
#pragma unroll
    for (int o = 32; o > 0; o >>= 1) { sum += __shfl_xor(sum, o); sq += __shfl_xor(sq, o); }
    float mu = sum / DHd, var = sq / DHd - mu * mu, inv = rsqrtf(var + EPSV);
    size_t zb = (size_t)bt * (2 * IN) + IN + h * DHd;
    out[base + tid]      = (x0 - mu) * inv * hn[h * DHd + tid]      * siluf(up[zb + tid]);
    out[base + 64 + tid] = (x1 - mu) * inv * hn[h * DHd + 64 + tid] * siluf(up[zb + 64 + tid]);
}

// ---------------------------------------------------------------- head: LN+ReLU of cls rows -> vcls
__global__ __launch_bounds__(256) void cls_ln_kernel(const float* __restrict__ hbuf,
                                                     const float* __restrict__ s, const float* __restrict__ bb,
                                                     float* __restrict__ vcls) {
    int b = blockIdx.x, tid = threadIdx.x;
    const float* r = hbuf + ((size_t)b * TT + TT - 1) * Dm;
    __shared__ float s1[4], s2[4];
    float x0 = r[tid], x1 = r[tid + 256];
    float sum = x0 + x1, sq = x0 * x0 + x1 * x1;
#pragma unroll
    for (int o = 32; o > 0; o >>= 1) { sum += __shfl_xor(sum, o); sq += __shfl_xor(sq, o); }
    if ((tid & 63) == 0) { s1[tid >> 6] = sum; s2[tid >> 6] = sq; }
    __syncthreads();
    sum = s1[0] + s1[1] + s1[2] + s1[3];
    sq  = s2[0] + s2[1] + s2[2] + s2[3];
    float mu = sum / Dm, var = sq / Dm - mu * mu, inv = rsqrtf(var + EPSV);
    float n0 = (x0 - mu) * inv * s[tid] + bb[tid];
    float n1 = (x1 - mu) * inv * s[tid + 256] + bb[tid + 256];
    vcls[b * Dm + tid]       = fmaxf(n0, 0.f);
    vcls[b * Dm + tid + 256] = fmaxf(n1, 0.f);
}

// ---------------------------------------------------------------- head: FC
__global__ __launch_bounds__(256) void fc_kernel(const float* __restrict__ vcls,
                                                 const float* __restrict__ fw,
                                                 const float* __restrict__ fb,
                                                 float* __restrict__ out) {
    __shared__ float svc[Bsz][Dm];
    __shared__ float sred[4][256];
    int tid = threadIdx.x;
    int j0 = blockIdx.x * 64;
    {
        const float4* src = (const float4*)vcls;
        float4* dst = (float4*)&svc[0][0];
        dst[tid] = src[tid];
        dst[tid + 256] = src[tid + 256];
    }
    __syncthreads();
    int j = j0 + (tid & 63);
    int chunk = tid >> 6;
    int kbase = chunk * 128;
    float a0 = 0.f, a1 = 0.f, a2 = 0.f, a3 = 0.f;
    if (j < NCc) {
        const float* fwp = fw + (size_t)kbase * NCc + j;
#pragma unroll 4
        for (int kk = 0; kk < 128; kk++) {
            float w = fwp[(size_t)kk * NCc];
            a0 += svc[0][kbase + kk] * w;
            a1 += svc[1][kbase + kk] * w;
            a2 += svc[2][kbase + kk] * w;
            a3 += svc[3][kbase + kk] * w;
        }
    }
    int jl = tid & 63;
    sred[chunk][jl * 4 + 0] = a0;
    sred[chunk][jl * 4 + 1] = a1;
    sred[chunk][jl * 4 + 2] = a2;
    sred[chunk][jl * 4 + 3] = a3;
    __syncthreads();
    if (tid < 64) {
        int jj = j0 + tid;
        if (jj < NCc) {
            float bias = fb[jj];
#pragma unroll
            for (int b = 0; b < Bsz; b++) {
                float v = sred[0][tid * 4 + b] + sred[1][tid * 4 + b]
                        + sred[2][tid * 4 + b] + sred[3][tid * 4 + b];
                out[b * NCc + jj] = v + bias;
            }
        }
    }
}

// ---------------------------------------------------------------- launch
extern "C" void kernel_launch(void* const* d_in, const int* in_sizes, int n_in,
                              void* d_out, int out_size, void* d_ws, size_t ws_size,
                              hipStream_t stream) {
    const float* x      = (const float*)d_in[0];
    const float* cls    = (const float*)d_in[1];
    const float* ln_s   = (const float*)d_in[2];
    const float* ln_b   = (const float*)d_in[3];
    const float* w_up   = (const float*)d_in[4];
    const float* b_up   = (const float*)d_in[5];
    const float* conv_k = (const float*)d_in[6];
    const float* conv_b = (const float*)d_in[7];
    const float* w_q    = (const float*)d_in[8];
    const float* w_k    = (const float*)d_in[9];
    const float* w_v    = (const float*)d_in[10];
    const float* w_ig   = (const float*)d_in[11];
    const float* b_ig   = (const float*)d_in[12];
    const float* w_fg   = (const float*)d_in[13];
    const float* b_fg   = (const float*)d_in[14];
    const float* hn_s   = (const float*)d_in[15];
    const float* w_down = (const float*)d_in[16];
    const float* b_down = (const float*)d_in[17];
    const float* fcls   = (const float*)d_in[18];
    const float* fclb   = (const float*)d_in[19];
    const float* fc_w   = (const float*)d_in[20];
    const float* fc_b   = (const float*)d_in[21];
    float* out = (float*)d_out;

    float* ws = (float*)d_ws;
    size_t off = 0;
    float* f_h  = ws + off; off += (size_t)ROWS * Dm;
    float* f_xn = ws + off; off += (size_t)ROWS * Dm;
    float* f_up = ws + off; off += (size_t)ROWS * 2 * IN;
    float* f_xc = ws + off; off += (size_t)ROWS * IN;
    float* f_q  = ws + off; off += (size_t)ROWS * IN;
    float* f_k  = ws + off; off += (size_t)ROWS * IN;
    float* f_v  = ws + off; off += (size_t)ROWS * IN;
    float* f_hs = ws + off; off += (size_t)ROWS * IN;
    float* f_ip = ws + off; off += (size_t)ROWS * NHh;
    float* f_fp = ws + off; off += (size_t)ROWS * NHh;
    float* g_G  = ws + off; off += 32 * TT;
    float* g_M  = ws + off; off += 32 * TT;
    float* g_Mb = ws + off; off += 32 * NCH;
    float* g_De = ws + off; off += 32 * NCH;
    float* g_P  = ws + off; off += (size_t)NCH * 32 * DHd * DHd;
    float* g_nP = ws + off; off += (size_t)NCH * 32 * DHd;
    float* f_vc = ws + off; off += Bsz * Dm;
    float* g_wt = ws + off; off += 2 * 16 * IN;
    u16* g_Wt = (u16*)(ws + off); off += (2 * WT_STRIDE + 1) / 2;

    const float kscale = 0.08838834764831845f; // DH^-0.5
    const int MB = (ROWS + 127) / 128;         // 17

    concat_kernel<<<(ROWS * Dm + 255) / 256, 256, 0, stream>>>(x, cls, f_h);
    gate_w_transpose<<<(2 * 16 * IN + 255) / 256, 256, 0, stream>>>(w_ig, w_fg, g_wt);
    w_transpose_kernel<<<dim3(1024, 10), 256, 0, stream>>>(w_up, w_q, w_k, w_v, w_down, g_Wt);

    for (int blk = 0; blk < 2; blk++) {
        const float* p_ln_s = ln_s + blk * Dm;
        const float* p_ln_b = ln_b + blk * Dm;
        const float* p_bup  = b_up + (size_t)blk * 2 * IN;
        const float* p_ck   = conv_k + (size_t)blk * IN * KK;
        const float* p_cb   = conv_b + (size_t)blk * IN;
        const float* p_big  = b_ig + (size_t)blk * NHh;
        const float* p_bfg  = b_fg + (size_t)blk * NHh;
        const float* p_hns  = hn_s + (size_t)blk * NHh * DHd;
        const float* p_bd   = b_down + (size_t)blk * Dm;
        const u16*   p_wt   = g_Wt + (size_t)blk * WT_STRIDE;

        ln_kernel<<<ROWS, 256, 0, stream>>>(f_h, p_ln_s, p_ln_b, f_xn);

        gemm_mfma_kernel<<<dim3(2 * IN / 128, MB), 256, 0, stream>>>(
            f_xn, Dm, p_wt + WT_UP, Dm, p_bup, nullptr, 0, f_up, 2 * IN, ROWS, 1.f);

        conv_silu_kernel<<<(ROWS * IN + 255) / 256, 256, 0, stream>>>(f_up, p_ck, p_cb, f_xc);

        qkv_mfma_kernel<<<dim3(24, MB), 256, 0, stream>>>(
            f_xc, f_up, p_wt, f_q, f_k, f_v, kscale);

        gates_kernel<<<ROWS, 256, 0, stream>>>(f_xc, g_wt + blk * 16 * IN, p_big, p_bfg,
                                               f_ip, f_fp);

        // chunkwise-parallel mLSTM
        gate_scan_kernel<<<32, 64, 0, stream>>>(f_ip, f_fp, g_G, g_M, g_Mb, g_De);
        chunk_state_kernel<<<dim3(NCH, 32), 256, 0, stream>>>(f_k, f_v, g_G, g_Mb, g_P, g_nP);
        chunk_combine_kernel<<<32 * 64, 256, 0, stream>>>(g_P, g_De);
        n_combine_kernel<<<16, 256, 0, stream>>>(g_nP, g_De);
        chunk_out_kernel<<<dim3(NCH, 32), 512, 0, stream>>>(f_q, f_k, f_v, g_G, g_M, g_Mb,
                                                            g_P, g_nP, f_hs);

        headnorm_kernel<<<ROWS * NHh, 64, 0, stream>>>(f_hs, p_hns, f_up, f_xc);

        gemm_mfma_kernel<<<dim3(Dm / 128, MB), 256, 0, stream>>>(
            f_xc, IN, p_wt + WT_DN, IN, p_bd, f_h, Dm, f_h, Dm, ROWS, 1.f);
    }

    cls_ln_kernel<<<Bsz, 256, 0, stream>>>(f_h, fcls, fclb, f_vc);
    fc_kernel<<<(NCc + 63) / 64, 256, 0, stream>>>(f_vc, fc_w, fc_b, out);
}

// Round 12
// 601.855 us; speedup vs baseline: 5.3141x; 1.1059x over previous
//
#include <hip/hip_runtime.h>

// ---------------------------------------------------------------- constants
#define EPSV 1e-5f
constexpr int Bsz = 4, T0 = 512, Dm = 512, TT = 513, NHh = 8, KK = 4;
constexpr int IN = 1024, DHd = 128, NCc = 1000;
constexpr int ROWS = Bsz * TT; // 2052
constexpr int NCH = 9;         // chunks of 64: 8*64 + 1 = 513

// bf16 k-major weight buffer offsets (u16 elements), per transformer block
constexpr size_t WT_UP = 0;                      // [2048][512]
constexpr size_t WT_Q  = WT_UP + 2048 * 512;     // [1024][1024]
constexpr size_t WT_K  = WT_Q + 1024 * 1024;
constexpr size_t WT_V  = WT_K + 1024 * 1024;
constexpr size_t WT_DN = WT_V + 1024 * 1024;     // [512][1024]
constexpr size_t WT_STRIDE = WT_DN + 512 * 1024; // 4,718,592 u16

typedef __attribute__((ext_vector_type(8))) short bf16x8;
typedef __attribute__((ext_vector_type(4))) float f32x4;
typedef __attribute__((ext_vector_type(4))) unsigned short ushort4v;
typedef __attribute__((ext_vector_type(8))) unsigned short ushort8v;
typedef unsigned short u16;

__device__ __forceinline__ float siluf(float x) { return x / (1.f + __expf(-x)); }
__device__ __forceinline__ u16 f2bf(float f) {
    unsigned int u = __float_as_uint(f);
    u = (u + 0x7FFFu + ((u >> 16) & 1u)) >> 16;
    return (u16)u;
}
__device__ __forceinline__ float bfu(u16 u) {
    return __uint_as_float(((unsigned int)u) << 16);
}

// ---------------------------------------------------------------- concat x + cls
__global__ __launch_bounds__(256) void concat_kernel(const float* __restrict__ x,
                                                     const float* __restrict__ cls,
                                                     float* __restrict__ h) {
    int idx = blockIdx.x * 256 + threadIdx.x;
    if (idx >= Bsz * TT * Dm) return;
    int d = idx & (Dm - 1);
    int bt = idx >> 9;
    int t = bt % TT, b = bt / TT;
    h[idx] = (t < T0) ? x[((size_t)(b * T0 + t)) * Dm + d] : cls[d];
}

// ---------------------------------------------------------------- LayerNorm rows of D=512
__global__ __launch_bounds__(256) void ln_kernel(const float* __restrict__ in,
                                                 const float* __restrict__ s,
                                                 const float* __restrict__ bb,
                                                 float* __restrict__ out) {
    int row = blockIdx.x, tid = threadIdx.x;
    const float* r = in + (size_t)row * Dm;
    __shared__ float s1[4], s2[4];
    float x0 = r[tid], x1 = r[tid + 256];
    float sum = x0 + x1, sq = x0 * x0 + x1 * x1;
#pragma unroll
    for (int o = 32; o > 0; o >>= 1) { sum += __shfl_xor(sum, o); sq += __shfl_xor(sq, o); }
    if ((tid & 63) == 0) { s1[tid >> 6] = sum; s2[tid >> 6] = sq; }
    __syncthreads();
    sum = s1[0] + s1[1] + s1[2] + s1[3];
    sq  = s2[0] + s2[1] + s2[2] + s2[3];
    float mu = sum / Dm, var = sq / Dm - mu * mu, inv = rsqrtf(var + EPSV);
    out[(size_t)row * Dm + tid]       = (x0 - mu) * inv * s[tid] + bb[tid];
    out[(size_t)row * Dm + tid + 256] = (x1 - mu) * inv * s[tid + 256] + bb[tid + 256];
}

// ---------------------------------------------------------------- weight transpose f32 KxN -> bf16 [N][K]
__global__ __launch_bounds__(256) void w_transpose_kernel(const float* __restrict__ wup,
        const float* __restrict__ wq, const float* __restrict__ wk,
        const float* __restrict__ wv, const float* __restrict__ wdn,
        u16* __restrict__ wt) {
    int y = blockIdx.y;             // 0..9
    int blk = y / 5, sel = y - blk * 5;
    int Kd, N; const float* src; size_t doff;
    if (sel == 0)      { Kd = 512;  N = 2048; src = wup + (size_t)blk * 512 * 2048; doff = WT_UP; }
    else if (sel == 1) { Kd = 1024; N = 1024; src = wq  + (size_t)blk * 1024 * 1024; doff = WT_Q; }
    else if (sel == 2) { Kd = 1024; N = 1024; src = wk  + (size_t)blk * 1024 * 1024; doff = WT_K; }
    else if (sel == 3) { Kd = 1024; N = 1024; src = wv  + (size_t)blk * 1024 * 1024; doff = WT_V; }
    else               { Kd = 1024; N = 512;  src = wdn + (size_t)blk * 1024 * 512;  doff = WT_DN; }
    u16* dst = wt + (size_t)blk * WT_STRIDE + doff;
    int ntx = N >> 5;
    int ntiles = ntx * (Kd >> 5);
    int ti = blockIdx.x;
    if (ti >= ntiles) return;
    int tk = ti / ntx, tn = ti - tk * ntx;
    __shared__ u16 s[32][33];
    int tx = threadIdx.x & 31, ty = threadIdx.x >> 5;
#pragma unroll
    for (int i = 0; i < 4; i++) {
        int k = tk * 32 + ty + i * 8;
        s[ty + i * 8][tx] = f2bf(src[(size_t)k * N + tn * 32 + tx]);
    }
    __syncthreads();
#pragma unroll
    for (int i = 0; i < 4; i++) {
        int n = tn * 32 + ty + i * 8;
        dst[(size_t)n * Kd + tk * 32 + tx] = s[tx][ty + i * 8];
    }
}

// ---------------------------------------------------------------- MFMA bf16 GEMM, double-buffered
__device__ __forceinline__ void gemm_tile_body(const float* __restrict__ A, int lda,
                                               const u16* __restrict__ Wt, int Kd,
                                               const float* __restrict__ bias,
                                               const float* __restrict__ resid, int ldr,
                                               float* __restrict__ Cout, int ldc,
                                               int M, float scale, int m0, int n0,
                                               u16 (*As)[128][40], u16 (*Bs)[128][40]) {
    int tid = threadIdx.x;
    int wave = tid >> 6, lane = tid & 63;
    int wm = (wave >> 1) * 64, wn = (wave & 1) * 64;
    int lrow = lane & 15, lquad = lane >> 4;

    f32x4 acc[4][4];
#pragma unroll
    for (int i = 0; i < 4; i++)
#pragma unroll
        for (int j = 0; j < 4; j++)
#pragma unroll
            for (int r = 0; r < 4; r++) acc[i][j][r] = 0.f;

    int am = tid >> 1, ak = (tid & 1) * 16;
    int bn = tid & 127, bk = (tid >> 7) * 16;
    int gm = m0 + am;
    const u16* wrow = Wt + (size_t)(n0 + bn) * Kd + bk;

    float4 a0, a1, a2, a3;
    ushort8v b0, b1;

    auto load_tile = [&](int k0) {
        if (gm < M) {
            const float4* ap = (const float4*)(A + (size_t)gm * lda + k0 + ak);
            a0 = ap[0]; a1 = ap[1]; a2 = ap[2]; a3 = ap[3];
        } else {
            a0 = a1 = a2 = a3 = make_float4(0.f, 0.f, 0.f, 0.f);
        }
        b0 = *(const ushort8v*)(wrow + k0);
        b1 = *(const ushort8v*)(wrow + k0 + 8);
    };
    auto store_tile = [&](int buf) {
        ushort4v t0 = {f2bf(a0.x), f2bf(a0.y), f2bf(a0.z), f2bf(a0.w)};
        ushort4v t1 = {f2bf(a1.x), f2bf(a1.y), f2bf(a1.z), f2bf(a1.w)};
        ushort4v t2 = {f2bf(a2.x), f2bf(a2.y), f2bf(a2.z), f2bf(a2.w)};
        ushort4v t3 = {f2bf(a3.x), f2bf(a3.y), f2bf(a3.z), f2bf(a3.w)};
        *(ushort4v*)&As[buf][am][ak + 0]  = t0;
        *(ushort4v*)&As[buf][am][ak + 4]  = t1;
        *(ushort4v*)&As[buf][am][ak + 8]  = t2;
        *(ushort4v*)&As[buf][am][ak + 12] = t3;
        *(ushort8v*)&Bs[buf][bn][bk]     = b0;
        *(ushort8v*)&Bs[buf][bn][bk + 8] = b1;
    };

    load_tile(0);
    store_tile(0);
    __syncthreads();

    int nk = Kd >> 5;
#pragma unroll 1
    for (int it = 0; it < nk; it++) {
        int cur = it & 1;
        bool more = (it + 1 < nk);
        if (more) load_tile((it + 1) << 5);
        bf16x8 afr[4], bfr[4];
#pragma unroll
        for (int mt = 0; mt < 4; mt++)
            afr[mt] = *(const bf16x8*)&As[cur][wm + mt * 16 + lrow][lquad * 8];
#pragma unroll
        for (int nt = 0; nt < 4; nt++)
            bfr[nt] = *(const bf16x8*)&Bs[cur][wn + nt * 16 + lrow][lquad * 8];
#pragma unroll
        for (int mt = 0; mt < 4; mt++)
#pragma unroll
            for (int nt = 0; nt < 4; nt++)
                acc[mt][nt] = __builtin_amdgcn_mfma_f32_16x16x32_bf16(
                    afr[mt], bfr[nt], acc[mt][nt], 0, 0, 0);
        if (more) store_tile(cur ^ 1);
        __syncthreads();
    }

#pragma unroll
    for (int mt = 0; mt < 4; mt++) {
#pragma unroll
        for (int r = 0; r < 4; r++) {
            int gmr = m0 + wm + mt * 16 + lquad * 4 + r;
            if (gmr >= M) continue;
#pragma unroll
            for (int nt = 0; nt < 4; nt++) {
                int gn = n0 + wn + nt * 16 + lrow;
                float v = acc[mt][nt][r] * scale;
                if (bias) v += bias[gn];
                if (resid) v += resid[(size_t)gmr * ldr + gn];
                Cout[(size_t)gmr * ldc + gn] = v;
            }
        }
    }
}

__global__ __launch_bounds__(256, 2) void gemm_mfma_kernel(const float* __restrict__ A, int lda,
                                                           const u16* __restrict__ Wt, int Kd,
                                                           const float* __restrict__ bias,
                                                           const float* __restrict__ resid, int ldr,
                                                           float* __restrict__ Cout, int ldc,
                                                           int M, float scale) {
    __shared__ __align__(16) u16 As[2][128][40];
    __shared__ __align__(16) u16 Bs[2][128][40];
    gemm_tile_body(A, lda, Wt, Kd, bias, resid, ldr, Cout, ldc, M, scale,
                   blockIdx.y * 128, blockIdx.x * 128, As, Bs);
}

__global__ __launch_bounds__(256, 2) void qkv_mfma_kernel(const float* __restrict__ xc,
                                                          const float* __restrict__ up,
                                                          const u16* __restrict__ wtblk,
                                                          float* __restrict__ fq,
                                                          float* __restrict__ fk,
                                                          float* __restrict__ fv,
                                                          float kscale) {
    __shared__ __align__(16) u16 As[2][128][40];
    __shared__ __align__(16) u16 Bs[2][128][40];
    int sel = blockIdx.x >> 3, nx = blockIdx.x & 7;
    const float* A = (sel == 2) ? up : xc;
    int lda = (sel == 2) ? 2 * IN : IN;
    const u16* Wt = wtblk + ((sel == 0) ? WT_Q : (sel == 1) ? WT_K : WT_V);
    float* C = (sel == 0) ? fq : (sel == 1) ? fk : fv;
    float scale = (sel == 1) ? kscale : 1.f;
    gemm_tile_body(A, lda, Wt, IN, nullptr, nullptr, 0, C, IN, ROWS, scale,
                   blockIdx.y * 128, nx * 128, As, Bs);
}

// ---------------------------------------------------------------- causal depthwise conv (K=4) + SiLU
__global__ __launch_bounds__(256) void conv_silu_kernel(const float* __restrict__ up,
                                                        const float* __restrict__ ck,
                                                        const float* __restrict__ cb,
                                                        float* __restrict__ xc) {
    int idx = blockIdx.x * 256 + threadIdx.x;
    if (idx >= ROWS * IN) return;
    int c = idx & (IN - 1);
    int bt = idx >> 10;
    int t = bt % TT, b = bt / TT;
    float acc = cb[c];
#pragma unroll
    for (int j = 0; j < KK; j++) {
        int tt = t - (KK - 1) + j;
        if (tt >= 0) acc += up[((size_t)(b * TT + tt)) * (2 * IN) + c] * ck[c * KK + j];
    }
    xc[idx] = siluf(acc);
}

// ---------------------------------------------------------------- gate weight transpose
__global__ __launch_bounds__(256) void gate_w_transpose(const float* __restrict__ wig,
                                                        const float* __restrict__ wfg,
                                                        float* __restrict__ wt) {
    int idx = blockIdx.x * 256 + threadIdx.x;
    int k = idx & 1023;
    int g = (idx >> 10) & 15;
    int blk = idx >> 14;
    const float* w = (g < 8) ? (wig + (size_t)blk * IN * NHh) : (wfg + (size_t)blk * IN * NHh);
    wt[idx] = w[k * NHh + (g & 7)];
}

// ---------------------------------------------------------------- gate projections (coalesced wt)
__global__ __launch_bounds__(256) void gates_kernel(const float* __restrict__ xc,
                                                    const float* __restrict__ wt,
                                                    const float* __restrict__ big,
                                                    const float* __restrict__ bfg,
                                                    float* __restrict__ ip, float* __restrict__ fp) {
    int row = blockIdx.x, tid = threadIdx.x;
    __shared__ float sx[IN];
    *(float4*)&sx[tid * 4] = *(const float4*)(xc + (size_t)row * IN + tid * 4);
    __syncthreads();
    int g = tid >> 4, l = tid & 15;
    const float* wrow = wt + g * IN;
    float acc = 0.f;
#pragma unroll
    for (int j = 0; j < 16; j++) {
        int k = j * 64 + l * 4;
        float4 w4 = *(const float4*)(wrow + k);
        float4 x4 = *(const float4*)&sx[k];
        acc += w4.x * x4.x + w4.y * x4.y + w4.z * x4.z + w4.w * x4.w;
    }
#pragma unroll
    for (int o = 8; o > 0; o >>= 1) acc += __shfl_down(acc, o, 16);
    if (l == 0) {
        if (g < 8) ip[(size_t)row * NHh + g] = acc + big[g];
        else       fp[(size_t)row * NHh + (g - 8)] = acc + bfg[g - 8];
    }
}

// ---------------------------------------------------------------- chunkwise mLSTM
__global__ __launch_bounds__(64) void gate_scan_kernel(const float* __restrict__ ip,
        const float* __restrict__ fp, float* __restrict__ gG, float* __restrict__ gM,
        float* __restrict__ gMb, float* __restrict__ gDec) {
    constexpr int PER = 9;
    int chain = blockIdx.x;
    int b = chain >> 3, h = chain & 7;
    int lane = threadIdx.x;
    int tbase = lane * PER;
    float lcs[PER];
    float gi[PER];
    float csum = 0.f;
#pragma unroll
    for (int i = 0; i < PER; i++) {
        int t = tbase + i;
        float fpv = 0.f, ipv = 0.f;
        if (t < TT) {
            size_t gidx = (size_t)(b * TT + t) * NHh + h;
            fpv = fp[gidx]; ipv = ip[gidx];
        }
        float flv = (fpv >= 0.f) ? -log1pf(__expf(-fpv)) : (fpv - log1pf(__expf(fpv)));
        if (t >= TT) flv = 0.f;
        csum += flv;
        lcs[i] = csum;
        gi[i] = ipv;
    }
    float ps = csum;
#pragma unroll
    for (int o = 1; o < 64; o <<= 1) {
        float v = __shfl_up(ps, o);
        if (lane >= o) ps += v;
    }
    float Fexcl = ps - csum;
    float G[PER];
    float cmax = -1e30f;
#pragma unroll
    for (int i = 0; i < PER; i++) {
        int t = tbase + i;
        G[i] = (t < TT) ? (gi[i] - (Fexcl + lcs[i])) : -1e30f;
        cmax = fmaxf(cmax, G[i]);
        lcs[i] = cmax;
    }
    float pm = cmax;
#pragma unroll
    for (int o = 1; o < 64; o <<= 1) {
        float v = __shfl_up(pm, o);
        if (lane >= o) pm = fmaxf(pm, v);
    }
    float Me = __shfl_up(pm, 1);
    if (lane == 0) Me = -1e30f;
    __shared__ float sMb[NCH];
#pragma unroll
    for (int i = 0; i < PER; i++) {
        int t = tbase + i;
        if (t < TT) {
            float Mt = fmaxf(0.f, fmaxf(Me, lcs[i]));
            gG[chain * TT + t] = G[i];
            gM[chain * TT + t] = Mt;
            if (((t & 63) == 63) || t == TT - 1) sMb[t >> 6] = Mt;
        }
    }
    __syncthreads();
    if (lane < NCH) {
        float Mb = sMb[lane];
        float Mbp = (lane == 0) ? 0.f : sMb[lane - 1];
        gMb[chain * NCH + lane] = Mb;
        gDec[chain * NCH + lane] = __expf(Mbp - Mb);
    }
}

// Kernel B1: per-chunk local state. NOTE: P now stored [e][d] (e-major) so
// chunk_out can stage it directly as an MFMA B-fragment. P[e][d] = C[d][e].
__global__ __launch_bounds__(256) void chunk_state_kernel(const float* __restrict__ kk,
        const float* __restrict__ vv, const float* __restrict__ gG,
        const float* __restrict__ gMb, float* __restrict__ P, float* __restrict__ nP) {
    int c = blockIdx.x, chain = blockIdx.y;
    int b = chain >> 3, h = chain & 7;
    int t0 = c * 64;
    int nvalid = min(64, TT - t0);
    __shared__ float sK[32][128], sV[32][128], sw[64];
    int tid = threadIdx.x;
    if (tid < 64) {
        float Mb = gMb[chain * NCH + c];
        sw[tid] = (tid < nvalid) ? __expf(gG[chain * TT + t0 + tid] - Mb) : 0.f;
    }
    int e = tid & 127, dg = (tid >> 7) * 64;
    float4 acc[16];
#pragma unroll
    for (int i = 0; i < 16; i++) acc[i] = make_float4(0.f, 0.f, 0.f, 0.f);
    float na = 0.f;
    for (int jh = 0; jh < 2; jh++) {
        int lrow = tid >> 5, lcol = (tid & 31) * 4;
        for (int rr = 0; rr < 4; rr++) {
            int r = lrow + rr * 8;
            int gr = jh * 32 + r;
            float4 kv = make_float4(0.f,0.f,0.f,0.f), vvv = kv;
            if (gr < nvalid) {
                size_t gb = ((size_t)(b * TT + t0 + gr)) * IN + h * DHd + lcol;
                kv = *(const float4*)(kk + gb);
                vvv = *(const float4*)(vv + gb);
            }
            *(float4*)&sK[r][lcol] = kv;
            *(float4*)&sV[r][lcol] = vvv;
        }
        __syncthreads();
        int jmax = min(32, nvalid - jh * 32);
#pragma unroll 1
        for (int j = 0; j < jmax; j++) {
            float wvj = sw[jh * 32 + j] * sV[j][e];
            const float4* kr = (const float4*)&sK[j][dg];
#pragma unroll
            for (int d4 = 0; d4 < 16; d4++) {
                float4 kq = kr[d4];
                acc[d4].x += kq.x * wvj; acc[d4].y += kq.y * wvj;
                acc[d4].z += kq.z * wvj; acc[d4].w += kq.w * wvj;
            }
        }
        if (tid < 128) {
#pragma unroll 1
            for (int j = 0; j < jmax; j++) na += sw[jh * 32 + j] * sK[j][tid];
        }
        __syncthreads();
    }
    float* Pbase = P + (((size_t)(c * 32 + chain)) << 14);
#pragma unroll
    for (int d4 = 0; d4 < 16; d4++)
        *(float4*)&Pbase[(size_t)e * 128 + dg + d4 * 4] = acc[d4];
    if (tid < 128) nP[(size_t)(c * 32 + chain) * 128 + tid] = na;
}

// Kernel B2: in-place exclusive combine over chunks (layout-agnostic, flat).
__global__ __launch_bounds__(256) void chunk_combine_kernel(float* __restrict__ P,
        const float* __restrict__ gDec) {
    int chain = blockIdx.x >> 6;
    int idx = (blockIdx.x & 63) * 256 + threadIdx.x;
    float run = 0.f;
    for (int c = 0; c < NCH; c++) {
        size_t a = (((size_t)(c * 32 + chain)) << 14) + idx;
        float tmp = P[a];
        P[a] = run;
        run = run * gDec[chain * NCH + c] + tmp;
    }
}

__global__ __launch_bounds__(256) void n_combine_kernel(float* __restrict__ nP,
        const float* __restrict__ gDec) {
    int gidx = blockIdx.x * 256 + threadIdx.x;
    int chain = gidx >> 7, d = gidx & 127;
    float run = 0.f;
    for (int c = 0; c < NCH; c++) {
        size_t a = (size_t)(c * 32 + chain) * 128 + d;
        float tmp = nP[a];
        nP[a] = run;
        run = run * gDec[chain * NCH + c] + tmp;
    }
}

// Kernel C v2: all three matmuls on MFMA, shared C-layout accumulator.
// 8 waves: wave = mq(4) x nh(2). acc covers rows mq*16..+15, cols nh*64..+63.
// Phase0 inter = Q@CB (CB staged from P[e][d]); phase1 S=QK^T -> weights ->
// sD bf16 + in-reg rowsums; phase2 denom; phase3 acc += D@V (V^T staged).
__global__ __launch_bounds__(512, 2) void chunk_out_kernel(const float* __restrict__ qq,
        const float* __restrict__ kk, const float* __restrict__ vv,
        const float* __restrict__ gG, const float* __restrict__ gM,
        const float* __restrict__ gMb, const float* __restrict__ P,
        const float* __restrict__ nP, float* __restrict__ hs) {
    int c = blockIdx.x, chain = blockIdx.y;
    int b = chain >> 3, h = chain & 7;
    int t0 = c * 64;
    int nvalid = min(64, TT - t0);
    __shared__ __align__(16) u16 smem[30720];   // 61.4 KB arena
    __shared__ float sG[64], sM[64], sWr[64], sInv[64], sNb[128], sRS[2][64];
    u16* sQ  = smem;            // [64][136] bf16   (phases 0-2)
    u16* sCB = smem + 8704;     // [128][136] bf16  (phase 0)
    u16* sK  = smem + 8704;     // [64][136] bf16   (phase 1, overlays sCB)
    u16* sVt = smem;            // [128][72] bf16   (phase 3, overlays sQ)
    u16* sD  = smem + 26112;    // [64][72] bf16    (phase 1 write, 3 read)
    int tid = threadIdx.x;
    int wave = tid >> 6, lane = tid & 63;
    int lrow = lane & 15, lquad = lane >> 4;
    int mq = wave >> 1, nh = wave & 1;

    float Mbprev = (c > 0) ? gMb[chain * NCH + c - 1] : 0.f;
    if (tid < 64) {
        bool val = tid < nvalid;
        sG[tid] = val ? gG[chain * TT + t0 + tid] : -1e30f;
        float Mv = val ? gM[chain * TT + t0 + tid] : 1e30f;
        sM[tid] = Mv;
        sWr[tid] = val ? __expf(Mbprev - Mv) : 0.f;
    }
    if (tid >= 128 && tid < 256) sNb[tid - 128] = nP[(size_t)(c * 32 + chain) * 128 + (tid - 128)];

    // ---- stage sQ [64][136]
    {
        int lr = tid >> 3, c0 = (tid & 7) * 16;
        bool val = lr < nvalid;
        size_t gb = ((size_t)(b * TT + t0 + lr)) * IN + h * DHd + c0;
#pragma unroll
        for (int i = 0; i < 4; i++) {
            float4 q4 = val ? *(const float4*)(qq + gb + i * 4) : make_float4(0.f,0.f,0.f,0.f);
            ushort4v tq = {f2bf(q4.x), f2bf(q4.y), f2bf(q4.z), f2bf(q4.w)};
            *(ushort4v*)&sQ[lr * 136 + c0 + i * 4] = tq;
        }
    }
    // ---- stage sCB [128][136] from P[e][d]
    {
        const float* CBbase = P + (((size_t)(c * 32 + chain)) << 14);
        int e = tid >> 2, d0 = (tid & 3) * 32;
#pragma unroll
        for (int i = 0; i < 8; i++) {
            float4 c4 = *(const float4*)(CBbase + (size_t)e * 128 + d0 + i * 4);
            ushort4v tc = {f2bf(c4.x), f2bf(c4.y), f2bf(c4.z), f2bf(c4.w)};
            *(ushort4v*)&sCB[e * 136 + d0 + i * 4] = tc;
        }
    }
    __syncthreads();

    // ---- phase 0: inter = Q @ CB, C-layout acc; then scale by wr
    f32x4 acc[4];
#pragma unroll
    for (int tt = 0; tt < 4; tt++)
#pragma unroll
        for (int r = 0; r < 4; r++) acc[tt][r] = 0.f;
#pragma unroll 1
    for (int ks = 0; ks < 4; ks++) {
        bf16x8 af = *(const bf16x8*)&sQ[(mq * 16 + lrow) * 136 + ks * 32 + lquad * 8];
#pragma unroll
        for (int tt = 0; tt < 4; tt++) {
            bf16x8 bf = *(const bf16x8*)&sCB[(nh * 64 + tt * 16 + lrow) * 136 + ks * 32 + lquad * 8];
            acc[tt] = __builtin_amdgcn_mfma_f32_16x16x32_bf16(af, bf, acc[tt], 0, 0, 0);
        }
    }
#pragma unroll
    for (int tt = 0; tt < 4; tt++)
#pragma unroll
        for (int r = 0; r < 4; r++) acc[tt][r] *= sWr[mq * 16 + lquad * 4 + r];
    __syncthreads();

    // ---- stage sK (overlays sCB)
    {
        int lr = tid >> 3, c0 = (tid & 7) * 16;
        bool val = lr < nvalid;
        size_t gb = ((size_t)(b * TT + t0 + lr)) * IN + h * DHd + c0;
#pragma unroll
        for (int i = 0; i < 4; i++) {
            float4 k4 = val ? *(const float4*)(kk + gb + i * 4) : make_float4(0.f,0.f,0.f,0.f);
            ushort4v tk = {f2bf(k4.x), f2bf(k4.y), f2bf(k4.z), f2bf(k4.w)};
            *(ushort4v*)&sK[lr * 136 + c0 + i * 4] = tk;
        }
    }
    __syncthreads();

    // ---- phase 1: S = Q K^T (2 n-tiles/wave), weights, sD bf16, in-reg rowsums
    {
        f32x4 accS[2];
#pragma unroll
        for (int tt = 0; tt < 2; tt++)
#pragma unroll
            for (int r = 0; r < 4; r++) accS[tt][r] = 0.f;
#pragma unroll 1
        for (int ks = 0; ks < 4; ks++) {
            bf16x8 af = *(const bf16x8*)&sQ[(mq * 16 + lrow) * 136 + ks * 32 + lquad * 8];
#pragma unroll
            for (int tt = 0; tt < 2; tt++) {
                bf16x8 bf = *(const bf16x8*)&sK[((nh * 2 + tt) * 16 + lrow) * 136 + ks * 32 + lquad * 8];
                accS[tt] = __builtin_amdgcn_mfma_f32_16x16x32_bf16(af, bf, accS[tt], 0, 0, 0);
            }
        }
        float rsum[4] = {0.f, 0.f, 0.f, 0.f};
#pragma unroll
        for (int tt = 0; tt < 2; tt++) {
            int j = (nh * 2 + tt) * 16 + lrow;
            float Gj = sG[j];
#pragma unroll
            for (int r = 0; r < 4; r++) {
                int t = mq * 16 + lquad * 4 + r;
                float w = (j <= t) ? __expf(Gj - sM[t]) : 0.f;
                float wD = accS[tt][r] * w;
                rsum[r] += wD;
                sD[t * 72 + j] = f2bf(wD);
            }
        }
#pragma unroll
        for (int r = 0; r < 4; r++) {
#pragma unroll
            for (int msk = 1; msk < 16; msk <<= 1) rsum[r] += __shfl_xor(rsum[r], msk);
        }
        if (lrow == 0) {
#pragma unroll
            for (int r = 0; r < 4; r++) sRS[nh][mq * 16 + lquad * 4 + r] = rsum[r];
        }
    }
    __syncthreads();

    // ---- phase 2: denominators (tid<64); qnb from bf16 sQ
    if (tid < 64) {
        float qn = 0.f;
#pragma unroll 1
        for (int d4 = 0; d4 < 32; d4++) {
            ushort4v q4 = *(const ushort4v*)&sQ[tid * 136 + d4 * 4];
            float4 nb = *(const float4*)&sNb[d4 * 4];
            qn += bfu(q4.x) * nb.x + bfu(q4.y) * nb.y + bfu(q4.z) * nb.z + bfu(q4.w) * nb.w;
        }
        float den = sRS[0][tid] + sRS[1][tid] + sWr[tid] * qn;
        sInv[tid] = 1.f / fmaxf(fabsf(den), 1.f);
    }
    __syncthreads();

    // ---- stage sVt [128][72] = V^T bf16 (overlays sQ)
    {
        int e = tid & 127, tg = (tid >> 7) * 16;
#pragma unroll 1
        for (int i = 0; i < 16; i++) {
            int t = tg + i;
            float v = (t < nvalid) ? vv[((size_t)(b * TT + t0 + t)) * IN + h * DHd + e] : 0.f;
            sVt[e * 72 + t] = f2bf(v);
        }
    }
    __syncthreads();

    // ---- phase 3: acc += D @ V (same tile ownership as phase 0)
#pragma unroll 1
    for (int ks = 0; ks < 2; ks++) {
        bf16x8 af = *(const bf16x8*)&sD[(mq * 16 + lrow) * 72 + ks * 32 + lquad * 8];
#pragma unroll
        for (int tt = 0; tt < 4; tt++) {
            bf16x8 bf = *(const bf16x8*)&sVt[(nh * 64 + tt * 16 + lrow) * 72 + ks * 32 + lquad * 8];
            acc[tt] = __builtin_amdgcn_mfma_f32_16x16x32_bf16(af, bf, acc[tt], 0, 0, 0);
        }
    }

    // ---- store (C-layout: col=lane&15 -> e, row=quad*4+r -> t)
#pragma unroll
    for (int tt = 0; tt < 4; tt++) {
#pragma unroll
        for (int r = 0; r < 4; r++) {
            int t = mq * 16 + lquad * 4 + r;
            if (t < nvalid) {
                int e = nh * 64 + tt * 16 + lrow;
                hs[((size_t)(b * TT + t0 + t)) * IN + h * DHd + e] = acc[tt][r] * sInv[t];
            }
        }
    }
}

// ---------------------------------------------------------------- per-head norm * hn_s * silu(z)
__global__ __launch_bounds__(64) void headnorm_kernel(const float* __restrict__ hs,
                                                      const float* __restrict__ hn,
                                                      const float* __restrict__ up,
                                                      float* __restrict__ out) {
    int idx = blockIdx.x;
    int h = idx & 7, bt = idx >> 3;
    int tid = threadIdx.x;
    size_t base = (size_t)bt * IN + h * DHd;
    float x0 = hs[base + tid], x1 = hs[base + 64 + tid];
    float sum = x0 + x1, sq = x0 * x0 + x1 * x1;
#pragma unroll
    for (int o = 32; o > 0; o >>= 1) { sum += __shfl_xor(sum, o); sq += __shfl_xor(sq, o); }
    float mu = sum / DHd, var = sq / DHd - mu * mu, inv = rsqrtf(var + EPSV);
    size_t zb = (size_t)bt * (2 * IN) + IN + h * DHd;
    out[base + tid]      = (x0 - mu) * inv * hn[h * DHd + tid]      * siluf(up[zb + tid]);
    out[base + 64 + tid] = (x1 - mu) * inv * hn[h * DHd + 64 + tid] * siluf(up[zb + 64 + tid]);
}

// ---------------------------------------------------------------- head: LN+ReLU of cls rows -> vcls
__global__ __launch_bounds__(256) void cls_ln_kernel(const float* __restrict__ hbuf,
                                                     const float* __restrict__ s, const float* __restrict__ bb,
                                                     float* __restrict__ vcls) {
    int b = blockIdx.x, tid = threadIdx.x;
    const float* r = hbuf + ((size_t)b * TT + TT - 1) * Dm;
    __shared__ float s1[4], s2[4];
    float x0 = r[tid], x1 = r[tid + 256];
    float sum = x0 + x1, sq = x0 * x0 + x1 * x1;
#pragma unroll
    for (int o = 32; o > 0; o >>= 1) { sum += __shfl_xor(sum, o); sq += __shfl_xor(sq, o); }
    if ((tid & 63) == 0) { s1[tid >> 6] = sum; s2[tid >> 6] = sq; }
    __syncthreads();
    sum = s1[0] + s1[1] + s1[2] + s1[3];
    sq  = s2[0] + s2[1] + s2[2] + s2[3];
    float mu = sum / Dm, var = sq / Dm - mu * mu, inv = rsqrtf(var + EPSV);
    float n0 = (x0 - mu) * inv * s[tid] + bb[tid];
    float n1 = (x1 - mu) * inv * s[tid + 256] + bb[tid + 256];
    vcls[b * Dm + tid]       = fmaxf(n0, 0.f);
    vcls[b * Dm + tid + 256] = fmaxf(n1, 0.f);
}

// ---------------------------------------------------------------- head: FC
__global__ __launch_bounds__(256) void fc_kernel(const float* __restrict__ vcls,
                                                 const float* __restrict__ fw,
                                                 const float* __restrict__ fb,
                                                 float* __restrict__ out) {
    __shared__ float svc[Bsz][Dm];
    __shared__ float sred[4][256];
    int tid = threadIdx.x;
    int j0 = blockIdx.x * 64;
    {
        const float4* src = (const float4*)vcls;
        float4* dst = (float4*)&svc[0][0];
        dst[tid] = src[tid];
        dst[tid + 256] = src[tid + 256];
    }
    __syncthreads();
    int j = j0 + (tid & 63);
    int chunk = tid >> 6;
    int kbase = chunk * 128;
    float a0 = 0.f, a1 = 0.f, a2 = 0.f, a3 = 0.f;
    if (j < NCc) {
        const float* fwp = fw + (size_t)kbase * NCc + j;
#pragma unroll 4
        for (int kk = 0; kk < 128; kk++) {
            float w = fwp[(size_t)kk * NCc];
            a0 += svc[0][kbase + kk] * w;
            a1 += svc[1][kbase + kk] * w;
            a2 += svc[2][kbase + kk] * w;
            a3 += svc[3][kbase + kk] * w;
        }
    }
    int jl = tid & 63;
    sred[chunk][jl * 4 + 0] = a0;
    sred[chunk][jl * 4 + 1] = a1;
    sred[chunk][jl * 4 + 2] = a2;
    sred[chunk][jl * 4 + 3] = a3;
    __syncthreads();
    if (tid < 64) {
        int jj = j0 + tid;
        if (jj < NCc) {
            float bias = fb[jj];
#pragma unroll
            for (int b = 0; b < Bsz; b++) {
                float v = sred[0][tid * 4 + b] + sred[1][tid * 4 + b]
                        + sred[2][tid * 4 + b] + sred[3][tid * 4 + b];
                out[b * NCc + jj] = v + bias;
            }
        }
    }
}

// ---------------------------------------------------------------- launch
extern "C" void kernel_launch(void* const* d_in, const int* in_sizes, int n_in,
                              void* d_out, int out_size, void* d_ws, size_t ws_size,
                              hipStream_t stream) {
    const float* x      = (const float*)d_in[0];
    const float* cls    = (const float*)d_in[1];
    const float* ln_s   = (const float*)d_in[2];
    const float* ln_b   = (const float*)d_in[3];
    const float* w_up   = (const float*)d_in[4];
    const float* b_up   = (const float*)d_in[5];
    const float* conv_k = (const float*)d_in[6];
    const float* conv_b = (const float*)d_in[7];
    const float* w_q    = (const float*)d_in[8];
    const float* w_k    = (const float*)d_in[9];
    const float* w_v    = (const float*)d_in[10];
    const float* w_ig   = (const float*)d_in[11];
    const float* b_ig   = (const float*)d_in[12];
    const float* w_fg   = (const float*)d_in[13];
    const float* b_fg   = (const float*)d_in[14];
    const float* hn_s   = (const float*)d_in[15];
    const float* w_down = (const float*)d_in[16];
    const float* b_down = (const float*)d_in[17];
    const float* fcls   = (const float*)d_in[18];
    const float* fclb   = (const float*)d_in[19];
    const float* fc_w   = (const float*)d_in[20];
    const float* fc_b   = (const float*)d_in[21];
    float* out = (float*)d_out;

    float* ws = (float*)d_ws;
    size_t off = 0;
    float* f_h  = ws + off; off += (size_t)ROWS * Dm;
    float* f_xn = ws + off; off += (size_t)ROWS * Dm;
    float* f_up = ws + off; off += (size_t)ROWS * 2 * IN;
    float* f_xc = ws + off; off += (size_t)ROWS * IN;
    float* f_q  = ws + off; off += (size_t)ROWS * IN;
    float* f_k  = ws + off; off += (size_t)ROWS * IN;
    float* f_v  = ws + off; off += (size_t)ROWS * IN;
    float* f_hs = ws + off; off += (size_t)ROWS * IN;
    float* f_ip = ws + off; off += (size_t)ROWS * NHh;
    float* f_fp = ws + off; off += (size_t)ROWS * NHh;
    float* g_G  = ws + off; off += 32 * TT;
    float* g_M  = ws + off; off += 32 * TT;
    float* g_Mb = ws + off; off += 32 * NCH;
    float* g_De = ws + off; off += 32 * NCH;
    float* g_P  = ws + off; off += (size_t)NCH * 32 * DHd * DHd;
    float* g_nP = ws + off; off += (size_t)NCH * 32 * DHd;
    float* f_vc = ws + off; off += Bsz * Dm;
    float* g_wt = ws + off; off += 2 * 16 * IN;
    u16* g_Wt = (u16*)(ws + off); off += (2 * WT_STRIDE + 1) / 2;

    const float kscale = 0.08838834764831845f; // DH^-0.5
    const int MB = (ROWS + 127) / 128;         // 17

    concat_kernel<<<(ROWS * Dm + 255) / 256, 256, 0, stream>>>(x, cls, f_h);
    gate_w_transpose<<<(2 * 16 * IN + 255) / 256, 256, 0, stream>>>(w_ig, w_fg, g_wt);
    w_transpose_kernel<<<dim3(1024, 10), 256, 0, stream>>>(w_up, w_q, w_k, w_v, w_down, g_Wt);

    for (int blk = 0; blk < 2; blk++) {
        const float* p_ln_s = ln_s + blk * Dm;
        const float* p_ln_b = ln_b + blk * Dm;
        const float* p_bup  = b_up + (size_t)blk * 2 * IN;
        const float* p_ck   = conv_k + (size_t)blk * IN * KK;
        const float* p_cb   = conv_b + (size_t)blk * IN;
        const float* p_big  = b_ig + (size_t)blk * NHh;
        const float* p_bfg  = b_fg + (size_t)blk * NHh;
        const float* p_hns  = hn_s + (size_t)blk * NHh * DHd;
        const float* p_bd   = b_down + (size_t)blk * Dm;
        const u16*   p_wt   = g_Wt + (size_t)blk * WT_STRIDE;

        ln_kernel<<<ROWS, 256, 0, stream>>>(f_h, p_ln_s, p_ln_b, f_xn);

        gemm_mfma_kernel<<<dim3(2 * IN / 128, MB), 256, 0, stream>>>(
            f_xn, Dm, p_wt + WT_UP, Dm, p_bup, nullptr, 0, f_up, 2 * IN, ROWS, 1.f);

        conv_silu_kernel<<<(ROWS * IN + 255) / 256, 256, 0, stream>>>(f_up, p_ck, p_cb, f_xc);

        qkv_mfma_kernel<<<dim3(24, MB), 256, 0, stream>>>(
            f_xc, f_up, p_wt, f_q, f_k, f_v, kscale);

        gates_kernel<<<ROWS, 256, 0, stream>>>(f_xc, g_wt + blk * 16 * IN, p_big, p_bfg,
                                               f_ip, f_fp);

        // chunkwise-parallel mLSTM
        gate_scan_kernel<<<32, 64, 0, stream>>>(f_ip, f_fp, g_G, g_M, g_Mb, g_De);
        chunk_state_kernel<<<dim3(NCH, 32), 256, 0, stream>>>(f_k, f_v, g_G, g_Mb, g_P, g_nP);
        chunk_combine_kernel<<<32 * 64, 256, 0, stream>>>(g_P, g_De);
        n_combine_kernel<<<16, 256, 0, stream>>>(g_nP, g_De);
        chunk_out_kernel<<<dim3(NCH, 32), 512, 0, stream>>>(f_q, f_k, f_v, g_G, g_M, g_Mb,
                                                            g_P, g_nP, f_hs);

        headnorm_kernel<<<ROWS * NHh, 64, 0, stream>>>(f_hs, p_hns, f_up, f_xc);

        gemm_mfma_kernel<<<dim3(Dm / 128, MB), 256, 0, stream>>>(
            f_xc, IN, p_wt + WT_DN, IN, p_bd, f_h, Dm, f_h, Dm, ROWS, 1.f);
    }

    cls_ln_kernel<<<Bsz, 256, 0, stream>>>(f_h, fcls, fclb, f_vc);
    fc_kernel<<<(NCc + 63) / 64, 256, 0, stream>>>(f_vc, fc_w, fc_b, out);
}

// Round 13
// 561.368 us; speedup vs baseline: 5.6974x; 1.0721x over previous
//
#include <hip/hip_runtime.h>

// ---------------------------------------------------------------- constants
#define EPSV 1e-5f
constexpr int Bsz = 4, T0 = 512, Dm = 512, TT = 513, NHh = 8, KK = 4;
constexpr int IN = 1024, DHd = 128, NCc = 1000;
constexpr int ROWS = Bsz * TT; // 2052
constexpr int NCH = 9;         // chunks of 64: 8*64 + 1 = 513

// bf16 k-major weight buffer offsets (u16 elements), per transformer block
constexpr size_t WT_UP = 0;                      // [2048][512]
constexpr size_t WT_Q  = WT_UP + 2048 * 512;     // [1024][1024]
constexpr size_t WT_K  = WT_Q + 1024 * 1024;
constexpr size_t WT_V  = WT_K + 1024 * 1024;
constexpr size_t WT_DN = WT_V + 1024 * 1024;     // [512][1024]
constexpr size_t WT_STRIDE = WT_DN + 512 * 1024; // 4,718,592 u16

typedef __attribute__((ext_vector_type(8))) short bf16x8;
typedef __attribute__((ext_vector_type(4))) float f32x4;
typedef __attribute__((ext_vector_type(4))) unsigned short ushort4v;
typedef __attribute__((ext_vector_type(8))) unsigned short ushort8v;
typedef unsigned short u16;

__device__ __forceinline__ float siluf(float x) { return x / (1.f + __expf(-x)); }
__device__ __forceinline__ u16 f2bf(float f) {
    unsigned int u = __float_as_uint(f);
    u = (u + 0x7FFFu + ((u >> 16) & 1u)) >> 16;
    return (u16)u;
}
__device__ __forceinline__ float bfu(u16 u) {
    return __uint_as_float(((unsigned int)u) << 16);
}

// ---------------------------------------------------------------- concat x + cls
__global__ __launch_bounds__(256) void concat_kernel(const float* __restrict__ x,
                                                     const float* __restrict__ cls,
                                                     float* __restrict__ h) {
    int idx = blockIdx.x * 256 + threadIdx.x;
    if (idx >= Bsz * TT * Dm) return;
    int d = idx & (Dm - 1);
    int bt = idx >> 9;
    int t = bt % TT, b = bt / TT;
    h[idx] = (t < T0) ? x[((size_t)(b * T0 + t)) * Dm + d] : cls[d];
}

// ---------------------------------------------------------------- LayerNorm rows of D=512
__global__ __launch_bounds__(256) void ln_kernel(const float* __restrict__ in,
                                                 const float* __restrict__ s,
                                                 const float* __restrict__ bb,
                                                 float* __restrict__ out) {
    int row = blockIdx.x, tid = threadIdx.x;
    const float* r = in + (size_t)row * Dm;
    __shared__ float s1[4], s2[4];
    float x0 = r[tid], x1 = r[tid + 256];
    float sum = x0 + x1, sq = x0 * x0 + x1 * x1;
#pragma unroll
    for (int o = 32; o > 0; o >>= 1) { sum += __shfl_xor(sum, o); sq += __shfl_xor(sq, o); }
    if ((tid & 63) == 0) { s1[tid >> 6] = sum; s2[tid >> 6] = sq; }
    __syncthreads();
    sum = s1[0] + s1[1] + s1[2] + s1[3];
    sq  = s2[0] + s2[1] + s2[2] + s2[3];
    float mu = sum / Dm, var = sq / Dm - mu * mu, inv = rsqrtf(var + EPSV);
    out[(size_t)row * Dm + tid]       = (x0 - mu) * inv * s[tid] + bb[tid];
    out[(size_t)row * Dm + tid + 256] = (x1 - mu) * inv * s[tid + 256] + bb[tid + 256];
}

// ---------------------------------------------------------------- weight transpose f32 KxN -> bf16 [N][K]
__global__ __launch_bounds__(256) void w_transpose_kernel(const float* __restrict__ wup,
        const float* __restrict__ wq, const float* __restrict__ wk,
        const float* __restrict__ wv, const float* __restrict__ wdn,
        u16* __restrict__ wt) {
    int y = blockIdx.y;             // 0..9
    int blk = y / 5, sel = y - blk * 5;
    int Kd, N; const float* src; size_t doff;
    if (sel == 0)      { Kd = 512;  N = 2048; src = wup + (size_t)blk * 512 * 2048; doff = WT_UP; }
    else if (sel == 1) { Kd = 1024; N = 1024; src = wq  + (size_t)blk * 1024 * 1024; doff = WT_Q; }
    else if (sel == 2) { Kd = 1024; N = 1024; src = wk  + (size_t)blk * 1024 * 1024; doff = WT_K; }
    else if (sel == 3) { Kd = 1024; N = 1024; src = wv  + (size_t)blk * 1024 * 1024; doff = WT_V; }
    else               { Kd = 1024; N = 512;  src = wdn + (size_t)blk * 1024 * 512;  doff = WT_DN; }
    u16* dst = wt + (size_t)blk * WT_STRIDE + doff;
    int ntx = N >> 5;
    int ntiles = ntx * (Kd >> 5);
    int ti = blockIdx.x;
    if (ti >= ntiles) return;
    int tk = ti / ntx, tn = ti - tk * ntx;
    __shared__ u16 s[32][33];
    int tx = threadIdx.x & 31, ty = threadIdx.x >> 5;
#pragma unroll
    for (int i = 0; i < 4; i++) {
        int k = tk * 32 + ty + i * 8;
        s[ty + i * 8][tx] = f2bf(src[(size_t)k * N + tn * 32 + tx]);
    }
    __syncthreads();
#pragma unroll
    for (int i = 0; i < 4; i++) {
        int n = tn * 32 + ty + i * 8;
        dst[(size_t)n * Kd + tk * 32 + tx] = s[tx][ty + i * 8];
    }
}

// ---------------------------------------------------------------- MFMA bf16 GEMM, double-buffered
// Templated tile (BM x BN), 256 threads, waves 2x2. BK=32.
template<int BM, int BN>
__device__ __forceinline__ void gemm_tile_body(const float* __restrict__ A, int lda,
                                               const u16* __restrict__ Wt, int Kd,
                                               const float* __restrict__ bias,
                                               const float* __restrict__ resid, int ldr,
                                               float* __restrict__ Cout, int ldc,
                                               int M, float scale, int m0, int n0,
                                               u16 (*As)[BM][40], u16 (*Bs)[BN][40]) {
    constexpr int MT = BM / 32;            // mfma m-tiles per wave
    constexpr int NT = BN / 32;            // mfma n-tiles per wave
    constexpr int ANF4 = BM / 32;          // float4 A-loads per thread
    constexpr int BNV = BN / 64;           // ushort8 B-loads per thread
    int tid = threadIdx.x;
    int wave = tid >> 6, lane = tid & 63;
    int wm = (wave >> 1) * (BM / 2), wn = (wave & 1) * (BN / 2);
    int lrow = lane & 15, lquad = lane >> 4;

    f32x4 acc[MT][NT];
#pragma unroll
    for (int i = 0; i < MT; i++)
#pragma unroll
        for (int j = 0; j < NT; j++)
#pragma unroll
            for (int r = 0; r < 4; r++) acc[i][j][r] = 0.f;

    int am, ak, bn, bk;
    if (BM == 128) { am = tid >> 1; ak = (tid & 1) * 16; }
    else           { am = tid >> 2; ak = (tid & 3) * 8; }
    if (BN == 128) { bn = tid & 127; bk = (tid >> 7) * 16; }
    else           { bn = tid & 63;  bk = (tid >> 6) * 8; }
    int gm = m0 + am;
    const u16* wrow = Wt + (size_t)(n0 + bn) * Kd + bk;

    float4 areg[ANF4];
    ushort8v breg[BNV];

    auto load_tile = [&](int k0) {
        if (gm < M) {
            const float4* ap = (const float4*)(A + (size_t)gm * lda + k0 + ak);
#pragma unroll
            for (int i = 0; i < ANF4; i++) areg[i] = ap[i];
        } else {
#pragma unroll
            for (int i = 0; i < ANF4; i++) areg[i] = make_float4(0.f, 0.f, 0.f, 0.f);
        }
#pragma unroll
        for (int i = 0; i < BNV; i++) breg[i] = *(const ushort8v*)(wrow + k0 + i * 8);
    };
    auto store_tile = [&](int buf) {
#pragma unroll
        for (int i = 0; i < ANF4; i++) {
            ushort4v t = {f2bf(areg[i].x), f2bf(areg[i].y), f2bf(areg[i].z), f2bf(areg[i].w)};
            *(ushort4v*)&As[buf][am][ak + i * 4] = t;
        }
#pragma unroll
        for (int i = 0; i < BNV; i++)
            *(ushort8v*)&Bs[buf][bn][bk + i * 8] = breg[i];
    };

    load_tile(0);
    store_tile(0);
    __syncthreads();

    int nk = Kd >> 5;
#pragma unroll 1
    for (int it = 0; it < nk; it++) {
        int cur = it & 1;
        bool more = (it + 1 < nk);
        if (more) load_tile((it + 1) << 5);
        bf16x8 afr[MT], bfr[NT];
#pragma unroll
        for (int mt = 0; mt < MT; mt++)
            afr[mt] = *(const bf16x8*)&As[cur][wm + mt * 16 + lrow][lquad * 8];
#pragma unroll
        for (int nt = 0; nt < NT; nt++)
            bfr[nt] = *(const bf16x8*)&Bs[cur][wn + nt * 16 + lrow][lquad * 8];
#pragma unroll
        for (int mt = 0; mt < MT; mt++)
#pragma unroll
            for (int nt = 0; nt < NT; nt++)
                acc[mt][nt] = __builtin_amdgcn_mfma_f32_16x16x32_bf16(
                    afr[mt], bfr[nt], acc[mt][nt], 0, 0, 0);
        if (more) store_tile(cur ^ 1);
        __syncthreads();
    }

#pragma unroll
    for (int mt = 0; mt < MT; mt++) {
#pragma unroll
        for (int r = 0; r < 4; r++) {
            int gmr = m0 + wm + mt * 16 + lquad * 4 + r;
            if (gmr >= M) continue;
#pragma unroll
            for (int nt = 0; nt < NT; nt++) {
                int gn = n0 + wn + nt * 16 + lrow;
                float v = acc[mt][nt][r] * scale;
                if (bias) v += bias[gn];
                if (resid) v += resid[(size_t)gmr * ldr + gn];
                Cout[(size_t)gmr * ldc + gn] = v;
            }
        }
    }
}

template<int BM, int BN>
__global__ __launch_bounds__(256, 2) void gemm_mfma_kernel(const float* __restrict__ A, int lda,
                                                           const u16* __restrict__ Wt, int Kd,
                                                           const float* __restrict__ bias,
                                                           const float* __restrict__ resid, int ldr,
                                                           float* __restrict__ Cout, int ldc,
                                                           int M, float scale) {
    __shared__ __align__(16) u16 As[2][BM][40];
    __shared__ __align__(16) u16 Bs[2][BN][40];
    gemm_tile_body<BM, BN>(A, lda, Wt, Kd, bias, resid, ldr, Cout, ldc, M, scale,
                           blockIdx.y * BM, blockIdx.x * BN, As, Bs);
}

// q/k/v in ONE dispatch, BN=64: blockIdx.x in [0,48): sel = x>>4, nx = x&15.
__global__ __launch_bounds__(256, 2) void qkv_mfma_kernel(const float* __restrict__ xc,
                                                          const float* __restrict__ up,
                                                          const u16* __restrict__ wtblk,
                                                          float* __restrict__ fq,
                                                          float* __restrict__ fk,
                                                          float* __restrict__ fv,
                                                          float kscale) {
    __shared__ __align__(16) u16 As[2][128][40];
    __shared__ __align__(16) u16 Bs[2][64][40];
    int sel = blockIdx.x >> 4, nx = blockIdx.x & 15;
    const float* A = (sel == 2) ? up : xc;
    int lda = (sel == 2) ? 2 * IN : IN;
    const u16* Wt = wtblk + ((sel == 0) ? WT_Q : (sel == 1) ? WT_K : WT_V);
    float* C = (sel == 0) ? fq : (sel == 1) ? fk : fv;
    float scale = (sel == 1) ? kscale : 1.f;
    gemm_tile_body<128, 64>(A, lda, Wt, IN, nullptr, nullptr, 0, C, IN, ROWS, scale,
                            blockIdx.y * 128, nx * 64, As, Bs);
}

// ---------------------------------------------------------------- causal depthwise conv (K=4) + SiLU
__global__ __launch_bounds__(256) void conv_silu_kernel(const float* __restrict__ up,
                                                        const float* __restrict__ ck,
                                                        const float* __restrict__ cb,
                                                        float* __restrict__ xc) {
    int idx = blockIdx.x * 256 + threadIdx.x;
    if (idx >= ROWS * IN) return;
    int c = idx & (IN - 1);
    int bt = idx >> 10;
    int t = bt % TT, b = bt / TT;
    float acc = cb[c];
#pragma unroll
    for (int j = 0; j < KK; j++) {
        int tt = t - (KK - 1) + j;
        if (tt >= 0) acc += up[((size_t)(b * TT + tt)) * (2 * IN) + c] * ck[c * KK + j];
    }
    xc[idx] = siluf(acc);
}

// ---------------------------------------------------------------- gate weight transpose
__global__ __launch_bounds__(256) void gate_w_transpose(const float* __restrict__ wig,
                                                        const float* __restrict__ wfg,
                                                        float* __restrict__ wt) {
    int idx = blockIdx.x * 256 + threadIdx.x;
    int k = idx & 1023;
    int g = (idx >> 10) & 15;
    int blk = idx >> 14;
    const float* w = (g < 8) ? (wig + (size_t)blk * IN * NHh) : (wfg + (size_t)blk * IN * NHh);
    wt[idx] = w[k * NHh + (g & 7)];
}

// ---------------------------------------------------------------- gate projections (coalesced wt)
__global__ __launch_bounds__(256) void gates_kernel(const float* __restrict__ xc,
                                                    const float* __restrict__ wt,
                                                    const float* __restrict__ big,
                                                    const float* __restrict__ bfg,
                                                    float* __restrict__ ip, float* __restrict__ fp) {
    int row = blockIdx.x, tid = threadIdx.x;
    __shared__ float sx[IN];
    *(float4*)&sx[tid * 4] = *(const float4*)(xc + (size_t)row * IN + tid * 4);
    __syncthreads();
    int g = tid >> 4, l = tid & 15;
    const float* wrow = wt + g * IN;
    float acc = 0.f;
#pragma unroll
    for (int j = 0; j < 16; j++) {
        int k = j * 64 + l * 4;
        float4 w4 = *(const float4*)(wrow + k);
        float4 x4 = *(const float4*)&sx[k];
        acc += w4.x * x4.x + w4.y * x4.y + w4.z * x4.z + w4.w * x4.w;
    }
#pragma unroll
    for (int o = 8; o > 0; o >>= 1) acc += __shfl_down(acc, o, 16);
    if (l == 0) {
        if (g < 8) ip[(size_t)row * NHh + g] = acc + big[g];
        else       fp[(size_t)row * NHh + (g - 8)] = acc + bfg[g - 8];
    }
}

// ---------------------------------------------------------------- chunkwise mLSTM
__global__ __launch_bounds__(64) void gate_scan_kernel(const float* __restrict__ ip,
        const float* __restrict__ fp, float* __restrict__ gG, float* __restrict__ gM,
        float* __restrict__ gMb, float* __restrict__ gDec) {
    constexpr int PER = 9;
    int chain = blockIdx.x;
    int b = chain >> 3, h = chain & 7;
    int lane = threadIdx.x;
    int tbase = lane * PER;
    float lcs[PER];
    float gi[PER];
    float csum = 0.f;
#pragma unroll
    for (int i = 0; i < PER; i++) {
        int t = tbase + i;
        float fpv = 0.f, ipv = 0.f;
        if (t < TT) {
            size_t gidx = (size_t)(b * TT + t) * NHh + h;
            fpv = fp[gidx]; ipv = ip[gidx];
        }
        float flv = (fpv >= 0.f) ? -log1pf(__expf(-fpv)) : (fpv - log1pf(__expf(fpv)));
        if (t >= TT) flv = 0.f;
        csum += flv;
        lcs[i] = csum;
        gi[i] = ipv;
    }
    float ps = csum;
#pragma unroll
    for (int o = 1; o < 64; o <<= 1) {
        float v = __shfl_up(ps, o);
        if (lane >= o) ps += v;
    }
    float Fexcl = ps - csum;
    float G[PER];
    float cmax = -1e30f;
#pragma unroll
    for (int i = 0; i < PER; i++) {
        int t = tbase + i;
        G[i] = (t < TT) ? (gi[i] - (Fexcl + lcs[i])) : -1e30f;
        cmax = fmaxf(cmax, G[i]);
        lcs[i] = cmax;
    }
    float pm = cmax;
#pragma unroll
    for (int o = 1; o < 64; o <<= 1) {
        float v = __shfl_up(pm, o);
        if (lane >= o) pm = fmaxf(pm, v);
    }
    float Me = __shfl_up(pm, 1);
    if (lane == 0) Me = -1e30f;
    __shared__ float sMb[NCH];
#pragma unroll
    for (int i = 0; i < PER; i++) {
        int t = tbase + i;
        if (t < TT) {
            float Mt = fmaxf(0.f, fmaxf(Me, lcs[i]));
            gG[chain * TT + t] = G[i];
            gM[chain * TT + t] = Mt;
            if (((t & 63) == 63) || t == TT - 1) sMb[t >> 6] = Mt;
        }
    }
    __syncthreads();
    if (lane < NCH) {
        float Mb = sMb[lane];
        float Mbp = (lane == 0) ? 0.f : sMb[lane - 1];
        gMb[chain * NCH + lane] = Mb;
        gDec[chain * NCH + lane] = __expf(Mbp - Mb);
    }
}

// Kernel B1: per-chunk local state. P stored [e][d] (e-major).
__global__ __launch_bounds__(256) void chunk_state_kernel(const float* __restrict__ kk,
        const float* __restrict__ vv, const float* __restrict__ gG,
        const float* __restrict__ gMb, float* __restrict__ P, float* __restrict__ nP) {
    int c = blockIdx.x, chain = blockIdx.y;
    int b = chain >> 3, h = chain & 7;
    int t0 = c * 64;
    int nvalid = min(64, TT - t0);
    __shared__ float sK[32][128], sV[32][128], sw[64];
    int tid = threadIdx.x;
    if (tid < 64) {
        float Mb = gMb[chain * NCH + c];
        sw[tid] = (tid < nvalid) ? __expf(gG[chain * TT + t0 + tid] - Mb) : 0.f;
    }
    int e = tid & 127, dg = (tid >> 7) * 64;
    float4 acc[16];
#pragma unroll
    for (int i = 0; i < 16; i++) acc[i] = make_float4(0.f, 0.f, 0.f, 0.f);
    float na = 0.f;
    for (int jh = 0; jh < 2; jh++) {
        int lrow = tid >> 5, lcol = (tid & 31) * 4;
        for (int rr = 0; rr < 4; rr++) {
            int r = lrow + rr * 8;
            int gr = jh * 32 + r;
            float4 kv = make_float4(0.f,0.f,0.f,0.f), vvv = kv;
            if (gr < nvalid) {
                size_t gb = ((size_t)(b * TT + t0 + gr)) * IN + h * DHd + lcol;
                kv = *(const float4*)(kk + gb);
                vvv = *(const float4*)(vv + gb);
            }
            *(float4*)&sK[r][lcol] = kv;
            *(float4*)&sV[r][lcol] = vvv;
        }
        __syncthreads();
        int jmax = min(32, nvalid - jh * 32);
#pragma unroll 1
        for (int j = 0; j < jmax; j++) {
            float wvj = sw[jh * 32 + j] * sV[j][e];
            const float4* kr = (const float4*)&sK[j][dg];
#pragma unroll
            for (int d4 = 0; d4 < 16; d4++) {
                float4 kq = kr[d4];
                acc[d4].x += kq.x * wvj; acc[d4].y += kq.y * wvj;
                acc[d4].z += kq.z * wvj; acc[d4].w += kq.w * wvj;
            }
        }
        if (tid < 128) {
#pragma unroll 1
            for (int j = 0; j < jmax; j++) na += sw[jh * 32 + j] * sK[j][tid];
        }
        __syncthreads();
    }
    float* Pbase = P + (((size_t)(c * 32 + chain)) << 14);
#pragma unroll
    for (int d4 = 0; d4 < 16; d4++)
        *(float4*)&Pbase[(size_t)e * 128 + dg + d4 * 4] = acc[d4];
    if (tid < 128) nP[(size_t)(c * 32 + chain) * 128 + tid] = na;
}

// Kernel B2: in-place exclusive combine over chunks.
__global__ __launch_bounds__(256) void chunk_combine_kernel(float* __restrict__ P,
        const float* __restrict__ gDec) {
    int chain = blockIdx.x >> 6;
    int idx = (blockIdx.x & 63) * 256 + threadIdx.x;
    float run = 0.f;
    for (int c = 0; c < NCH; c++) {
        size_t a = (((size_t)(c * 32 + chain)) << 14) + idx;
        float tmp = P[a];
        P[a] = run;
        run = run * gDec[chain * NCH + c] + tmp;
    }
}

__global__ __launch_bounds__(256) void n_combine_kernel(float* __restrict__ nP,
        const float* __restrict__ gDec) {
    int gidx = blockIdx.x * 256 + threadIdx.x;
    int chain = gidx >> 7, d = gidx & 127;
    float run = 0.f;
    for (int c = 0; c < NCH; c++) {
        size_t a = (size_t)(c * 32 + chain) * 128 + d;
        float tmp = nP[a];
        nP[a] = run;
        run = run * gDec[chain * NCH + c] + tmp;
    }
}

// Kernel C: MFMA chunk outputs (shared C-layout accumulator).
__global__ __launch_bounds__(512, 2) void chunk_out_kernel(const float* __restrict__ qq,
        const float* __restrict__ kk, const float* __restrict__ vv,
        const float* __restrict__ gG, const float* __restrict__ gM,
        const float* __restrict__ gMb, const float* __restrict__ P,
        const float* __restrict__ nP, float* __restrict__ hs) {
    int c = blockIdx.x, chain = blockIdx.y;
    int b = chain >> 3, h = chain & 7;
    int t0 = c * 64;
    int nvalid = min(64, TT - t0);
    __shared__ __align__(16) u16 smem[30720];   // 61.4 KB arena
    __shared__ float sG[64], sM[64], sWr[64], sInv[64], sNb[128], sRS[2][64];
    u16* sQ  = smem;            // [64][136] bf16   (phases 0-2)
    u16* sCB = smem + 8704;     // [128][136] bf16  (phase 0)
    u16* sK  = smem + 8704;     // [64][136] bf16   (phase 1, overlays sCB)
    u16* sVt = smem;            // [128][72] bf16   (phase 3, overlays sQ)
    u16* sD  = smem + 26112;    // [64][72] bf16    (phase 1 write, 3 read)
    int tid = threadIdx.x;
    int wave = tid >> 6, lane = tid & 63;
    int lrow = lane & 15, lquad = lane >> 4;
    int mq = wave >> 1, nh = wave & 1;

    float Mbprev = (c > 0) ? gMb[chain * NCH + c - 1] : 0.f;
    if (tid < 64) {
        bool val = tid < nvalid;
        sG[tid] = val ? gG[chain * TT + t0 + tid] : -1e30f;
        float Mv = val ? gM[chain * TT + t0 + tid] : 1e30f;
        sM[tid] = Mv;
        sWr[tid] = val ? __expf(Mbprev - Mv) : 0.f;
    }
    if (tid >= 128 && tid < 256) sNb[tid - 128] = nP[(size_t)(c * 32 + chain) * 128 + (tid - 128)];

    // ---- stage sQ [64][136]
    {
        int lr = tid >> 3, c0 = (tid & 7) * 16;
        bool val = lr < nvalid;
        size_t gb = ((size_t)(b * TT + t0 + lr)) * IN + h * DHd + c0;
#pragma unroll
        for (int i = 0; i < 4; i++) {
            float4 q4 = val ? *(const float4*)(qq + gb + i * 4) : make_float4(0.f,0.f,0.f,0.f);
            ushort4v tq = {f2bf(q4.x), f2bf(q4.y), f2bf(q4.z), f2bf(q4.w)};
            *(ushort4v*)&sQ[lr * 136 + c0 + i * 4] = tq;
        }
    }
    // ---- stage sCB [128][136] from P[e][d]
    {
        const float* CBbase = P + (((size_t)(c * 32 + chain)) << 14);
        int e = tid >> 2, d0 = (tid & 3) * 32;
#pragma unroll
        for (int i = 0; i < 8; i++) {
            float4 c4 = *(const float4*)(CBbase + (size_t)e * 128 + d0 + i * 4);
            ushort4v tc = {f2bf(c4.x), f2bf(c4.y), f2bf(c4.z), f2bf(c4.w)};
            *(ushort4v*)&sCB[e * 136 + d0 + i * 4] = tc;
        }
    }
    __syncthreads();

    // ---- phase 0: inter = Q @ CB, C-layout acc; then scale by wr
    f32x4 acc[4];
#pragma unroll
    for (int tt = 0; tt < 4; tt++)
#pragma unroll
        for (int r = 0; r < 4; r++) acc[tt][r] = 0.f;
#pragma unroll 1
    for (int ks = 0; ks < 4; ks++) {
        bf16x8 af = *(const bf16x8*)&sQ[(mq * 16 + lrow) * 136 + ks * 32 + lquad * 8];
#pragma unroll
        for (int tt = 0; tt < 4; tt++) {
            bf16x8 bf = *(const bf16x8*)&sCB[(nh * 64 + tt * 16 + lrow) * 136 + ks * 32 + lquad * 8];
            acc[tt] = __builtin_amdgcn_mfma_f32_16x16x32_bf16(af, bf, acc[tt], 0, 0, 0);
        }
    }
#pragma unroll
    for (int tt = 0; tt < 4; tt++)
#pragma unroll
        for (int r = 0; r < 4; r++) acc[tt][r] *= sWr[mq * 16 + lquad * 4 + r];
    __syncthreads();

    // ---- stage sK (overlays sCB)
    {
        int lr = tid >> 3, c0 = (tid & 7) * 16;
        bool val = lr < nvalid;
        size_t gb = ((size_t)(b * TT + t0 + lr)) * IN + h * DHd + c0;
#pragma unroll
        for (int i = 0; i < 4; i++) {
            float4 k4 = val ? *(const float4*)(kk + gb + i * 4) : make_float4(0.f,0.f,0.f,0.f);
            ushort4v tk = {f2bf(k4.x), f2bf(k4.y), f2bf(k4.z), f2bf(k4.w)};
            *(ushort4v*)&sK[lr * 136 + c0 + i * 4] = tk;
        }
    }
    __syncthreads();

    // ---- phase 1: S = Q K^T (2 n-tiles/wave), weights, sD bf16, in-reg rowsums
    {
        f32x4 accS[2];
#pragma unroll
        for (int tt = 0; tt < 2; tt++)
#pragma unroll
            for (int r = 0; r < 4; r++) accS[tt][r] = 0.f;
#pragma unroll 1
        for (int ks = 0; ks < 4; ks++) {
            bf16x8 af = *(const bf16x8*)&sQ[(mq * 16 + lrow) * 136 + ks * 32 + lquad * 8];
#pragma unroll
            for (int tt = 0; tt < 2; tt++) {
                bf16x8 bf = *(const bf16x8*)&sK[((nh * 2 + tt) * 16 + lrow) * 136 + ks * 32 + lquad * 8];
                accS[tt] = __builtin_amdgcn_mfma_f32_16x16x32_bf16(af, bf, accS[tt], 0, 0, 0);
            }
        }
        float rsum[4] = {0.f, 0.f, 0.f, 0.f};
#pragma unroll
        for (int tt = 0; tt < 2; tt++) {
            int j = (nh * 2 + tt) * 16 + lrow;
            float Gj = sG[j];
#pragma unroll
            for (int r = 0; r < 4; r++) {
                int t = mq * 16 + lquad * 4 + r;
                float w = (j <= t) ? __expf(Gj - sM[t]) : 0.f;
                float wD = accS[tt][r] * w;
                rsum[r] += wD;
                sD[t * 72 + j] = f2bf(wD);
            }
        }
#pragma unroll
        for (int r = 0; r < 4; r++) {
#pragma unroll
            for (int msk = 1; msk < 16; msk <<= 1) rsum[r] += __shfl_xor(rsum[r], msk);
        }
        if (lrow == 0) {
#pragma unroll
            for (int r = 0; r < 4; r++) sRS[nh][mq * 16 + lquad * 4 + r] = rsum[r];
        }
    }
    __syncthreads();

    // ---- phase 2: denominators (tid<64); qnb from bf16 sQ
    if (tid < 64) {
        float qn = 0.f;
#pragma unroll 1
        for (int d4 = 0; d4 < 32; d4++) {
            ushort4v q4 = *(const ushort4v*)&sQ[tid * 136 + d4 * 4];
            float4 nb = *(const float4*)&sNb[d4 * 4];
            qn += bfu(q4.x) * nb.x + bfu(q4.y) * nb.y + bfu(q4.z) * nb.z + bfu(q4.w) * nb.w;
        }
        float den = sRS[0][tid] + sRS[1][tid] + sWr[tid] * qn;
        sInv[tid] = 1.f / fmaxf(fabsf(den), 1.f);
    }
    __syncthreads();

    // ---- stage sVt [128][72] = V^T bf16 (overlays sQ)
    {
        int e = tid & 127, tg = (tid >> 7) * 16;
#pragma unroll 1
        for (int i = 0; i < 16; i++) {
            int t = tg + i;
            float v = (t < nvalid) ? vv[((size_t)(b * TT + t0 + t)) * IN + h * DHd + e] : 0.f;
            sVt[e * 72 + t] = f2bf(v);
        }
    }
    __syncthreads();

    // ---- phase 3: acc += D @ V
#pragma unroll 1
    for (int ks = 0; ks < 2; ks++) {
        bf16x8 af = *(const bf16x8*)&sD[(mq * 16 + lrow) * 72 + ks * 32 + lquad * 8];
#pragma unroll
        for (int tt = 0; tt < 4; tt++) {
            bf16x8 bf = *(const bf16x8*)&sVt[(nh * 64 + tt * 16 + lrow) * 72 + ks * 32 + lquad * 8];
            acc[tt] = __builtin_amdgcn_mfma_f32_16x16x32_bf16(af, bf, acc[tt], 0, 0, 0);
        }
    }

    // ---- store (C-layout: col=lane&15 -> e, row=quad*4+r -> t)
#pragma unroll
    for (int tt = 0; tt < 4; tt++) {
#pragma unroll
        for (int r = 0; r < 4; r++) {
            int t = mq * 16 + lquad * 4 + r;
            if (t < nvalid) {
                int e = nh * 64 + tt * 16 + lrow;
                hs[((size_t)(b * TT + t0 + t)) * IN + h * DHd + e] = acc[tt][r] * sInv[t];
            }
        }
    }
}

// ---------------------------------------------------------------- per-head norm * hn_s * silu(z)
__global__ __launch_bounds__(64) void headnorm_kernel(const float* __restrict__ hs,
                                                      const float* __restrict__ hn,
                                                      const float* __restrict__ up,
                                                      float* __restrict__ out) {
    int idx = blockIdx.x;
    int h = idx & 7, bt = idx >> 3;
    int tid = threadIdx.x;
    size_t base = (size_t)bt * IN + h * DHd;
    float x0 = hs[base + tid], x1 = hs[base + 64 + tid];
    float sum = x0 + x1, sq = x0 * x0 + x1 * x1;
#pragma unroll
    for (int o = 32; o > 0; o >>= 1) { sum += __shfl_xor(sum, o); sq += __shfl_xor(sq, o); }
    float mu = sum / DHd, var = sq / DHd - mu * mu, inv = rsqrtf(var + EPSV);
    size_t zb = (size_t)bt * (2 * IN) + IN + h * DHd;
    out[base + tid]      = (x0 - mu) * inv * hn[h * DHd + tid]      * siluf(up[zb + tid]);
    out[base + 64 + tid] = (x1 - mu) * inv * hn[h * DHd + 64 + tid] * siluf(up[zb + 64 + tid]);
}

// ---------------------------------------------------------------- head: LN+ReLU of cls rows -> vcls
__global__ __launch_bounds__(256) void cls_ln_kernel(const float* __restrict__ hbuf,
                                                     const float* __restrict__ s, const float* __restrict__ bb,
                                                     float* __restrict__ vcls) {
    int b = blockIdx.x, tid = threadIdx.x;
    const float* r = hbuf + ((size_t)b * TT + TT - 1) * Dm;
    __shared__ float s1[4], s2[4];
    float x0 = r[tid], x1 = r[tid + 256];
    float sum = x0 + x1, sq = x0 * x0 + x1 * x1;
#pragma unroll
    for (int o = 32; o > 0; o >>= 1) { sum += __shfl_xor(sum, o); sq += __shfl_xor(sq, o); }
    if ((tid & 63) == 0) { s1[tid >> 6] = sum; s2[tid >> 6] = sq; }
    __syncthreads();
    sum = s1[0] + s1[1] + s1[2] + s1[3];
    sq  = s2[0] + s2[1] + s2[2] + s2[3];
    float mu = sum / Dm, var = sq / Dm - mu * mu, inv = rsqrtf(var + EPSV);
    float n0 = (x0 - mu) * inv * s[tid] + bb[tid];
    float n1 = (x1 - mu) * inv * s[tid + 256] + bb[tid + 256];
    vcls[b * Dm + tid]       = fmaxf(n0, 0.f);
    vcls[b * Dm + tid + 256] = fmaxf(n1, 0.f);
}

// ---------------------------------------------------------------- head: FC
__global__ __launch_bounds__(256) void fc_kernel(const float* __restrict__ vcls,
                                                 const float* __restrict__ fw,
                                                 const float* __restrict__ fb,
                                                 float* __restrict__ out) {
    __shared__ float svc[Bsz][Dm];
    __shared__ float sred[4][256];
    int tid = threadIdx.x;
    int j0 = blockIdx.x * 64;
    {
        const float4* src = (const float4*)vcls;
        float4* dst = (float4*)&svc[0][0];
        dst[tid] = src[tid];
        dst[tid + 256] = src[tid + 256];
    }
    __syncthreads();
    int j = j0 + (tid & 63);
    int chunk = tid >> 6;
    int kbase = chunk * 128;
    float a0 = 0.f, a1 = 0.f, a2 = 0.f, a3 = 0.f;
    if (j < NCc) {
        const float* fwp = fw + (size_t)kbase * NCc + j;
#pragma unroll 4
        for (int kk = 0; kk < 128; kk++) {
            float w = fwp[(size_t)kk * NCc];
            a0 += svc[0][kbase + kk] * w;
            a1 += svc[1][kbase + kk] * w;
            a2 += svc[2][kbase + kk] * w;
            a3 += svc[3][kbase + kk] * w;
        }
    }
    int jl = tid & 63;
    sred[chunk][jl * 4 + 0] = a0;
    sred[chunk][jl * 4 + 1] = a1;
    sred[chunk][jl * 4 + 2] = a2;
    sred[chunk][jl * 4 + 3] = a3;
    __syncthreads();
    if (tid < 64) {
        int jj = j0 + tid;
        if (jj < NCc) {
            float bias = fb[jj];
#pragma unroll
            for (int b = 0; b < Bsz; b++) {
                float v = sred[0][tid * 4 + b] + sred[1][tid * 4 + b]
                        + sred[2][tid * 4 + b] + sred[3][tid * 4 + b];
                out[b * NCc + jj] = v + bias;
            }
        }
    }
}

// ---------------------------------------------------------------- launch
extern "C" void kernel_launch(void* const* d_in, const int* in_sizes, int n_in,
                              void* d_out, int out_size, void* d_ws, size_t ws_size,
                              hipStream_t stream) {
    const float* x      = (const float*)d_in[0];
    const float* cls    = (const float*)d_in[1];
    const float* ln_s   = (const float*)d_in[2];
    const float* ln_b   = (const float*)d_in[3];
    const float* w_up   = (const float*)d_in[4];
    const float* b_up   = (const float*)d_in[5];
    const float* conv_k = (const float*)d_in[6];
    const float* conv_b = (const float*)d_in[7];
    const float* w_q    = (const float*)d_in[8];
    const float* w_k    = (const float*)d_in[9];
    const float* w_v    = (const float*)d_in[10];
    const float* w_ig   = (const float*)d_in[11];
    const float* b_ig   = (const float*)d_in[12];
    const float* w_fg   = (const float*)d_in[13];
    const float* b_fg   = (const float*)d_in[14];
    const float* hn_s   = (const float*)d_in[15];
    const float* w_down = (const float*)d_in[16];
    const float* b_down = (const float*)d_in[17];
    const float* fcls   = (const float*)d_in[18];
    const float* fclb   = (const float*)d_in[19];
    const float* fc_w   = (const float*)d_in[20];
    const float* fc_b   = (const float*)d_in[21];
    float* out = (float*)d_out;

    float* ws = (float*)d_ws;
    size_t off = 0;
    float* f_h  = ws + off; off += (size_t)ROWS * Dm;
    float* f_xn = ws + off; off += (size_t)ROWS * Dm;
    float* f_up = ws + off; off += (size_t)ROWS * 2 * IN;
    float* f_xc = ws + off; off += (size_t)ROWS * IN;
    float* f_q  = ws + off; off += (size_t)ROWS * IN;
    float* f_k  = ws + off; off += (size_t)ROWS * IN;
    float* f_v  = ws + off; off += (size_t)ROWS * IN;
    float* f_hs = ws + off; off += (size_t)ROWS * IN;
    float* f_ip = ws + off; off += (size_t)ROWS * NHh;
    float* f_fp = ws + off; off += (size_t)ROWS * NHh;
    float* g_G  = ws + off; off += 32 * TT;
    float* g_M  = ws + off; off += 32 * TT;
    float* g_Mb = ws + off; off += 32 * NCH;
    float* g_De = ws + off; off += 32 * NCH;
    float* g_P  = ws + off; off += (size_t)NCH * 32 * DHd * DHd;
    float* g_nP = ws + off; off += (size_t)NCH * 32 * DHd;
    float* f_vc = ws + off; off += Bsz * Dm;
    float* g_wt = ws + off; off += 2 * 16 * IN;
    u16* g_Wt = (u16*)(ws + off); off += (2 * WT_STRIDE + 1) / 2;

    const float kscale = 0.08838834764831845f; // DH^-0.5
    const int MB = (ROWS + 127) / 128;         // 17
    const int MB64 = (ROWS + 63) / 64;         // 33

    concat_kernel<<<(ROWS * Dm + 255) / 256, 256, 0, stream>>>(x, cls, f_h);
    gate_w_transpose<<<(2 * 16 * IN + 255) / 256, 256, 0, stream>>>(w_ig, w_fg, g_wt);
    w_transpose_kernel<<<dim3(1024, 10), 256, 0, stream>>>(w_up, w_q, w_k, w_v, w_down, g_Wt);

    for (int blk = 0; blk < 2; blk++) {
        const float* p_ln_s = ln_s + blk * Dm;
        const float* p_ln_b = ln_b + blk * Dm;
        const float* p_bup  = b_up + (size_t)blk * 2 * IN;
        const float* p_ck   = conv_k + (size_t)blk * IN * KK;
        const float* p_cb   = conv_b + (size_t)blk * IN;
        const float* p_big  = b_ig + (size_t)blk * NHh;
        const float* p_bfg  = b_fg + (size_t)blk * NHh;
        const float* p_hns  = hn_s + (size_t)blk * NHh * DHd;
        const float* p_bd   = b_down + (size_t)blk * Dm;
        const u16*   p_wt   = g_Wt + (size_t)blk * WT_STRIDE;

        ln_kernel<<<ROWS, 256, 0, stream>>>(f_h, p_ln_s, p_ln_b, f_xn);

        gemm_mfma_kernel<128, 64><<<dim3(2 * IN / 64, MB), 256, 0, stream>>>(
            f_xn, Dm, p_wt + WT_UP, Dm, p_bup, nullptr, 0, f_up, 2 * IN, ROWS, 1.f);

        conv_silu_kernel<<<(ROWS * IN + 255) / 256, 256, 0, stream>>>(f_up, p_ck, p_cb, f_xc);

        qkv_mfma_kernel<<<dim3(48, MB), 256, 0, stream>>>(
            f_xc, f_up, p_wt, f_q, f_k, f_v, kscale);

        gates_kernel<<<ROWS, 256, 0, stream>>>(f_xc, g_wt + blk * 16 * IN, p_big, p_bfg,
                                               f_ip, f_fp);

        // chunkwise-parallel mLSTM
        gate_scan_kernel<<<32, 64, 0, stream>>>(f_ip, f_fp, g_G, g_M, g_Mb, g_De);
        chunk_state_kernel<<<dim3(NCH, 32), 256, 0, stream>>>(f_k, f_v, g_G, g_Mb, g_P, g_nP);
        chunk_combine_kernel<<<32 * 64, 256, 0, stream>>>(g_P, g_De);
        n_combine_kernel<<<16, 256, 0, stream>>>(g_nP, g_De);
        chunk_out_kernel<<<dim3(NCH, 32), 512, 0, stream>>>(f_q, f_k, f_v, g_G, g_M, g_Mb,
                                                            g_P, g_nP, f_hs);

        headnorm_kernel<<<ROWS * NHh, 64, 0, stream>>>(f_hs, p_hns, f_up, f_xc);

        gemm_mfma_kernel<64, 64><<<dim3(Dm / 64, MB64), 256, 0, stream>>>(
            f_xc, IN, p_wt + WT_DN, IN, p_bd, f_h, Dm, f_h, Dm, ROWS, 1.f);
    }

    cls_ln_kernel<<<Bsz, 256, 0, stream>>>(f_h, fcls, fclb, f_vc);
    fc_kernel<<<(NCc + 63) / 64, 256, 0, stream>>>(f_vc, fc_w, fc_b, out);
}

// Round 14
// 515.296 us; speedup vs baseline: 6.2068x; 1.0894x over previous
//
#include <hip/hip_runtime.h>

// ---------------------------------------------------------------- constants
#define EPSV 1e-5f
constexpr int Bsz = 4, T0 = 512, Dm = 512, TT = 513, NHh = 8, KK = 4;
constexpr int IN = 1024, DHd = 128, NCc = 1000;
constexpr int ROWS = Bsz * TT; // 2052
constexpr int NCH = 9;         // chunks of 64: 8*64 + 1 = 513

// bf16 k-major weight buffer offsets (u16 elements), per transformer block
constexpr size_t WT_UP = 0;                      // [2048][512]
constexpr size_t WT_Q  = WT_UP + 2048 * 512;     // [1024][1024]
constexpr size_t WT_K  = WT_Q + 1024 * 1024;
constexpr size_t WT_V  = WT_K + 1024 * 1024;
constexpr size_t WT_DN = WT_V + 1024 * 1024;     // [512][1024]
constexpr size_t WT_STRIDE = WT_DN + 512 * 1024; // 4,718,592 u16

typedef __attribute__((ext_vector_type(8))) short bf16x8;
typedef __attribute__((ext_vector_type(4))) float f32x4;
typedef __attribute__((ext_vector_type(4))) unsigned short ushort4v;
typedef __attribute__((ext_vector_type(8))) unsigned short ushort8v;
typedef unsigned short u16;

__device__ __forceinline__ float siluf(float x) { return x / (1.f + __expf(-x)); }
__device__ __forceinline__ u16 f2bf(float f) {
    unsigned int u = __float_as_uint(f);
    u = (u + 0x7FFFu + ((u >> 16) & 1u)) >> 16;
    return (u16)u;
}
__device__ __forceinline__ float bfu(u16 u) {
    return __uint_as_float(((unsigned int)u) << 16);
}

// ---------------------------------------------------------------- concat x + cls
__global__ __launch_bounds__(256) void concat_kernel(const float* __restrict__ x,
                                                     const float* __restrict__ cls,
                                                     float* __restrict__ h) {
    int idx = blockIdx.x * 256 + threadIdx.x;
    if (idx >= Bsz * TT * Dm) return;
    int d = idx & (Dm - 1);
    int bt = idx >> 9;
    int t = bt % TT, b = bt / TT;
    h[idx] = (t < T0) ? x[((size_t)(b * T0 + t)) * Dm + d] : cls[d];
}

// ---------------------------------------------------------------- LayerNorm rows of D=512 -> bf16
__global__ __launch_bounds__(256) void ln_kernel(const float* __restrict__ in,
                                                 const float* __restrict__ s,
                                                 const float* __restrict__ bb,
                                                 u16* __restrict__ out16) {
    int row = blockIdx.x, tid = threadIdx.x;
    const float* r = in + (size_t)row * Dm;
    __shared__ float s1[4], s2[4];
    float x0 = r[tid], x1 = r[tid + 256];
    float sum = x0 + x1, sq = x0 * x0 + x1 * x1;
#pragma unroll
    for (int o = 32; o > 0; o >>= 1) { sum += __shfl_xor(sum, o); sq += __shfl_xor(sq, o); }
    if ((tid & 63) == 0) { s1[tid >> 6] = sum; s2[tid >> 6] = sq; }
    __syncthreads();
    sum = s1[0] + s1[1] + s1[2] + s1[3];
    sq  = s2[0] + s2[1] + s2[2] + s2[3];
    float mu = sum / Dm, var = sq / Dm - mu * mu, inv = rsqrtf(var + EPSV);
    out16[(size_t)row * Dm + tid]       = f2bf((x0 - mu) * inv * s[tid] + bb[tid]);
    out16[(size_t)row * Dm + tid + 256] = f2bf((x1 - mu) * inv * s[tid + 256] + bb[tid + 256]);
}

// ---------------------------------------------------------------- weight transpose f32 KxN -> bf16 [N][K]
__global__ __launch_bounds__(256) void w_transpose_kernel(const float* __restrict__ wup,
        const float* __restrict__ wq, const float* __restrict__ wk,
        const float* __restrict__ wv, const float* __restrict__ wdn,
        u16* __restrict__ wt) {
    int y = blockIdx.y;             // 0..9
    int blk = y / 5, sel = y - blk * 5;
    int Kd, N; const float* src; size_t doff;
    if (sel == 0)      { Kd = 512;  N = 2048; src = wup + (size_t)blk * 512 * 2048; doff = WT_UP; }
    else if (sel == 1) { Kd = 1024; N = 1024; src = wq  + (size_t)blk * 1024 * 1024; doff = WT_Q; }
    else if (sel == 2) { Kd = 1024; N = 1024; src = wk  + (size_t)blk * 1024 * 1024; doff = WT_K; }
    else if (sel == 3) { Kd = 1024; N = 1024; src = wv  + (size_t)blk * 1024 * 1024; doff = WT_V; }
    else               { Kd = 1024; N = 512;  src = wdn + (size_t)blk * 1024 * 512;  doff = WT_DN; }
    u16* dst = wt + (size_t)blk * WT_STRIDE + doff;
    int ntx = N >> 5;
    int ntiles = ntx * (Kd >> 5);
    int ti = blockIdx.x;
    if (ti >= ntiles) return;
    int tk = ti / ntx, tn = ti - tk * ntx;
    __shared__ u16 s[32][33];
    int tx = threadIdx.x & 31, ty = threadIdx.x >> 5;
#pragma unroll
    for (int i = 0; i < 4; i++) {
        int k = tk * 32 + ty + i * 8;
        s[ty + i * 8][tx] = f2bf(src[(size_t)k * N + tn * 32 + tx]);
    }
    __syncthreads();
#pragma unroll
    for (int i = 0; i < 4; i++) {
        int n = tn * 32 + ty + i * 8;
        dst[(size_t)n * Kd + tk * 32 + tx] = s[tx][ty + i * 8];
    }
}

// ---------------------------------------------------------------- MFMA bf16 GEMM, double-buffered
// A: bf16 MxK (lda, u16). Wt: bf16 [N][Kd] k-contiguous. Templated (BM,BN), BK=32.
template<int BM, int BN>
__device__ __forceinline__ void gemm_tile_body(const u16* __restrict__ A, int lda,
                                               const u16* __restrict__ Wt, int Kd,
                                               const float* __restrict__ bias,
                                               const float* __restrict__ resid, int ldr,
                                               float* __restrict__ Cout, int ldc,
                                               int M, float scale, int m0, int n0,
                                               u16 (*As)[BM][40], u16 (*Bs)[BN][40]) {
    constexpr int MT = BM / 32;
    constexpr int NT = BN / 32;
    constexpr int ANV = BM / 64;           // ushort8 A-loads per thread
    constexpr int BNV = BN / 64;           // ushort8 B-loads per thread
    int tid = threadIdx.x;
    int wave = tid >> 6, lane = tid & 63;
    int wm = (wave >> 1) * (BM / 2), wn = (wave & 1) * (BN / 2);
    int lrow = lane & 15, lquad = lane >> 4;

    f32x4 acc[MT][NT];
#pragma unroll
    for (int i = 0; i < MT; i++)
#pragma unroll
        for (int j = 0; j < NT; j++)
#pragma unroll
            for (int r = 0; r < 4; r++) acc[i][j][r] = 0.f;

    int am, ak, bn, bk;
    if (BM == 128) { am = tid >> 1; ak = (tid & 1) * 16; }
    else           { am = tid >> 2; ak = (tid & 3) * 8; }
    if (BN == 128) { bn = tid & 127; bk = (tid >> 7) * 16; }
    else           { bn = tid & 63;  bk = (tid >> 6) * 8; }
    int gm = m0 + am;
    const u16* arow = A + (size_t)(gm < M ? gm : 0) * lda + ak;
    bool avalid = gm < M;
    const u16* wrow = Wt + (size_t)(n0 + bn) * Kd + bk;

    ushort8v areg[ANV];
    ushort8v breg[BNV];

    auto load_tile = [&](int k0) {
        if (avalid) {
#pragma unroll
            for (int i = 0; i < ANV; i++) areg[i] = *(const ushort8v*)(arow + k0 + i * 8);
        } else {
#pragma unroll
            for (int i = 0; i < ANV; i++) areg[i] = (ushort8v){0,0,0,0,0,0,0,0};
        }
#pragma unroll
        for (int i = 0; i < BNV; i++) breg[i] = *(const ushort8v*)(wrow + k0 + i * 8);
    };
    auto store_tile = [&](int buf) {
#pragma unroll
        for (int i = 0; i < ANV; i++)
            *(ushort8v*)&As[buf][am][ak + i * 8] = areg[i];
#pragma unroll
        for (int i = 0; i < BNV; i++)
            *(ushort8v*)&Bs[buf][bn][bk + i * 8] = breg[i];
    };

    load_tile(0);
    store_tile(0);
    __syncthreads();

    int nk = Kd >> 5;
#pragma unroll 1
    for (int it = 0; it < nk; it++) {
        int cur = it & 1;
        bool more = (it + 1 < nk);
        if (more) load_tile((it + 1) << 5);
        bf16x8 afr[MT], bfr[NT];
#pragma unroll
        for (int mt = 0; mt < MT; mt++)
            afr[mt] = *(const bf16x8*)&As[cur][wm + mt * 16 + lrow][lquad * 8];
#pragma unroll
        for (int nt = 0; nt < NT; nt++)
            bfr[nt] = *(const bf16x8*)&Bs[cur][wn + nt * 16 + lrow][lquad * 8];
#pragma unroll
        for (int mt = 0; mt < MT; mt++)
#pragma unroll
            for (int nt = 0; nt < NT; nt++)
                acc[mt][nt] = __builtin_amdgcn_mfma_f32_16x16x32_bf16(
                    afr[mt], bfr[nt], acc[mt][nt], 0, 0, 0);
        if (more) store_tile(cur ^ 1);
        __syncthreads();
    }

#pragma unroll
    for (int mt = 0; mt < MT; mt++) {
#pragma unroll
        for (int r = 0; r < 4; r++) {
            int gmr = m0 + wm + mt * 16 + lquad * 4 + r;
            if (gmr >= M) continue;
#pragma unroll
            for (int nt = 0; nt < NT; nt++) {
                int gn = n0 + wn + nt * 16 + lrow;
                float v = acc[mt][nt][r] * scale;
                if (bias) v += bias[gn];
                if (resid) v += resid[(size_t)gmr * ldr + gn];
                Cout[(size_t)gmr * ldc + gn] = v;
            }
        }
    }
}

template<int BM, int BN>
__global__ __launch_bounds__(256, 2) void gemm_mfma_kernel(const u16* __restrict__ A, int lda,
                                                           const u16* __restrict__ Wt, int Kd,
                                                           const float* __restrict__ bias,
                                                           const float* __restrict__ resid, int ldr,
                                                           float* __restrict__ Cout, int ldc,
                                                           int M, float scale) {
    __shared__ __align__(16) u16 As[2][BM][40];
    __shared__ __align__(16) u16 Bs[2][BN][40];
    gemm_tile_body<BM, BN>(A, lda, Wt, Kd, bias, resid, ldr, Cout, ldc, M, scale,
                           blockIdx.y * BM, blockIdx.x * BN, As, Bs);
}

// q/k/v in ONE dispatch, BN=64: blockIdx.x in [0,48): sel = x>>4, nx = x&15.
__global__ __launch_bounds__(256, 2) void qkv_mfma_kernel(const u16* __restrict__ xc16,
                                                          const u16* __restrict__ xu16,
                                                          const u16* __restrict__ wtblk,
                                                          float* __restrict__ fq,
                                                          float* __restrict__ fk,
                                                          float* __restrict__ fv,
                                                          float kscale) {
    __shared__ __align__(16) u16 As[2][128][40];
    __shared__ __align__(16) u16 Bs[2][64][40];
    int sel = blockIdx.x >> 4, nx = blockIdx.x & 15;
    const u16* A = (sel == 2) ? xu16 : xc16;
    const u16* Wt = wtblk + ((sel == 0) ? WT_Q : (sel == 1) ? WT_K : WT_V);
    float* C = (sel == 0) ? fq : (sel == 1) ? fk : fv;
    float scale = (sel == 1) ? kscale : 1.f;
    gemm_tile_body<128, 64>(A, IN, Wt, IN, nullptr, nullptr, 0, C, IN, ROWS, scale,
                            blockIdx.y * 128, nx * 64, As, Bs);
}

// ---------------------------------------------------------------- causal depthwise conv (K=4) + SiLU
// Emits f32 xc (gates), bf16 xc16 (q/k GEMM A), bf16 xu16 (v GEMM A).
__global__ __launch_bounds__(256) void conv_silu_kernel(const float* __restrict__ up,
                                                        const float* __restrict__ ck,
                                                        const float* __restrict__ cb,
                                                        float* __restrict__ xc,
                                                        u16* __restrict__ xc16,
                                                        u16* __restrict__ xu16) {
    int idx = blockIdx.x * 256 + threadIdx.x;
    if (idx >= ROWS * IN) return;
    int c = idx & (IN - 1);
    int bt = idx >> 10;
    int t = bt % TT, b = bt / TT;
    float cur = up[((size_t)(b * TT + t)) * (2 * IN) + c];
    float acc = cb[c] + cur * ck[c * KK + (KK - 1)];
#pragma unroll
    for (int j = 0; j < KK - 1; j++) {
        int tt = t - (KK - 1) + j;
        if (tt >= 0) acc += up[((size_t)(b * TT + tt)) * (2 * IN) + c] * ck[c * KK + j];
    }
    float s = siluf(acc);
    xc[idx] = s;
    xc16[idx] = f2bf(s);
    xu16[idx] = f2bf(cur);
}

// ---------------------------------------------------------------- gate weight transpose
__global__ __launch_bounds__(256) void gate_w_transpose(const float* __restrict__ wig,
                                                        const float* __restrict__ wfg,
                                                        float* __restrict__ wt) {
    int idx = blockIdx.x * 256 + threadIdx.x;
    int k = idx & 1023;
    int g = (idx >> 10) & 15;
    int blk = idx >> 14;
    const float* w = (g < 8) ? (wig + (size_t)blk * IN * NHh) : (wfg + (size_t)blk * IN * NHh);
    wt[idx] = w[k * NHh + (g & 7)];
}

// ---------------------------------------------------------------- gate projections (coalesced wt)
__global__ __launch_bounds__(256) void gates_kernel(const float* __restrict__ xc,
                                                    const float* __restrict__ wt,
                                                    const float* __restrict__ big,
                                                    const float* __restrict__ bfg,
                                                    float* __restrict__ ip, float* __restrict__ fp) {
    int row = blockIdx.x, tid = threadIdx.x;
    __shared__ float sx[IN];
    *(float4*)&sx[tid * 4] = *(const float4*)(xc + (size_t)row * IN + tid * 4);
    __syncthreads();
    int g = tid >> 4, l = tid & 15;
    const float* wrow = wt + g * IN;
    float acc = 0.f;
#pragma unroll
    for (int j = 0; j < 16; j++) {
        int k = j * 64 + l * 4;
        float4 w4 = *(const float4*)(wrow + k);
        float4 x4 = *(const float4*)&sx[k];
        acc += w4.x * x4.x + w4.y * x4.y + w4.z * x4.z + w4.w * x4.w;
    }
#pragma unroll
    for (int o = 8; o > 0; o >>= 1) acc += __shfl_down(acc, o, 16);
    if (l == 0) {
        if (g < 8) ip[(size_t)row * NHh + g] = acc + big[g];
        else       fp[(size_t)row * NHh + (g - 8)] = acc + bfg[g - 8];
    }
}

// ---------------------------------------------------------------- chunkwise mLSTM
__global__ __launch_bounds__(64) void gate_scan_kernel(const float* __restrict__ ip,
        const float* __restrict__ fp, float* __restrict__ gG, float* __restrict__ gM,
        float* __restrict__ gMb, float* __restrict__ gDec) {
    constexpr int PER = 9;
    int chain = blockIdx.x;
    int b = chain >> 3, h = chain & 7;
    int lane = threadIdx.x;
    int tbase = lane * PER;
    float lcs[PER];
    float gi[PER];
    float csum = 0.f;
#pragma unroll
    for (int i = 0; i < PER; i++) {
        int t = tbase + i;
        float fpv = 0.f, ipv = 0.f;
        if (t < TT) {
            size_t gidx = (size_t)(b * TT + t) * NHh + h;
            fpv = fp[gidx]; ipv = ip[gidx];
        }
        float flv = (fpv >= 0.f) ? -log1pf(__expf(-fpv)) : (fpv - log1pf(__expf(fpv)));
        if (t >= TT) flv = 0.f;
        csum += flv;
        lcs[i] = csum;
        gi[i] = ipv;
    }
    float ps = csum;
#pragma unroll
    for (int o = 1; o < 64; o <<= 1) {
        float v = __shfl_up(ps, o);
        if (lane >= o) ps += v;
    }
    float Fexcl = ps - csum;
    float G[PER];
    float cmax = -1e30f;
#pragma unroll
    for (int i = 0; i < PER; i++) {
        int t = tbase + i;
        G[i] = (t < TT) ? (gi[i] - (Fexcl + lcs[i])) : -1e30f;
        cmax = fmaxf(cmax, G[i]);
        lcs[i] = cmax;
    }
    float pm = cmax;
#pragma unroll
    for (int o = 1; o < 64; o <<= 1) {
        float v = __shfl_up(pm, o);
        if (lane >= o) pm = fmaxf(pm, v);
    }
    float Me = __shfl_up(pm, 1);
    if (lane == 0) Me = -1e30f;
    __shared__ float sMb[NCH];
#pragma unroll
    for (int i = 0; i < PER; i++) {
        int t = tbase + i;
        if (t < TT) {
            float Mt = fmaxf(0.f, fmaxf(Me, lcs[i]));
            gG[chain * TT + t] = G[i];
            gM[chain * TT + t] = Mt;
            if (((t & 63) == 63) || t == TT - 1) sMb[t >> 6] = Mt;
        }
    }
    __syncthreads();
    if (lane < NCH) {
        float Mb = sMb[lane];
        float Mbp = (lane == 0) ? 0.f : sMb[lane - 1];
        gMb[chain * NCH + lane] = Mb;
        gDec[chain * NCH + lane] = __expf(Mbp - Mb);
    }
}

// Kernel B1: per-chunk local state. P stored [e][d] (e-major).
__global__ __launch_bounds__(256) void chunk_state_kernel(const float* __restrict__ kk,
        const float* __restrict__ vv, const float* __restrict__ gG,
        const float* __restrict__ gMb, float* __restrict__ P, float* __restrict__ nP) {
    int c = blockIdx.x, chain = blockIdx.y;
    int b = chain >> 3, h = chain & 7;
    int t0 = c * 64;
    int nvalid = min(64, TT - t0);
    __shared__ float sK[32][128], sV[32][128], sw[64];
    int tid = threadIdx.x;
    if (tid < 64) {
        float Mb = gMb[chain * NCH + c];
        sw[tid] = (tid < nvalid) ? __expf(gG[chain * TT + t0 + tid] - Mb) : 0.f;
    }
    int e = tid & 127, dg = (tid >> 7) * 64;
    float4 acc[16];
#pragma unroll
    for (int i = 0; i < 16; i++) acc[i] = make_float4(0.f, 0.f, 0.f, 0.f);
    float na = 0.f;
    for (int jh = 0; jh < 2; jh++) {
        int lrow = tid >> 5, lcol = (tid & 31) * 4;
        for (int rr = 0; rr < 4; rr++) {
            int r = lrow + rr * 8;
            int gr = jh * 32 + r;
            float4 kv = make_float4(0.f,0.f,0.f,0.f), vvv = kv;
            if (gr < nvalid) {
                size_t gb = ((size_t)(b * TT + t0 + gr)) * IN + h * DHd + lcol;
                kv = *(const float4*)(kk + gb);
                vvv = *(const float4*)(vv + gb);
            }
            *(float4*)&sK[r][lcol] = kv;
            *(float4*)&sV[r][lcol] = vvv;
        }
        __syncthreads();
        int jmax = min(32, nvalid - jh * 32);
#pragma unroll 1
        for (int j = 0; j < jmax; j++) {
            float wvj = sw[jh * 32 + j] * sV[j][e];
            const float4* kr = (const float4*)&sK[j][dg];
#pragma unroll
            for (int d4 = 0; d4 < 16; d4++) {
                float4 kq = kr[d4];
                acc[d4].x += kq.x * wvj; acc[d4].y += kq.y * wvj;
                acc[d4].z += kq.z * wvj; acc[d4].w += kq.w * wvj;
            }
        }
        if (tid < 128) {
#pragma unroll 1
            for (int j = 0; j < jmax; j++) na += sw[jh * 32 + j] * sK[j][tid];
        }
        __syncthreads();
    }
    float* Pbase = P + (((size_t)(c * 32 + chain)) << 14);
#pragma unroll
    for (int d4 = 0; d4 < 16; d4++)
        *(float4*)&Pbase[(size_t)e * 128 + dg + d4 * 4] = acc[d4];
    if (tid < 128) nP[(size_t)(c * 32 + chain) * 128 + tid] = na;
}

// Kernel B2: in-place exclusive combine over chunks.
__global__ __launch_bounds__(256) void chunk_combine_kernel(float* __restrict__ P,
        const float* __restrict__ gDec) {
    int chain = blockIdx.x >> 6;
    int idx = (blockIdx.x & 63) * 256 + threadIdx.x;
    float run = 0.f;
    for (int c = 0; c < NCH; c++) {
        size_t a = (((size_t)(c * 32 + chain)) << 14) + idx;
        float tmp = P[a];
        P[a] = run;
        run = run * gDec[chain * NCH + c] + tmp;
    }
}

__global__ __launch_bounds__(256) void n_combine_kernel(float* __restrict__ nP,
        const float* __restrict__ gDec) {
    int gidx = blockIdx.x * 256 + threadIdx.x;
    int chain = gidx >> 7, d = gidx & 127;
    float run = 0.f;
    for (int c = 0; c < NCH; c++) {
        size_t a = (size_t)(c * 32 + chain) * 128 + d;
        float tmp = nP[a];
        nP[a] = run;
        run = run * gDec[chain * NCH + c] + tmp;
    }
}

// Kernel C: MFMA chunk outputs (shared C-layout accumulator).
__global__ __launch_bounds__(512, 2) void chunk_out_kernel(const float* __restrict__ qq,
        const float* __restrict__ kk, const float* __restrict__ vv,
        const float* __restrict__ gG, const float* __restrict__ gM,
        const float* __restrict__ gMb, const float* __restrict__ P,
        const float* __restrict__ nP, float* __restrict__ hs) {
    int c = blockIdx.x, chain = blockIdx.y;
    int b = chain >> 3, h = chain & 7;
    int t0 = c * 64;
    int nvalid = min(64, TT - t0);
    __shared__ __align__(16) u16 smem[30720];   // 61.4 KB arena
    __shared__ float sG[64], sM[64], sWr[64], sInv[64], sNb[128], sRS[2][64];
    u16* sQ  = smem;            // [64][136] bf16   (phases 0-2)
    u16* sCB = smem + 8704;     // [128][136] bf16  (phase 0)
    u16* sK  = smem + 8704;     // [64][136] bf16   (phase 1, overlays sCB)
    u16* sVt = smem;            // [128][72] bf16   (phase 3, overlays sQ)
    u16* sD  = smem + 26112;    // [64][72] bf16    (phase 1 write, 3 read)
    int tid = threadIdx.x;
    int wave = tid >> 6, lane = tid & 63;
    int lrow = lane & 15, lquad = lane >> 4;
    int mq = wave >> 1, nh = wave & 1;

    float Mbprev = (c > 0) ? gMb[chain * NCH + c - 1] : 0.f;
    if (tid < 64) {
        bool val = tid < nvalid;
        sG[tid] = val ? gG[chain * TT + t0 + tid] : -1e30f;
        float Mv = val ? gM[chain * TT + t0 + tid] : 1e30f;
        sM[tid] = Mv;
        sWr[tid] = val ? __expf(Mbprev - Mv) : 0.f;
    }
    if (tid >= 128 && tid < 256) sNb[tid - 128] = nP[(size_t)(c * 32 + chain) * 128 + (tid - 128)];

    // ---- stage sQ [64][136]
    {
        int lr = tid >> 3, c0 = (tid & 7) * 16;
        bool val = lr < nvalid;
        size_t gb = ((size_t)(b * TT + t0 + lr)) * IN + h * DHd + c0;
#pragma unroll
        for (int i = 0; i < 4; i++) {
            float4 q4 = val ? *(const float4*)(qq + gb + i * 4) : make_float4(0.f,0.f,0.f,0.f);
            ushort4v tq = {f2bf(q4.x), f2bf(q4.y), f2bf(q4.z), f2bf(q4.w)};
            *(ushort4v*)&sQ[lr * 136 + c0 + i * 4] = tq;
        }
    }
    // ---- stage sCB [128][136] from P[e][d]
    {
        const float* CBbase = P + (((size_t)(c * 32 + chain)) << 14);
        int e = tid >> 2, d0 = (tid & 3) * 32;
#pragma unroll
        for (int i = 0; i < 8; i++) {
            float4 c4 = *(const float4*)(CBbase + (size_t)e * 128 + d0 + i * 4);
            ushort4v tc = {f2bf(c4.x), f2bf(c4.y), f2bf(c4.z), f2bf(c4.w)};
            *(ushort4v*)&sCB[e * 136 + d0 + i * 4] = tc;
        }
    }
    __syncthreads();

    // ---- phase 0: inter = Q @ CB, C-layout acc; then scale by wr
    f32x4 acc[4];
#pragma unroll
    for (int tt = 0; tt < 4; tt++)
#pragma unroll
        for (int r = 0; r < 4; r++) acc[tt][r] = 0.f;
#pragma unroll 1
    for (int ks = 0; ks < 4; ks++) {
        bf16x8 af = *(const bf16x8*)&sQ[(mq * 16 + lrow) * 136 + ks * 32 + lquad * 8];
#pragma unroll
        for (int tt = 0; tt < 4; tt++) {
            bf16x8 bf = *(const bf16x8*)&sCB[(nh * 64 + tt * 16 + lrow) * 136 + ks * 32 + lquad * 8];
            acc[tt] = __builtin_amdgcn_mfma_f32_16x16x32_bf16(af, bf, acc[tt], 0, 0, 0);
        }
    }
#pragma unroll
    for (int tt = 0; tt < 4; tt++)
#pragma unroll
        for (int r = 0; r < 4; r++) acc[tt][r] *= sWr[mq * 16 + lquad * 4 + r];
    __syncthreads();

    // ---- stage sK (overlays sCB)
    {
        int lr = tid >> 3, c0 = (tid & 7) * 16;
        bool val = lr < nvalid;
        size_t gb = ((size_t)(b * TT + t0 + lr)) * IN + h * DHd + c0;
#pragma unroll
        for (int i = 0; i < 4; i++) {
            float4 k4 = val ? *(const float4*)(kk + gb + i * 4) : make_float4(0.f,0.f,0.f,0.f);
            ushort4v tk = {f2bf(k4.x), f2bf(k4.y), f2bf(k4.z), f2bf(k4.w)};
            *(ushort4v*)&sK[lr * 136 + c0 + i * 4] = tk;
        }
    }
    __syncthreads();

    // ---- phase 1: S = Q K^T (2 n-tiles/wave), weights, sD bf16, in-reg rowsums
    {
        f32x4 accS[2];
#pragma unroll
        for (int tt = 0; tt < 2; tt++)
#pragma unroll
            for (int r = 0; r < 4; r++) accS[tt][r] = 0.f;
#pragma unroll 1
        for (int ks = 0; ks < 4; ks++) {
            bf16x8 af = *(const bf16x8*)&sQ[(mq * 16 + lrow) * 136 + ks * 32 + lquad * 8];
#pragma unroll
            for (int tt = 0; tt < 2; tt++) {
                bf16x8 bf = *(const bf16x8*)&sK[((nh * 2 + tt) * 16 + lrow) * 136 + ks * 32 + lquad * 8];
                accS[tt] = __builtin_amdgcn_mfma_f32_16x16x32_bf16(af, bf, accS[tt], 0, 0, 0);
            }
        }
        float rsum[4] = {0.f, 0.f, 0.f, 0.f};
#pragma unroll
        for (int tt = 0; tt < 2; tt++) {
            int j = (nh * 2 + tt) * 16 + lrow;
            float Gj = sG[j];
#pragma unroll
            for (int r = 0; r < 4; r++) {
                int t = mq * 16 + lquad * 4 + r;
                float w = (j <= t) ? __expf(Gj - sM[t]) : 0.f;
                float wD = accS[tt][r] * w;
                rsum[r] += wD;
                sD[t * 72 + j] = f2bf(wD);
            }
        }
#pragma unroll
        for (int r = 0; r < 4; r++) {
#pragma unroll
            for (int msk = 1; msk < 16; msk <<= 1) rsum[r] += __shfl_xor(rsum[r], msk);
        }
        if (lrow == 0) {
#pragma unroll
            for (int r = 0; r < 4; r++) sRS[nh][mq * 16 + lquad * 4 + r] = rsum[r];
        }
    }
    __syncthreads();

    // ---- phase 2: denominators (tid<64); qnb from bf16 sQ
    if (tid < 64) {
        float qn = 0.f;
#pragma unroll 1
        for (int d4 = 0; d4 < 32; d4++) {
            ushort4v q4 = *(const ushort4v*)&sQ[tid * 136 + d4 * 4];
            float4 nb = *(const float4*)&sNb[d4 * 4];
            qn += bfu(q4.x) * nb.x + bfu(q4.y) * nb.y + bfu(q4.z) * nb.z + bfu(q4.w) * nb.w;
        }
        float den = sRS[0][tid] + sRS[1][tid] + sWr[tid] * qn;
        sInv[tid] = 1.f / fmaxf(fabsf(den), 1.f);
    }
    __syncthreads();

    // ---- stage sVt [128][72] = V^T bf16 (overlays sQ)
    {
        int e = tid & 127, tg = (tid >> 7) * 16;
#pragma unroll 1
        for (int i = 0; i < 16; i++) {
            int t = tg + i;
            float v = (t < nvalid) ? vv[((size_t)(b * TT + t0 + t)) * IN + h * DHd + e] : 0.f;
            sVt[e * 72 + t] = f2bf(v);
        }
    }
    __syncthreads();

    // ---- phase 3: acc += D @ V
#pragma unroll 1
    for (int ks = 0; ks < 2; ks++) {
        bf16x8 af = *(const bf16x8*)&sD[(mq * 16 + lrow) * 72 + ks * 32 + lquad * 8];
#pragma unroll
        for (int tt = 0; tt < 4; tt++) {
            bf16x8 bf = *(const bf16x8*)&sVt[(nh * 64 + tt * 16 + lrow) * 72 + ks * 32 + lquad * 8];
            acc[tt] = __builtin_amdgcn_mfma_f32_16x16x32_bf16(af, bf, acc[tt], 0, 0, 0);
        }
    }

    // ---- store (C-layout: col=lane&15 -> e, row=quad*4+r -> t)
#pragma unroll
    for (int tt = 0; tt < 4; tt++) {
#pragma unroll
        for (int r = 0; r < 4; r++) {
            int t = mq * 16 + lquad * 4 + r;
            if (t < nvalid) {
                int e = nh * 64 + tt * 16 + lrow;
                hs[((size_t)(b * TT + t0 + t)) * IN + h * DHd + e] = acc[tt][r] * sInv[t];
            }
        }
    }
}

// ---------------------------------------------------------------- per-head norm * hn_s * silu(z) -> bf16
__global__ __launch_bounds__(64) void headnorm_kernel(const float* __restrict__ hs,
                                                      const float* __restrict__ hn,
                                                      const float* __restrict__ up,
                                                      u16* __restrict__ out16) {
    int idx = blockIdx.x;
    int h = idx & 7, bt = idx >> 3;
    int tid = threadIdx.x;
    size_t base = (size_t)bt * IN + h * DHd;
    float x0 = hs[base + tid], x1 = hs[base + 64 + tid];
    float sum = x0 + x1, sq = x0 * x0 + x1 * x1;
#pragma unroll
    for (int o = 32; o > 0; o >>= 1) { sum += __shfl_xor(sum, o); sq += __shfl_xor(sq, o); }
    float mu = sum / DHd, var = sq / DHd - mu * mu, inv = rsqrtf(var + EPSV);
    size_t zb = (size_t)bt * (2 * IN) + IN + h * DHd;
    out16[base + tid]      = f2bf((x0 - mu) * inv * hn[h * DHd + tid]      * siluf(up[zb + tid]));
    out16[base + 64 + tid] = f2bf((x1 - mu) * inv * hn[h * DHd + 64 + tid] * siluf(up[zb + 64 + tid]));
}

// ---------------------------------------------------------------- head: LN+ReLU of cls rows -> vcls
__global__ __launch_bounds__(256) void cls_ln_kernel(const float* __restrict__ hbuf,
                                                     const float* __restrict__ s, const float* __restrict__ bb,
                                                     float* __restrict__ vcls) {
    int b = blockIdx.x, tid = threadIdx.x;
    const float* r = hbuf + ((size_t)b * TT + TT - 1) * Dm;
    __shared__ float s1[4], s2[4];
    float x0 = r[tid], x1 = r[tid + 256];
    float sum = x0 + x1, sq = x0 * x0 + x1 * x1;
#pragma unroll
    for (int o = 32; o > 0; o >>= 1) { sum += __shfl_xor(sum, o); sq += __shfl_xor(sq, o); }
    if ((tid & 63) == 0) { s1[tid >> 6] = sum; s2[tid >> 6] = sq; }
    __syncthreads();
    sum = s1[0] + s1[1] + s1[2] + s1[3];
    sq  = s2[0] + s2[1] + s2[2] + s2[3];
    float mu = sum / Dm, var = sq / Dm - mu * mu, inv = rsqrtf(var + EPSV);
    float n0 = (x0 - mu) * inv * s[tid] + bb[tid];
    float n1 = (x1 - mu) * inv * s[tid + 256] + bb[tid + 256];
    vcls[b * Dm + tid]       = fmaxf(n0, 0.f);
    vcls[b * Dm + tid + 256] = fmaxf(n1, 0.f);
}

// ---------------------------------------------------------------- head: FC
__global__ __launch_bounds__(256) void fc_kernel(const float* __restrict__ vcls,
                                                 const float* __restrict__ fw,
                                                 const float* __restrict__ fb,
                                                 float* __restrict__ out) {
    __shared__ float svc[Bsz][Dm];
    __shared__ float sred[4][256];
    int tid = threadIdx.x;
    int j0 = blockIdx.x * 64;
    {
        const float4* src = (const float4*)vcls;
        float4* dst = (float4*)&svc[0][0];
        dst[tid] = src[tid];
        dst[tid + 256] = src[tid + 256];
    }
    __syncthreads();
    int j = j0 + (tid & 63);
    int chunk = tid >> 6;
    int kbase = chunk * 128;
    float a0 = 0.f, a1 = 0.f, a2 = 0.f, a3 = 0.f;
    if (j < NCc) {
        const float* fwp = fw + (size_t)kbase * NCc + j;
#pragma unroll 4
        for (int kk = 0; kk < 128; kk++) {
            float w = fwp[(size_t)kk * NCc];
            a0 += svc[0][kbase + kk] * w;
            a1 += svc[1][kbase + kk] * w;
            a2 += svc[2][kbase + kk] * w;
            a3 += svc[3][kbase + kk] * w;
        }
    }
    int jl = tid & 63;
    sred[chunk][jl * 4 + 0] = a0;
    sred[chunk][jl * 4 + 1] = a1;
    sred[chunk][jl * 4 + 2] = a2;
    sred[chunk][jl * 4 + 3] = a3;
    __syncthreads();
    if (tid < 64) {
        int jj = j0 + tid;
        if (jj < NCc) {
            float bias = fb[jj];
#pragma unroll
            for (int b = 0; b < Bsz; b++) {
                float v = sred[0][tid * 4 + b] + sred[1][tid * 4 + b]
                        + sred[2][tid * 4 + b] + sred[3][tid * 4 + b];
                out[b * NCc + jj] = v + bias;
            }
        }
    }
}

// ---------------------------------------------------------------- launch
extern "C" void kernel_launch(void* const* d_in, const int* in_sizes, int n_in,
                              void* d_out, int out_size, void* d_ws, size_t ws_size,
                              hipStream_t stream) {
    const float* x      = (const float*)d_in[0];
    const float* cls    = (const float*)d_in[1];
    const float* ln_s   = (const float*)d_in[2];
    const float* ln_b   = (const float*)d_in[3];
    const float* w_up   = (const float*)d_in[4];
    const float* b_up   = (const float*)d_in[5];
    const float* conv_k = (const float*)d_in[6];
    const float* conv_b = (const float*)d_in[7];
    const float* w_q    = (const float*)d_in[8];
    const float* w_k    = (const float*)d_in[9];
    const float* w_v    = (const float*)d_in[10];
    const float* w_ig   = (const float*)d_in[11];
    const float* b_ig   = (const float*)d_in[12];
    const float* w_fg   = (const float*)d_in[13];
    const float* b_fg   = (const float*)d_in[14];
    const float* hn_s   = (const float*)d_in[15];
    const float* w_down = (const float*)d_in[16];
    const float* b_down = (const float*)d_in[17];
    const float* fcls   = (const float*)d_in[18];
    const float* fclb   = (const float*)d_in[19];
    const float* fc_w   = (const float*)d_in[20];
    const float* fc_b   = (const float*)d_in[21];
    float* out = (float*)d_out;

    float* ws = (float*)d_ws;
    size_t off = 0;
    float* f_h  = ws + off; off += (size_t)ROWS * Dm;
    float* f_up = ws + off; off += (size_t)ROWS * 2 * IN;
    float* f_xc = ws + off; off += (size_t)ROWS * IN;
    float* f_q  = ws + off; off += (size_t)ROWS * IN;
    float* f_k  = ws + off; off += (size_t)ROWS * IN;
    float* f_v  = ws + off; off += (size_t)ROWS * IN;
    float* f_hs = ws + off; off += (size_t)ROWS * IN;
    float* f_ip = ws + off; off += (size_t)ROWS * NHh;
    float* f_fp = ws + off; off += (size_t)ROWS * NHh;
    float* g_G  = ws + off; off += 32 * TT;
    float* g_M  = ws + off; off += 32 * TT;
    float* g_Mb = ws + off; off += 32 * NCH;
    float* g_De = ws + off; off += 32 * NCH;
    float* g_P  = ws + off; off += (size_t)NCH * 32 * DHd * DHd;
    float* g_nP = ws + off; off += (size_t)NCH * 32 * DHd;
    float* f_vc = ws + off; off += Bsz * Dm;
    float* g_wt = ws + off; off += 2 * 16 * IN;
    u16* g_Wt  = (u16*)(ws + off); off += (2 * WT_STRIDE + 1) / 2;
    u16* f_xn16 = (u16*)(ws + off); off += ((size_t)ROWS * Dm + 1) / 2;
    u16* f_xc16 = (u16*)(ws + off); off += ((size_t)ROWS * IN + 1) / 2;
    u16* f_xu16 = (u16*)(ws + off); off += ((size_t)ROWS * IN + 1) / 2;
    u16* f_xg16 = (u16*)(ws + off); off += ((size_t)ROWS * IN + 1) / 2;

    const float kscale = 0.08838834764831845f; // DH^-0.5
    const int MB = (ROWS + 127) / 128;         // 17
    const int MB64 = (ROWS + 63) / 64;         // 33

    concat_kernel<<<(ROWS * Dm + 255) / 256, 256, 0, stream>>>(x, cls, f_h);
    gate_w_transpose<<<(2 * 16 * IN + 255) / 256, 256, 0, stream>>>(w_ig, w_fg, g_wt);
    w_transpose_kernel<<<dim3(1024, 10), 256, 0, stream>>>(w_up, w_q, w_k, w_v, w_down, g_Wt);

    for (int blk = 0; blk < 2; blk++) {
        const float* p_ln_s = ln_s + blk * Dm;
        const float* p_ln_b = ln_b + blk * Dm;
        const float* p_bup  = b_up + (size_t)blk * 2 * IN;
        const float* p_ck   = conv_k + (size_t)blk * IN * KK;
        const float* p_cb   = conv_b + (size_t)blk * IN;
        const float* p_big  = b_ig + (size_t)blk * NHh;
        const float* p_bfg  = b_fg + (size_t)blk * NHh;
        const float* p_hns  = hn_s + (size_t)blk * NHh * DHd;
        const float* p_bd   = b_down + (size_t)blk * Dm;
        const u16*   p_wt   = g_Wt + (size_t)blk * WT_STRIDE;

        ln_kernel<<<ROWS, 256, 0, stream>>>(f_h, p_ln_s, p_ln_b, f_xn16);

        gemm_mfma_kernel<128, 64><<<dim3(2 * IN / 64, MB), 256, 0, stream>>>(
            f_xn16, Dm, p_wt + WT_UP, Dm, p_bup, nullptr, 0, f_up, 2 * IN, ROWS, 1.f);

        conv_silu_kernel<<<(ROWS * IN + 255) / 256, 256, 0, stream>>>(
            f_up, p_ck, p_cb, f_xc, f_xc16, f_xu16);

        qkv_mfma_kernel<<<dim3(48, MB), 256, 0, stream>>>(
            f_xc16, f_xu16, p_wt, f_q, f_k, f_v, kscale);

        gates_kernel<<<ROWS, 256, 0, stream>>>(f_xc, g_wt + blk * 16 * IN, p_big, p_bfg,
                                               f_ip, f_fp);

        // chunkwise-parallel mLSTM
        gate_scan_kernel<<<32, 64, 0, stream>>>(f_ip, f_fp, g_G, g_M, g_Mb, g_De);
        chunk_state_kernel<<<dim3(NCH, 32), 256, 0, stream>>>(f_k, f_v, g_G, g_Mb, g_P, g_nP);
        chunk_combine_kernel<<<32 * 64, 256, 0, stream>>>(g_P, g_De);
        n_combine_kernel<<<16, 256, 0, stream>>>(g_nP, g_De);
        chunk_out_kernel<<<dim3(NCH, 32), 512, 0, stream>>>(f_q, f_k, f_v, g_G, g_M, g_Mb,
                                                            g_P, g_nP, f_hs);

        headnorm_kernel<<<ROWS * NHh, 64, 0, stream>>>(f_hs, p_hns, f_up, f_xg16);

        gemm_mfma_kernel<64, 64><<<dim3(Dm / 64, MB64), 256, 0, stream>>>(
            f_xg16, IN, p_wt + WT_DN, IN, p_bd, f_h, Dm, f_h, Dm, ROWS, 1.f);
    }

    cls_ln_kernel<<<Bsz, 256, 0, stream>>>(f_h, fcls, fclb, f_vc);
    fc_kernel<<<(NCc + 63) / 64, 256, 0, stream>>>(f_vc, fc_w, fc_b, out);
}